// Round 9
// baseline (341.805 us; speedup 1.0000x reference)
//
#include <hip/hip_runtime.h>
#include <hip/hip_bf16.h>

#define MODS 3
#define BSZ 2
#define LSEQ 2048
#define DMODEL 512
#define DINNER 1024
#define DTRANK 32
#define NSTATE 16
#define DCONV 4
#define MROWS (BSZ*LSEQ)   // 4096
#define NCHUNK 64
#define CHUNK 32           // LSEQ / NCHUNK

#define LOG2E 1.44269504088896f
#define LN2   0.69314718055995f

typedef __attribute__((ext_vector_type(8))) short short8v;
typedef __attribute__((ext_vector_type(4))) short short4v;
typedef __attribute__((ext_vector_type(2))) short short2v;
typedef __attribute__((ext_vector_type(4))) float f32x4;

#if __has_builtin(__builtin_amdgcn_exp2f)
#define EXP2F __builtin_amdgcn_exp2f
#else
#define EXP2F exp2f
#endif
#if __has_builtin(__builtin_amdgcn_rcpf)
#define RCPF __builtin_amdgcn_rcpf
#else
#define RCPF(x) (1.0f / (x))
#endif

__device__ __forceinline__ short f2bf(float x) {
    __hip_bfloat16 h = __float2bfloat16(x);
    return __builtin_bit_cast(short, h);
}
__device__ __forceinline__ float bf2f(short s) {
    return __uint_as_float(((unsigned)(unsigned short)s) << 16);
}
__device__ __forceinline__ void gl_lds16(const short* g, short* l) {
    __builtin_amdgcn_global_load_lds(
        (const __attribute__((address_space(1))) unsigned int*)g,
        (__attribute__((address_space(3))) unsigned int*)l, 16, 0, 0);
}
__device__ __forceinline__ float sigmoid_f(float x) {
    return RCPF(1.f + EXP2F(-x * LOG2E));
}

// ---------------- bf16 MFMA GEMM NT, BK=32, XOR-swizzled LDS, 2-phase prefetch dbuf ----
// Tile 128 x (NJ*32), 4 waves 2x2; wave tile 64 x (NJ*16). NJ=8 -> wave 64x128
// (reuse 5.3 ops/read vs 4 at NJ=4 — raises the LDS-capped MfmaUtil ceiling).
template<int NJ>
__global__ __launch_bounds__(256) void gemm_bf16(
    const __hip_bfloat16* __restrict__ A_, const __hip_bfloat16* __restrict__ B_,
    int K, int lda, int ldb, long sA, long sB,
    float* __restrict__ Cf, __hip_bfloat16* __restrict__ Cb, int ldc, long sC,
    const float* __restrict__ res, long sRes,
    const float* __restrict__ coef_base, int coef_stride,
    const float* __restrict__ bias, long sBias, int act)
{
    constexpr int BK = 32;
    constexpr int BN = NJ * 32;
    constexpr int ASZ = 128 * BK;
    constexpr int BSZe = BN * BK;
    __shared__ alignas(16) short As[2 * ASZ];
    __shared__ alignas(16) short Bs[2 * BSZe];
    const int z = blockIdx.z;
    const int bm0 = blockIdx.y * 128;
    const int bn0 = blockIdx.x * BN;
    const short* Ag = (const short*)A_ + z * sA + (long)bm0 * lda;
    const short* Bg = (const short*)B_ + z * sB + (long)bn0 * ldb;
    const int tid = threadIdx.x;
    const int lane = tid & 63;
    const int w = tid >> 6;
    const int wr = w >> 1, wc = w & 1;
    const int lr = lane & 15;
    const int sidx = lane >> 4;
    const int srow = tid >> 2;
    const int sgcol = ((tid & 3) ^ ((srow >> 1) & 3)) * 8;
    const int fA = (lr >> 1) & 3;

    constexpr int AINSTR = ASZ / 2048;
    constexpr int BINSTR = BSZe / 2048;
    constexpr int RPI = 2048 / BK;

    f32x4 acc[4][NJ];
    #pragma unroll
    for (int i = 0; i < 4; ++i)
        #pragma unroll
        for (int j = 0; j < NJ; ++j)
            acc[i][j] = (f32x4){0.f, 0.f, 0.f, 0.f};

    auto stage = [&](int buf, int k0) {
        #pragma unroll
        for (int i = 0; i < AINSTR; ++i)
            gl_lds16(Ag + (long)(i * RPI + srow) * lda + k0 + sgcol,
                     As + buf * ASZ + i * 2048 + tid * 8);
        #pragma unroll
        for (int i = 0; i < BINSTR; ++i)
            gl_lds16(Bg + (long)(i * RPI + srow) * ldb + k0 + sgcol,
                     Bs + buf * BSZe + i * 2048 + tid * 8);
    };
    auto compute = [&](int buf) {
        const int sl = (sidx ^ fA) * 8;
        short8v af[4], bfr[NJ];
        #pragma unroll
        for (int i = 0; i < 4; ++i)
            af[i] = *(const short8v*)&As[buf * ASZ + (wr * 64 + i * 16 + lr) * BK + sl];
        #pragma unroll
        for (int j = 0; j < NJ; ++j)
            bfr[j] = *(const short8v*)&Bs[buf * BSZe + (wc * NJ * 16 + j * 16 + lr) * BK + sl];
        #pragma unroll
        for (int i = 0; i < 4; ++i)
            #pragma unroll
            for (int j = 0; j < NJ; ++j)
                acc[i][j] = __builtin_amdgcn_mfma_f32_16x16x32_bf16(af[i], bfr[j], acc[i][j], 0, 0, 0);
    };

    stage(0, 0);
    __syncthreads();
    int cur = 0;
    for (int k0 = BK; k0 < K; k0 += BK) {
        stage(cur ^ 1, k0);
        compute(cur);
        __syncthreads();
        cur ^= 1;
    }
    compute(cur);

    const float alpha = coef_base ? coef_base[z * coef_stride] : 1.0f;
    const float* resz = res ? res + z * sRes : nullptr;
    const float* biasz = bias ? bias + z * sBias : nullptr;
    float* Cfz = Cf ? Cf + z * sC : nullptr;
    __hip_bfloat16* Cbz = Cb ? Cb + z * sC : nullptr;
    #pragma unroll
    for (int i = 0; i < 4; ++i) {
        #pragma unroll
        for (int r = 0; r < 4; ++r) {
            const int row = bm0 + wr * 64 + i * 16 + (lane >> 4) * 4 + r;
            #pragma unroll
            for (int j = 0; j < NJ; ++j) {
                const int col = bn0 + wc * NJ * 16 + j * 16 + lr;
                float val = acc[i][j][r];
                if (biasz) val += biasz[col];
                if (act == 1)
                    val = (val > 20.f) ? val : LN2 * __log2f(1.f + EXP2F(val * LOG2E));
                val *= alpha;
                if (resz) val += resz[(long)row * ldc + col];
                if (Cfz) Cfz[(long)row * ldc + col] = val;
                else     Cbz[(long)row * ldc + col] = __float2bfloat16(val);
            }
        }
    }
}

// ---------------- stack: x_in = [v;a;t] f32, sec_bf = [a;t;v] bf16 ----------------
__global__ __launch_bounds__(256) void stack_vat_kernel(
    const float* __restrict__ v, const float* __restrict__ a, const float* __restrict__ t,
    float* __restrict__ x_in, __hip_bfloat16* __restrict__ sec_bf)
{
    const long idx = (long)blockIdx.x * 256 + threadIdx.x;
    const int m = (int)(idx >> 19);
    const long off = idx & 524287;
    const float* prim = (m == 0) ? v : (m == 1) ? a : t;
    const float* sec  = (m == 0) ? a : (m == 1) ? t : v;
    float4 pv = ((const float4*)prim)[off];
    float4 sv = ((const float4*)sec)[off];
    ((float4*)x_in)[idx] = pv;
    short4v s;
    s.x = f2bf(sv.x); s.y = f2bf(sv.y); s.z = f2bf(sv.z); s.w = f2bf(sv.w);
    ((short4v*)sec_bf)[idx] = s;
}

// ---------------- fused weight conversions: 5 segments f32 -> bf16 ----------------
__global__ __launch_bounds__(256) void cvt_all_kernel(
    const float* __restrict__ s0, __hip_bfloat16* __restrict__ d0, int n0,
    const float* __restrict__ s1, __hip_bfloat16* __restrict__ d1, int n1,
    const float* __restrict__ s2, __hip_bfloat16* __restrict__ d2, int n2,
    const float* __restrict__ s3, __hip_bfloat16* __restrict__ d3, int n3,
    const float* __restrict__ s4, __hip_bfloat16* __restrict__ d4, int n4)
{
    int idx = blockIdx.x * 256 + threadIdx.x;
    const float* s; __hip_bfloat16* d; int off = idx;
    if      (off < n0)                  { s = s0; d = d0; }
    else if ((off -= n0) < n1)          { s = s1; d = d1; }
    else if ((off -= n1) < n2)          { s = s2; d = d2; }
    else if ((off -= n2) < n3)          { s = s3; d = d3; }
    else if ((off -= n3) < n4)          { s = s4; d = d4; }
    else return;
    float4 vv = ((const float4*)s)[off];
    short4v o;
    o.x = f2bf(vv.x); o.y = f2bf(vv.y); o.z = f2bf(vv.z); o.w = f2bf(vv.w);
    ((short4v*)d)[off] = o;
}

// ---------------- small prep: conv-weight transpose + A2T ----------------
__global__ __launch_bounds__(256) void small_prep_kernel(const float* __restrict__ cw,
    float* __restrict__ cwT, const float* __restrict__ A_log, float* __restrict__ A2T)
{
    const int idx = blockIdx.x * 256 + threadIdx.x;
    if (idx < MODS * DINNER * DCONV) {
        const int k = idx & 3;
        const int c = (idx >> 2) & 1023;
        const int m = idx >> 12;
        cwT[(m * DCONV + k) * DINNER + c] = cw[idx];
    } else if (idx < MODS * DINNER * DCONV + MODS * NSTATE * DINNER) {
        const int j = idx - MODS * DINNER * DCONV;
        const int c = j & 1023;
        const int n = (j >> 10) & 15;
        const int m = j >> 14;
        A2T[j] = -EXP2F(A_log[((long)m * DINNER + c) * NSTATE + n] * LOG2E) * LOG2E;
    }
}

// ---------------- LayerNorm: f32 in -> bf16 out ----------------
__global__ __launch_bounds__(256) void ln_kernel(const float* __restrict__ x, __hip_bfloat16* __restrict__ xn,
                                                 const float* __restrict__ nw, const float* __restrict__ nb)
{
    const int row = blockIdx.x;
    const int m = row >> 12;
    const int tid = threadIdx.x;
    const float2 v = *reinterpret_cast<const float2*>(x + (long)row * DMODEL + tid * 2);
    float s = v.x + v.y;
    float sq = v.x * v.x + v.y * v.y;
    #pragma unroll
    for (int off = 32; off > 0; off >>= 1) {
        s  += __shfl_down(s, off);
        sq += __shfl_down(sq, off);
    }
    __shared__ float ws_s[4], ws_q[4];
    const int wid = tid >> 6, lane = tid & 63;
    if (lane == 0) { ws_s[wid] = s; ws_q[wid] = sq; }
    __syncthreads();
    if (tid == 0) {
        float ts = ws_s[0] + ws_s[1] + ws_s[2] + ws_s[3];
        float tq = ws_q[0] + ws_q[1] + ws_q[2] + ws_q[3];
        float mu = ts / DMODEL;
        float var = tq / DMODEL - mu * mu;
        ws_s[0] = mu;
        ws_q[0] = rsqrtf(var + 1e-5f);
    }
    __syncthreads();
    const float mu = ws_s[0], rstd = ws_q[0];
    const int e0 = tid * 2;
    float2 w  = *reinterpret_cast<const float2*>(nw + m * DMODEL + e0);
    float2 bb = *reinterpret_cast<const float2*>(nb + m * DMODEL + e0);
    short2v o;
    o.x = f2bf((v.x - mu) * rstd * w.x + bb.x);
    o.y = f2bf((v.y - mu) * rstd * w.y + bb.y);
    *reinterpret_cast<short2v*>((short*)xn + (long)row * DMODEL + e0) = o;
}

// ---------------- depthwise causal conv(4) + SiLU ----------------
__global__ __launch_bounds__(256) void conv_silu_kernel(const __hip_bfloat16* __restrict__ xz,
    const float* __restrict__ cwT, const float* __restrict__ cb, __hip_bfloat16* __restrict__ xc)
{
    const int idx = blockIdx.x * 256 + threadIdx.x;   // < 6*256*128 = 196608
    const int c8 = idx & 127;
    const int lt = (idx >> 7) & 255;
    const int mb = idx >> 15;
    const int m  = mb >> 1;
    const int c0 = c8 * 8;
    const int l0 = lt * 8;

    float4 wlo[DCONV], whi[DCONV];
    #pragma unroll
    for (int k = 0; k < DCONV; ++k) {
        wlo[k] = *(const float4*)&cwT[(m * DCONV + k) * DINNER + c0];
        whi[k] = *(const float4*)&cwT[(m * DCONV + k) * DINNER + c0 + 4];
    }
    const float4 blo = *(const float4*)&cb[m * DINNER + c0];
    const float4 bhi = *(const float4*)&cb[m * DINNER + c0 + 4];

    const short* base = (const short*)xz + (long)mb * LSEQ * 2048 + c0;
    short* obase = (short*)xc + (long)mb * LSEQ * DINNER + c0;

    short8v r0 = {}, r1 = {}, r2 = {};
    if (l0 - 3 >= 0) r0 = *(const short8v*)(base + (long)(l0 - 3) * 2048);
    if (l0 - 2 >= 0) r1 = *(const short8v*)(base + (long)(l0 - 2) * 2048);
    if (l0 - 1 >= 0) r2 = *(const short8v*)(base + (long)(l0 - 1) * 2048);

    #pragma unroll
    for (int i = 0; i < 8; ++i) {
        const short8v cur = *(const short8v*)(base + (long)(l0 + i) * 2048);
        float acc[8];
        #pragma unroll
        for (int j = 0; j < 4; ++j) {
            acc[j]     = ((const float*)&blo)[j];
            acc[4 + j] = ((const float*)&bhi)[j];
        }
        #pragma unroll
        for (int j = 0; j < 8; ++j) {
            const float w0 = (j < 4) ? ((const float*)&wlo[0])[j] : ((const float*)&whi[0])[j - 4];
            const float w1 = (j < 4) ? ((const float*)&wlo[1])[j] : ((const float*)&whi[1])[j - 4];
            const float w2 = (j < 4) ? ((const float*)&wlo[2])[j] : ((const float*)&whi[2])[j - 4];
            const float w3 = (j < 4) ? ((const float*)&wlo[3])[j] : ((const float*)&whi[3])[j - 4];
            acc[j] += w0 * bf2f(r0[j]) + w1 * bf2f(r1[j]) + w2 * bf2f(r2[j]) + w3 * bf2f(cur[j]);
        }
        short8v o;
        #pragma unroll
        for (int j = 0; j < 8; ++j)
            o[j] = f2bf(acc[j] * sigmoid_f(acc[j]));
        *(short8v*)(obase + (long)(l0 + i) * DINNER) = o;
        r0 = r1; r1 = r2; r2 = cur;
    }
}

// ---------------- chunk-parallel selective scan (bf16 activations) ----------------
// Fast path: A2[n] == (n+1)*A2[0] (true for A_log = log(1..16)) -> e_n = E^(n+1),
// 1 exp + 15 muls instead of 16 exps per step. Uniform runtime check; general
// fallback keeps correctness for arbitrary A_log.
__device__ __forceinline__ bool geo_check(const float* A2) {
    bool g = true;
    #pragma unroll
    for (int n = 1; n < NSTATE; ++n)
        g = g && (__builtin_fabsf(A2[n] - (float)(n + 1) * A2[0]) <= 1e-4f * __builtin_fabsf(A2[n]));
    return g;
}

__global__ __launch_bounds__(256) void scan_pass1_kernel(
    const __hip_bfloat16* __restrict__ delta, const __hip_bfloat16* __restrict__ xc,
    const __hip_bfloat16* __restrict__ dbc, const float* __restrict__ A2T,
    float* __restrict__ Fbuf, float* __restrict__ Dbuf)
{
    const int bx = blockIdx.x;             // mb(6) x cg(4) x chunk(64)
    const int chunk = bx & (NCHUNK - 1);
    const int cg = (bx >> 6) & 3;
    const int mb = bx >> 8;
    const int m = mb >> 1, b = mb & 1;
    const int tid = threadIdx.x;
    const int c = cg * 256 + tid;

    float A2[NSTATE];
    #pragma unroll
    for (int n = 0; n < NSTATE; ++n)
        A2[n] = A2T[((long)m * NSTATE + n) * DINNER + c];
    const bool geo = geo_check(A2);
    float h[NSTATE] = {};
    float sum_d = 0.f;

    __shared__ float sB[CHUNK][NSTATE];
    const short* dbc_mb = (const short*)dbc + (long)m * MROWS * 64 + (long)b * LSEQ * 64;
    const int t0 = chunk * CHUNK;
    for (int i = tid; i < CHUNK * NSTATE; i += 256) {
        int tt = i >> 4, j = i & 15;
        sB[tt][j] = bf2f(dbc_mb[(long)(t0 + tt) * 64 + 32 + j]);
    }
    __syncthreads();

    const short* dp = (const short*)delta;
    const short* up = (const short*)xc;
    const long base = ((long)mb * LSEQ + t0) * DINNER + c;
    if (geo) {
        #pragma unroll 4
        for (int tt = 0; tt < CHUNK; ++tt) {
            const float d = bf2f(dp[base + (long)tt * DINNER]);
            const float u = bf2f(up[base + (long)tt * DINNER]);
            const float du = d * u;
            sum_d += d;
            const float E = EXP2F(d * A2[0]);
            float e = 1.f;
            #pragma unroll
            for (int n = 0; n < NSTATE; ++n) {
                e *= E;
                h[n] = e * h[n] + du * sB[tt][n];
            }
        }
    } else {
        #pragma unroll 4
        for (int tt = 0; tt < CHUNK; ++tt) {
            const float d = bf2f(dp[base + (long)tt * DINNER]);
            const float u = bf2f(up[base + (long)tt * DINNER]);
            const float du = d * u;
            sum_d += d;
            #pragma unroll
            for (int n = 0; n < NSTATE; ++n) {
                float e = EXP2F(d * A2[n]);
                h[n] = e * h[n] + du * sB[tt][n];
            }
        }
    }
    const long ob = ((long)mb * NCHUNK + chunk) * (NSTATE * DINNER) + c;
    if (geo) {
        const float ED = EXP2F(sum_d * A2[0]);
        float e = 1.f;
        #pragma unroll
        for (int n = 0; n < NSTATE; ++n) {
            e *= ED;
            Fbuf[ob + n * DINNER] = h[n];
            Dbuf[ob + n * DINNER] = e;
        }
    } else {
        #pragma unroll
        for (int n = 0; n < NSTATE; ++n) {
            Fbuf[ob + n * DINNER] = h[n];
            Dbuf[ob + n * DINNER] = EXP2F(sum_d * A2[n]);
        }
    }
}

__global__ __launch_bounds__(256) void scan_pass2_kernel(float* __restrict__ Fbuf,
                                                         const float* __restrict__ Dbuf)
{
    const long idx = (long)blockIdx.x * 256 + threadIdx.x;  // < 6*16*1024
    const int mb = (int)(idx >> 14);
    const int cn = (int)(idx & 16383);
    float run = 0.f;
    for (int k = 0; k < NCHUNK; ++k) {
        const long o = ((long)(mb * NCHUNK + k) << 14) + cn;
        const float f = Fbuf[o];
        const float p = Dbuf[o];
        Fbuf[o] = run;
        run = p * run + f;
    }
}

__global__ __launch_bounds__(256) void scan_pass3_kernel(
    const __hip_bfloat16* __restrict__ delta, const __hip_bfloat16* __restrict__ xc,
    const __hip_bfloat16* __restrict__ dbc, __hip_bfloat16* __restrict__ xz,
    const float* __restrict__ A2T, const float* __restrict__ D_skip,
    const float* __restrict__ Hin)
{
    const int bx = blockIdx.x;
    const int chunk = bx & (NCHUNK - 1);
    const int cg = (bx >> 6) & 3;
    const int mb = bx >> 8;
    const int m = mb >> 1, b = mb & 1;
    const int tid = threadIdx.x;
    const int c = cg * 256 + tid;

    float A2[NSTATE];
    #pragma unroll
    for (int n = 0; n < NSTATE; ++n)
        A2[n] = A2T[((long)m * NSTATE + n) * DINNER + c];
    const bool geo = geo_check(A2);
    const float Dsk = D_skip[m * DINNER + c];

    float h[NSTATE];
    const long ho = ((long)mb * NCHUNK + chunk) * (NSTATE * DINNER) + c;
    #pragma unroll
    for (int n = 0; n < NSTATE; ++n) h[n] = Hin[ho + n * DINNER];

    __shared__ float sBC[CHUNK][2 * NSTATE];
    const short* dbc_mb = (const short*)dbc + (long)m * MROWS * 64 + (long)b * LSEQ * 64;
    const int t0 = chunk * CHUNK;
    for (int i = tid; i < CHUNK * 2 * NSTATE; i += 256) {
        int tt = i >> 5, j = i & 31;
        sBC[tt][j] = bf2f(dbc_mb[(long)(t0 + tt) * 64 + 32 + j]);
    }
    __syncthreads();

    const short* dp = (const short*)delta;
    const short* up = (const short*)xc;
    short* xzp = (short*)xz;
    const long base = ((long)mb * LSEQ + t0) * DINNER + c;
    const long xbase = ((long)mb * LSEQ + t0) * 2048 + c;
    if (geo) {
        #pragma unroll 4
        for (int tt = 0; tt < CHUNK; ++tt) {
            const long idx = base + (long)tt * DINNER;
            const long xi  = xbase + (long)tt * 2048;
            const float d = bf2f(dp[idx]);
            const float u = bf2f(up[idx]);
            const float zv = bf2f(xzp[xi + 1024]);
            const float du = d * u;
            const float E = EXP2F(d * A2[0]);
            float e = 1.f;
            float y = 0.f;
            #pragma unroll
            for (int n = 0; n < NSTATE; ++n) {
                e *= E;
                h[n] = e * h[n] + du * sBC[tt][n];
                y += h[n] * sBC[tt][16 + n];
            }
            y += u * Dsk;
            xzp[xi] = f2bf(y * (zv * sigmoid_f(zv)));
        }
    } else {
        #pragma unroll 4
        for (int tt = 0; tt < CHUNK; ++tt) {
            const long idx = base + (long)tt * DINNER;
            const long xi  = xbase + (long)tt * 2048;
            const float d = bf2f(dp[idx]);
            const float u = bf2f(up[idx]);
            const float zv = bf2f(xzp[xi + 1024]);
            const float du = d * u;
            float y = 0.f;
            #pragma unroll
            for (int n = 0; n < NSTATE; ++n) {
                float e = EXP2F(d * A2[n]);
                h[n] = e * h[n] + du * sBC[tt][n];
                y += h[n] * sBC[tt][16 + n];
            }
            y += u * Dsk;
            xzp[xi] = f2bf(y * (zv * sigmoid_f(zv)));
        }
    }
}

extern "C" void kernel_launch(void* const* d_in, const int* in_sizes, int n_in,
                              void* d_out, int out_size, void* d_ws, size_t ws_size,
                              hipStream_t stream)
{
    const float* v       = (const float*)d_in[0];
    const float* a       = (const float*)d_in[1];
    const float* t       = (const float*)d_in[2];
    const float* norm_w  = (const float*)d_in[3];
    const float* norm_b  = (const float*)d_in[4];
    const float* in_w    = (const float*)d_in[5];
    const float* conv_w  = (const float*)d_in[6];
    const float* conv_b  = (const float*)d_in[7];
    const float* xproj_w = (const float*)d_in[8];
    const float* dt_w    = (const float*)d_in[9];
    const float* dt_b    = (const float*)d_in[10];
    const float* A_log   = (const float*)d_in[11];
    const float* D_skip  = (const float*)d_in[12];
    const float* out_w   = (const float*)d_in[13];
    const float* couple_w= (const float*)d_in[14];
    const float* coef    = (const float*)d_in[15];
    float* out = (float*)d_out;

    typedef __hip_bfloat16 bf;
    float* x_in   = (float*)d_ws;                       // [3][4096][512] f32
    bf* xn_bf     = (bf*)(x_in + 6291456);              // [3][4096][512]
    bf* sec_bf    = xn_bf + 6291456;                    // [3][4096][512]
    bf* xz_bf     = sec_bf + 6291456;                   // [3][4096][2048]  (xc-pre | z; later y | z)
    bf* xc_bf     = xz_bf + 25165824;                   // [3][4096][1024]
    bf* delta_bf  = xc_bf + 12582912;                   // [3][4096][1024]
    bf* dbc_bf    = delta_bf + 12582912;                // [3][4096][64]
    bf* cw_bf     = dbc_bf + 786432;                    // [3][512][512]
    bf* inw_bf    = cw_bf + 786432;                     // [3][2048][512]
    bf* xpw_bf    = inw_bf + 3145728;                   // [3][64][1024]
    bf* dtw_bf    = xpw_bf + 196608;                    // [3][1024][32]
    bf* outw_bf   = dtw_bf + 98304;                     // [3][512][1024]
    float* cwT    = (float*)(outw_bf + 1572864);        // [3][4][1024] f32
    float* A2T    = cwT + 12288;                        // [3][16][1024] f32
    float* Fbuf   = A2T + 49152;                        // [6][64][16][1024] f32

    float* Dbuf = out;                                  // [6][64][16][1024] — exactly out_size

    dim3 blk(256);

    // 0. prep
    stack_vat_kernel<<<6144, blk, 0, stream>>>(v, a, t, x_in, sec_bf);
    cvt_all_kernel<<<(196608 + 786432 + 49152 + 24576 + 393216 + 255) / 256, blk, 0, stream>>>(
        couple_w, cw_bf, 196608, in_w, inw_bf, 786432, xproj_w, xpw_bf, 49152,
        dt_w, dtw_bf, 24576, out_w, outw_bf, 393216);
    small_prep_kernel<<<(12288 + 49152 + 255) / 256, blk, 0, stream>>>(conv_w, cwT, A_log, A2T);

    // 1. coupling: x_in += coef[z] * sec_bf @ cw^T  (NJ=4)
    gemm_bf16<4><<<dim3(4, 32, 3), blk, 0, stream>>>(
        (bf*)sec_bf, cw_bf, 512, 512, 512, 2097152L, 262144L,
        x_in, nullptr, 512, 2097152L, x_in, 2097152L, coef, 1, nullptr, 0L, 0);
    // 2. layernorm -> bf16
    ln_kernel<<<3*4096, blk, 0, stream>>>(x_in, xn_bf, norm_w, norm_b);
    // 3. in_proj (both halves, N=2048) -> xz  (NJ=8: wave tile 64x128)
    gemm_bf16<8><<<dim3(8, 32, 3), blk, 0, stream>>>(
        xn_bf, inw_bf, 512, 512, 512, 2097152L, 1048576L,
        nullptr, xz_bf, 2048, 8388608L, nullptr, 0L, nullptr, 0, nullptr, 0L, 0);
    // 4. conv + SiLU (reads xz cols 0..1023)
    conv_silu_kernel<<<768, blk, 0, stream>>>(xz_bf, cwT, conv_b, xc_bf);
    // 5. x_proj -> dbc bf16
    gemm_bf16<2><<<dim3(1, 32, 3), blk, 0, stream>>>(
        xc_bf, xpw_bf, 1024, 1024, 1024, 4194304L, 65536L,
        nullptr, dbc_bf, 64, 262144L, nullptr, 0L, nullptr, 0, nullptr, 0L, 0);
    // 6. delta = softplus(dt @ dt_w^T + dt_b) -> bf16
    gemm_bf16<4><<<dim3(8, 32, 3), blk, 0, stream>>>(
        dbc_bf, dtw_bf, 32, 64, 32, 262144L, 32768L,
        nullptr, delta_bf, 1024, 4194304L, nullptr, 0L, nullptr, 0, dt_b, 1024L, 1);
    // 7. chunk-parallel scan
    scan_pass1_kernel<<<6*4*NCHUNK, blk, 0, stream>>>(delta_bf, xc_bf, dbc_bf, A2T, Fbuf, Dbuf);
    scan_pass2_kernel<<<(6*1024*16)/256, blk, 0, stream>>>(Fbuf, Dbuf);
    scan_pass3_kernel<<<6*4*NCHUNK, blk, 0, stream>>>(delta_bf, xc_bf, dbc_bf, xz_bf,
                                                      A2T, D_skip, Fbuf);
    // 8. out_proj + residual -> d_out (NJ=4)
    gemm_bf16<4><<<dim3(4, 32, 3), blk, 0, stream>>>(
        xz_bf, outw_bf, 1024, 2048, 1024, 8388608L, 524288L,
        out, nullptr, 512, 2097152L, x_in, 2097152L, nullptr, 0, nullptr, 0L, 0);
}

// Round 11
// 310.523 us; speedup vs baseline: 1.1007x; 1.1007x over previous
//
#include <hip/hip_runtime.h>
#include <hip/hip_bf16.h>

#define MODS 3
#define BSZ 2
#define LSEQ 2048
#define DMODEL 512
#define DINNER 1024
#define DTRANK 32
#define NSTATE 16
#define DCONV 4
#define MROWS (BSZ*LSEQ)   // 4096
#define NCHUNK 64
#define CHUNK 32           // LSEQ / NCHUNK

#define LOG2E 1.44269504088896f
#define LN2   0.69314718055995f

typedef __attribute__((ext_vector_type(8))) short short8v;
typedef __attribute__((ext_vector_type(4))) short short4v;
typedef __attribute__((ext_vector_type(2))) short short2v;
typedef __attribute__((ext_vector_type(4))) float f32x4;

#if __has_builtin(__builtin_amdgcn_exp2f)
#define EXP2F __builtin_amdgcn_exp2f
#else
#define EXP2F exp2f
#endif
#if __has_builtin(__builtin_amdgcn_rcpf)
#define RCPF __builtin_amdgcn_rcpf
#else
#define RCPF(x) (1.0f / (x))
#endif

__device__ __forceinline__ short f2bf(float x) {
    __hip_bfloat16 h = __float2bfloat16(x);
    return __builtin_bit_cast(short, h);
}
__device__ __forceinline__ float bf2f(short s) {
    return __uint_as_float(((unsigned)(unsigned short)s) << 16);
}
__device__ __forceinline__ void gl_lds16(const short* g, short* l) {
    __builtin_amdgcn_global_load_lds(
        (const __attribute__((address_space(1))) unsigned int*)g,
        (__attribute__((address_space(3))) unsigned int*)l, 16, 0, 0);
}
__device__ __forceinline__ float sigmoid_f(float x) {
    return RCPF(1.f + EXP2F(-x * LOG2E));
}

// ---------------- bf16 MFMA GEMM NT, BK=32, XOR-swizzled LDS, 2-phase prefetch dbuf ----
// Tile 128 x (NJ*32), 4 waves 2x2. Grid: x = M-panel (fastest) so all N-tiles of
// a panel land on one XCD (id%8) -> A-panel L2 locality. y = N-tile, z = modality.
template<int NJ>
__global__ __launch_bounds__(256) void gemm_bf16(
    const __hip_bfloat16* __restrict__ A_, const __hip_bfloat16* __restrict__ B_,
    int K, int lda, int ldb, long sA, long sB,
    float* __restrict__ Cf, __hip_bfloat16* __restrict__ Cb, int ldc, long sC,
    const float* __restrict__ res, long sRes,
    const float* __restrict__ coef_base, int coef_stride,
    const float* __restrict__ bias, long sBias, int act)
{
    constexpr int BK = 32;
    constexpr int BN = NJ * 32;
    constexpr int ASZ = 128 * BK;
    constexpr int BSZe = BN * BK;
    __shared__ alignas(16) short As[2 * ASZ];
    __shared__ alignas(16) short Bs[2 * BSZe];
    const int z = blockIdx.z;
    const int bm0 = blockIdx.x * 128;     // panel-major: x is fastest-varying
    const int bn0 = blockIdx.y * BN;
    const short* Ag = (const short*)A_ + z * sA + (long)bm0 * lda;
    const short* Bg = (const short*)B_ + z * sB + (long)bn0 * ldb;
    const int tid = threadIdx.x;
    const int lane = tid & 63;
    const int w = tid >> 6;
    const int wr = w >> 1, wc = w & 1;
    const int lr = lane & 15;
    const int sidx = lane >> 4;
    const int srow = tid >> 2;
    const int sgcol = ((tid & 3) ^ ((srow >> 1) & 3)) * 8;
    const int fA = (lr >> 1) & 3;

    constexpr int AINSTR = ASZ / 2048;
    constexpr int BINSTR = BSZe / 2048;
    constexpr int RPI = 2048 / BK;

    f32x4 acc[4][NJ];
    #pragma unroll
    for (int i = 0; i < 4; ++i)
        #pragma unroll
        for (int j = 0; j < NJ; ++j)
            acc[i][j] = (f32x4){0.f, 0.f, 0.f, 0.f};

    auto stage = [&](int buf, int k0) {
        #pragma unroll
        for (int i = 0; i < AINSTR; ++i)
            gl_lds16(Ag + (long)(i * RPI + srow) * lda + k0 + sgcol,
                     As + buf * ASZ + i * 2048 + tid * 8);
        #pragma unroll
        for (int i = 0; i < BINSTR; ++i)
            gl_lds16(Bg + (long)(i * RPI + srow) * ldb + k0 + sgcol,
                     Bs + buf * BSZe + i * 2048 + tid * 8);
    };
    auto compute = [&](int buf) {
        const int sl = (sidx ^ fA) * 8;
        short8v af[4], bfr[NJ];
        #pragma unroll
        for (int i = 0; i < 4; ++i)
            af[i] = *(const short8v*)&As[buf * ASZ + (wr * 64 + i * 16 + lr) * BK + sl];
        #pragma unroll
        for (int j = 0; j < NJ; ++j)
            bfr[j] = *(const short8v*)&Bs[buf * BSZe + (wc * NJ * 16 + j * 16 + lr) * BK + sl];
        #pragma unroll
        for (int i = 0; i < 4; ++i)
            #pragma unroll
            for (int j = 0; j < NJ; ++j)
                acc[i][j] = __builtin_amdgcn_mfma_f32_16x16x32_bf16(af[i], bfr[j], acc[i][j], 0, 0, 0);
    };

    stage(0, 0);
    __syncthreads();
    int cur = 0;
    for (int k0 = BK; k0 < K; k0 += BK) {
        stage(cur ^ 1, k0);
        compute(cur);
        __syncthreads();
        cur ^= 1;
    }
    compute(cur);

    const float alpha = coef_base ? coef_base[z * coef_stride] : 1.0f;
    const float* resz = res ? res + z * sRes : nullptr;
    const float* biasz = bias ? bias + z * sBias : nullptr;
    float* Cfz = Cf ? Cf + z * sC : nullptr;
    __hip_bfloat16* Cbz = Cb ? Cb + z * sC : nullptr;
    #pragma unroll
    for (int i = 0; i < 4; ++i) {
        #pragma unroll
        for (int r = 0; r < 4; ++r) {
            const int row = bm0 + wr * 64 + i * 16 + (lane >> 4) * 4 + r;
            #pragma unroll
            for (int j = 0; j < NJ; ++j) {
                const int col = bn0 + wc * NJ * 16 + j * 16 + lr;
                float val = acc[i][j][r];
                if (biasz) val += biasz[col];
                if (act == 1)
                    val = (val > 20.f) ? val : LN2 * __log2f(1.f + EXP2F(val * LOG2E));
                val *= alpha;
                if (resz) val += resz[(long)row * ldc + col];
                if (Cfz) Cfz[(long)row * ldc + col] = val;
                else     Cbz[(long)row * ldc + col] = __float2bfloat16(val);
            }
        }
    }
}

// ---------------- sec conversions: sec_bf = [a;t;v] bf16 ----------------
// idx in float4 units: 3 modalities x 524288 float4 each.
__global__ __launch_bounds__(256) void sec_cvt_kernel(
    const float* __restrict__ a, const float* __restrict__ t, const float* __restrict__ v,
    __hip_bfloat16* __restrict__ sec_bf)
{
    const long idx = (long)blockIdx.x * 256 + threadIdx.x;   // < 3*524288
    const int m = (int)(idx >> 19);
    const long off = idx & 524287;
    const float* sec = (m == 0) ? a : (m == 1) ? t : v;
    float4 sv = ((const float4*)sec)[off];
    short4v s;
    s.x = f2bf(sv.x); s.y = f2bf(sv.y); s.z = f2bf(sv.z); s.w = f2bf(sv.w);
    ((short4v*)sec_bf)[idx] = s;
}

// ---------------- fused weight conversions: 5 segments f32 -> bf16 ----------------
__global__ __launch_bounds__(256) void cvt_all_kernel(
    const float* __restrict__ s0, __hip_bfloat16* __restrict__ d0, int n0,
    const float* __restrict__ s1, __hip_bfloat16* __restrict__ d1, int n1,
    const float* __restrict__ s2, __hip_bfloat16* __restrict__ d2, int n2,
    const float* __restrict__ s3, __hip_bfloat16* __restrict__ d3, int n3,
    const float* __restrict__ s4, __hip_bfloat16* __restrict__ d4, int n4)
{
    int idx = blockIdx.x * 256 + threadIdx.x;
    const float* s; __hip_bfloat16* d; int off = idx;
    if      (off < n0)                  { s = s0; d = d0; }
    else if ((off -= n0) < n1)          { s = s1; d = d1; }
    else if ((off -= n1) < n2)          { s = s2; d = d2; }
    else if ((off -= n2) < n3)          { s = s3; d = d3; }
    else if ((off -= n3) < n4)          { s = s4; d = d4; }
    else return;
    float4 vv = ((const float4*)s)[off];
    short4v o;
    o.x = f2bf(vv.x); o.y = f2bf(vv.y); o.z = f2bf(vv.z); o.w = f2bf(vv.w);
    ((short4v*)d)[off] = o;
}

// ---------------- small prep: conv-weight transpose + A2T ----------------
__global__ __launch_bounds__(256) void small_prep_kernel(const float* __restrict__ cw,
    float* __restrict__ cwT, const float* __restrict__ A_log, float* __restrict__ A2T)
{
    const int idx = blockIdx.x * 256 + threadIdx.x;
    if (idx < MODS * DINNER * DCONV) {
        const int k = idx & 3;
        const int c = (idx >> 2) & 1023;
        const int m = idx >> 12;
        cwT[(m * DCONV + k) * DINNER + c] = cw[idx];
    } else if (idx < MODS * DINNER * DCONV + MODS * NSTATE * DINNER) {
        const int j = idx - MODS * DINNER * DCONV;
        const int c = j & 1023;
        const int n = (j >> 10) & 15;
        const int m = j >> 14;
        A2T[j] = -EXP2F(A_log[((long)m * DINNER + c) * NSTATE + n] * LOG2E) * LOG2E;
    }
}

// ---------------- LayerNorm: f32 in -> bf16 out ----------------
__global__ __launch_bounds__(256) void ln_kernel(const float* __restrict__ x, __hip_bfloat16* __restrict__ xn,
                                                 const float* __restrict__ nw, const float* __restrict__ nb)
{
    const int row = blockIdx.x;
    const int m = row >> 12;
    const int tid = threadIdx.x;
    const float2 v = *reinterpret_cast<const float2*>(x + (long)row * DMODEL + tid * 2);
    float s = v.x + v.y;
    float sq = v.x * v.x + v.y * v.y;
    #pragma unroll
    for (int off = 32; off > 0; off >>= 1) {
        s  += __shfl_down(s, off);
        sq += __shfl_down(sq, off);
    }
    __shared__ float ws_s[4], ws_q[4];
    const int wid = tid >> 6, lane = tid & 63;
    if (lane == 0) { ws_s[wid] = s; ws_q[wid] = sq; }
    __syncthreads();
    if (tid == 0) {
        float ts = ws_s[0] + ws_s[1] + ws_s[2] + ws_s[3];
        float tq = ws_q[0] + ws_q[1] + ws_q[2] + ws_q[3];
        float mu = ts / DMODEL;
        float var = tq / DMODEL - mu * mu;
        ws_s[0] = mu;
        ws_q[0] = rsqrtf(var + 1e-5f);
    }
    __syncthreads();
    const float mu = ws_s[0], rstd = ws_q[0];
    const int e0 = tid * 2;
    float2 w  = *reinterpret_cast<const float2*>(nw + m * DMODEL + e0);
    float2 bb = *reinterpret_cast<const float2*>(nb + m * DMODEL + e0);
    short2v o;
    o.x = f2bf((v.x - mu) * rstd * w.x + bb.x);
    o.y = f2bf((v.y - mu) * rstd * w.y + bb.y);
    *reinterpret_cast<short2v*>((short*)xn + (long)row * DMODEL + e0) = o;
}

// ---------------- depthwise causal conv(4) + SiLU ----------------
__global__ __launch_bounds__(256) void conv_silu_kernel(const __hip_bfloat16* __restrict__ xz,
    const float* __restrict__ cwT, const float* __restrict__ cb, __hip_bfloat16* __restrict__ xc)
{
    const int idx = blockIdx.x * 256 + threadIdx.x;   // < 6*256*128 = 196608
    const int c8 = idx & 127;
    const int lt = (idx >> 7) & 255;
    const int mb = idx >> 15;
    const int m  = mb >> 1;
    const int c0 = c8 * 8;
    const int l0 = lt * 8;

    float4 wlo[DCONV], whi[DCONV];
    #pragma unroll
    for (int k = 0; k < DCONV; ++k) {
        wlo[k] = *(const float4*)&cwT[(m * DCONV + k) * DINNER + c0];
        whi[k] = *(const float4*)&cwT[(m * DCONV + k) * DINNER + c0 + 4];
    }
    const float4 blo = *(const float4*)&cb[m * DINNER + c0];
    const float4 bhi = *(const float4*)&cb[m * DINNER + c0 + 4];

    const short* base = (const short*)xz + (long)mb * LSEQ * 2048 + c0;
    short* obase = (short*)xc + (long)mb * LSEQ * DINNER + c0;

    short8v r0 = {}, r1 = {}, r2 = {};
    if (l0 - 3 >= 0) r0 = *(const short8v*)(base + (long)(l0 - 3) * 2048);
    if (l0 - 2 >= 0) r1 = *(const short8v*)(base + (long)(l0 - 2) * 2048);
    if (l0 - 1 >= 0) r2 = *(const short8v*)(base + (long)(l0 - 1) * 2048);

    #pragma unroll
    for (int i = 0; i < 8; ++i) {
        const short8v cur = *(const short8v*)(base + (long)(l0 + i) * 2048);
        float acc[8];
        #pragma unroll
        for (int j = 0; j < 4; ++j) {
            acc[j]     = ((const float*)&blo)[j];
            acc[4 + j] = ((const float*)&bhi)[j];
        }
        #pragma unroll
        for (int j = 0; j < 8; ++j) {
            const float w0 = (j < 4) ? ((const float*)&wlo[0])[j] : ((const float*)&whi[0])[j - 4];
            const float w1 = (j < 4) ? ((const float*)&wlo[1])[j] : ((const float*)&whi[1])[j - 4];
            const float w2 = (j < 4) ? ((const float*)&wlo[2])[j] : ((const float*)&whi[2])[j - 4];
            const float w3 = (j < 4) ? ((const float*)&wlo[3])[j] : ((const float*)&whi[3])[j - 4];
            acc[j] += w0 * bf2f(r0[j]) + w1 * bf2f(r1[j]) + w2 * bf2f(r2[j]) + w3 * bf2f(cur[j]);
        }
        short8v o;
        #pragma unroll
        for (int j = 0; j < 8; ++j)
            o[j] = f2bf(acc[j] * sigmoid_f(acc[j]));
        *(short8v*)(obase + (long)(l0 + i) * DINNER) = o;
        r0 = r1; r1 = r2; r2 = cur;
    }
}

// ---------------- chunk-parallel selective scan (bf16 activations) ----------------
__device__ __forceinline__ bool geo_check(const float* A2) {
    bool g = true;
    #pragma unroll
    for (int n = 1; n < NSTATE; ++n)
        g = g && (__builtin_fabsf(A2[n] - (float)(n + 1) * A2[0]) <= 1e-4f * __builtin_fabsf(A2[n]));
    return g;
}

__global__ __launch_bounds__(256) void scan_pass1_kernel(
    const __hip_bfloat16* __restrict__ delta, const __hip_bfloat16* __restrict__ xc,
    const __hip_bfloat16* __restrict__ dbc, const float* __restrict__ A2T,
    float* __restrict__ Fbuf, float* __restrict__ Dbuf)
{
    const int bx = blockIdx.x;             // mb(6) x cg(4) x chunk(64)
    const int chunk = bx & (NCHUNK - 1);
    const int cg = (bx >> 6) & 3;
    const int mb = bx >> 8;
    const int m = mb >> 1, b = mb & 1;
    const int tid = threadIdx.x;
    const int c = cg * 256 + tid;

    float A2[NSTATE];
    #pragma unroll
    for (int n = 0; n < NSTATE; ++n)
        A2[n] = A2T[((long)m * NSTATE + n) * DINNER + c];
    const bool geo = geo_check(A2);
    float h[NSTATE] = {};
    float sum_d = 0.f;

    __shared__ float sB[CHUNK][NSTATE];
    const short* dbc_mb = (const short*)dbc + (long)m * MROWS * 64 + (long)b * LSEQ * 64;
    const int t0 = chunk * CHUNK;
    for (int i = tid; i < CHUNK * NSTATE; i += 256) {
        int tt = i >> 4, j = i & 15;
        sB[tt][j] = bf2f(dbc_mb[(long)(t0 + tt) * 64 + 32 + j]);
    }
    __syncthreads();

    const short* dp = (const short*)delta;
    const short* up = (const short*)xc;
    const long base = ((long)mb * LSEQ + t0) * DINNER + c;
    if (geo) {
        #pragma unroll 4
        for (int tt = 0; tt < CHUNK; ++tt) {
            const float d = bf2f(dp[base + (long)tt * DINNER]);
            const float u = bf2f(up[base + (long)tt * DINNER]);
            const float du = d * u;
            sum_d += d;
            const float E = EXP2F(d * A2[0]);
            float e = 1.f;
            #pragma unroll
            for (int n = 0; n < NSTATE; ++n) {
                e *= E;
                h[n] = e * h[n] + du * sB[tt][n];
            }
        }
    } else {
        #pragma unroll 4
        for (int tt = 0; tt < CHUNK; ++tt) {
            const float d = bf2f(dp[base + (long)tt * DINNER]);
            const float u = bf2f(up[base + (long)tt * DINNER]);
            const float du = d * u;
            sum_d += d;
            #pragma unroll
            for (int n = 0; n < NSTATE; ++n) {
                float e = EXP2F(d * A2[n]);
                h[n] = e * h[n] + du * sB[tt][n];
            }
        }
    }
    const long ob = ((long)mb * NCHUNK + chunk) * (NSTATE * DINNER) + c;
    if (geo) {
        const float ED = EXP2F(sum_d * A2[0]);
        float e = 1.f;
        #pragma unroll
        for (int n = 0; n < NSTATE; ++n) {
            e *= ED;
            Fbuf[ob + n * DINNER] = h[n];
            Dbuf[ob + n * DINNER] = e;
        }
    } else {
        #pragma unroll
        for (int n = 0; n < NSTATE; ++n) {
            Fbuf[ob + n * DINNER] = h[n];
            Dbuf[ob + n * DINNER] = EXP2F(sum_d * A2[n]);
        }
    }
}

__global__ __launch_bounds__(256) void scan_pass2_kernel(float* __restrict__ Fbuf,
                                                         const float* __restrict__ Dbuf)
{
    const long idx = (long)blockIdx.x * 256 + threadIdx.x;  // < 6*16*1024
    const int mb = (int)(idx >> 14);
    const int cn = (int)(idx & 16383);
    float run = 0.f;
    #pragma unroll 4
    for (int k = 0; k < NCHUNK; ++k) {
        const long o = ((long)(mb * NCHUNK + k) << 14) + cn;
        const float f = Fbuf[o];
        const float p = Dbuf[o];
        Fbuf[o] = run;
        run = p * run + f;
    }
}

__global__ __launch_bounds__(256) void scan_pass3_kernel(
    const __hip_bfloat16* __restrict__ delta, const __hip_bfloat16* __restrict__ xc,
    const __hip_bfloat16* __restrict__ dbc, __hip_bfloat16* __restrict__ xz,
    const float* __restrict__ A2T, const float* __restrict__ D_skip,
    const float* __restrict__ Hin)
{
    const int bx = blockIdx.x;
    const int chunk = bx & (NCHUNK - 1);
    const int cg = (bx >> 6) & 3;
    const int mb = bx >> 8;
    const int m = mb >> 1, b = mb & 1;
    const int tid = threadIdx.x;
    const int c = cg * 256 + tid;

    float A2[NSTATE];
    #pragma unroll
    for (int n = 0; n < NSTATE; ++n)
        A2[n] = A2T[((long)m * NSTATE + n) * DINNER + c];
    const bool geo = geo_check(A2);
    const float Dsk = D_skip[m * DINNER + c];

    float h[NSTATE];
    const long ho = ((long)mb * NCHUNK + chunk) * (NSTATE * DINNER) + c;
    #pragma unroll
    for (int n = 0; n < NSTATE; ++n) h[n] = Hin[ho + n * DINNER];

    __shared__ float sBC[CHUNK][2 * NSTATE];
    const short* dbc_mb = (const short*)dbc + (long)m * MROWS * 64 + (long)b * LSEQ * 64;
    const int t0 = chunk * CHUNK;
    for (int i = tid; i < CHUNK * 2 * NSTATE; i += 256) {
        int tt = i >> 5, j = i & 31;
        sBC[tt][j] = bf2f(dbc_mb[(long)(t0 + tt) * 64 + 32 + j]);
    }
    __syncthreads();

    const short* dp = (const short*)delta;
    const short* up = (const short*)xc;
    short* xzp = (short*)xz;
    const long base = ((long)mb * LSEQ + t0) * DINNER + c;
    const long xbase = ((long)mb * LSEQ + t0) * 2048 + c;
    if (geo) {
        #pragma unroll 4
        for (int tt = 0; tt < CHUNK; ++tt) {
            const long idx = base + (long)tt * DINNER;
            const long xi  = xbase + (long)tt * 2048;
            const float d = bf2f(dp[idx]);
            const float u = bf2f(up[idx]);
            const float zv = bf2f(xzp[xi + 1024]);
            const float du = d * u;
            const float E = EXP2F(d * A2[0]);
            float e = 1.f;
            float y = 0.f;
            #pragma unroll
            for (int n = 0; n < NSTATE; ++n) {
                e *= E;
                h[n] = e * h[n] + du * sBC[tt][n];
                y += h[n] * sBC[tt][16 + n];
            }
            y += u * Dsk;
            xzp[xi] = f2bf(y * (zv * sigmoid_f(zv)));
        }
    } else {
        #pragma unroll 4
        for (int tt = 0; tt < CHUNK; ++tt) {
            const long idx = base + (long)tt * DINNER;
            const long xi  = xbase + (long)tt * 2048;
            const float d = bf2f(dp[idx]);
            const float u = bf2f(up[idx]);
            const float zv = bf2f(xzp[xi + 1024]);
            const float du = d * u;
            float y = 0.f;
            #pragma unroll
            for (int n = 0; n < NSTATE; ++n) {
                float e = EXP2F(d * A2[n]);
                h[n] = e * h[n] + du * sBC[tt][n];
                y += h[n] * sBC[tt][16 + n];
            }
            y += u * Dsk;
            xzp[xi] = f2bf(y * (zv * sigmoid_f(zv)));
        }
    }
}

extern "C" void kernel_launch(void* const* d_in, const int* in_sizes, int n_in,
                              void* d_out, int out_size, void* d_ws, size_t ws_size,
                              hipStream_t stream)
{
    const float* v       = (const float*)d_in[0];
    const float* a       = (const float*)d_in[1];
    const float* t       = (const float*)d_in[2];
    const float* norm_w  = (const float*)d_in[3];
    const float* norm_b  = (const float*)d_in[4];
    const float* in_w    = (const float*)d_in[5];
    const float* conv_w  = (const float*)d_in[6];
    const float* conv_b  = (const float*)d_in[7];
    const float* xproj_w = (const float*)d_in[8];
    const float* dt_w    = (const float*)d_in[9];
    const float* dt_b    = (const float*)d_in[10];
    const float* A_log   = (const float*)d_in[11];
    const float* D_skip  = (const float*)d_in[12];
    const float* out_w   = (const float*)d_in[13];
    const float* couple_w= (const float*)d_in[14];
    const float* coef    = (const float*)d_in[15];
    float* out = (float*)d_out;

    typedef __hip_bfloat16 bf;
    float* x_in   = (float*)d_ws;                       // [3][4096][512] f32
    bf* xn_bf     = (bf*)(x_in + 6291456);              // [3][4096][512]
    bf* sec_bf    = xn_bf + 6291456;                    // [3][4096][512]
    bf* xz_bf     = sec_bf + 6291456;                   // [3][4096][2048]  (xc-pre | z; later y | z)
    bf* xc_bf     = xz_bf + 25165824;                   // [3][4096][1024]
    bf* delta_bf  = xc_bf + 12582912;                   // [3][4096][1024]
    bf* dbc_bf    = delta_bf + 12582912;                // [3][4096][64]
    bf* cw_bf     = dbc_bf + 786432;                    // [3][512][512]
    bf* inw_bf    = cw_bf + 786432;                     // [3][2048][512]
    bf* xpw_bf    = inw_bf + 3145728;                   // [3][64][1024]
    bf* dtw_bf    = xpw_bf + 196608;                    // [3][1024][32]
    bf* outw_bf   = dtw_bf + 98304;                     // [3][512][1024]
    float* cwT    = (float*)(outw_bf + 1572864);        // [3][4][1024] f32
    float* A2T    = cwT + 12288;                        // [3][16][1024] f32
    float* Fbuf   = A2T + 49152;                        // [6][64][16][1024] f32

    float* Dbuf = out;                                  // [6][64][16][1024] — exactly out_size

    dim3 blk(256);

    // 0. prep: sec->bf16 (3*524288 float4), weight conversions, conv-wT/A2T
    sec_cvt_kernel<<<6144, blk, 0, stream>>>(a, t, v, sec_bf);
    cvt_all_kernel<<<(196608 + 786432 + 49152 + 24576 + 393216 + 255) / 256, blk, 0, stream>>>(
        couple_w, cw_bf, 196608, in_w, inw_bf, 786432, xproj_w, xpw_bf, 49152,
        dt_w, dtw_bf, 24576, out_w, outw_bf, 393216);
    small_prep_kernel<<<(12288 + 49152 + 255) / 256, blk, 0, stream>>>(conv_w, cwT, A_log, A2T);

    // 1. coupling: x_in[m] = prim[m] + coef[m] * sec_bf[m] @ cw[m]^T (res read directly)
    const float* prim[3] = {v, a, t};
    for (int mI = 0; mI < 3; ++mI) {
        gemm_bf16<2><<<dim3(32, 8, 1), blk, 0, stream>>>(
            sec_bf + (long)mI * 2097152, cw_bf + (long)mI * 262144, 512, 512, 512, 0L, 0L,
            x_in + (long)mI * 2097152, nullptr, 512, 0L,
            prim[mI], 0L, coef + mI, 0, nullptr, 0L, 0);
    }
    // 2. layernorm -> bf16
    ln_kernel<<<3*4096, blk, 0, stream>>>(x_in, xn_bf, norm_w, norm_b);
    // 3. in_proj (both halves, N=2048) -> xz  (NJ=4, panel-major grid)
    gemm_bf16<4><<<dim3(32, 16, 3), blk, 0, stream>>>(
        xn_bf, inw_bf, 512, 512, 512, 2097152L, 1048576L,
        nullptr, xz_bf, 2048, 8388608L, nullptr, 0L, nullptr, 0, nullptr, 0L, 0);
    // 4. conv + SiLU (reads xz cols 0..1023)
    conv_silu_kernel<<<768, blk, 0, stream>>>(xz_bf, cwT, conv_b, xc_bf);
    // 5. x_proj -> dbc bf16
    gemm_bf16<2><<<dim3(32, 1, 3), blk, 0, stream>>>(
        xc_bf, xpw_bf, 1024, 1024, 1024, 4194304L, 65536L,
        nullptr, dbc_bf, 64, 262144L, nullptr, 0L, nullptr, 0, nullptr, 0L, 0);
    // 6. delta = softplus(dt @ dt_w^T + dt_b) -> bf16
    gemm_bf16<4><<<dim3(32, 8, 3), blk, 0, stream>>>(
        dbc_bf, dtw_bf, 32, 64, 32, 262144L, 32768L,
        nullptr, delta_bf, 1024, 4194304L, nullptr, 0L, nullptr, 0, dt_b, 1024L, 1);
    // 7. chunk-parallel scan
    scan_pass1_kernel<<<6*4*NCHUNK, blk, 0, stream>>>(delta_bf, xc_bf, dbc_bf, A2T, Fbuf, Dbuf);
    scan_pass2_kernel<<<(6*1024*16)/256, blk, 0, stream>>>(Fbuf, Dbuf);
    scan_pass3_kernel<<<6*4*NCHUNK, blk, 0, stream>>>(delta_bf, xc_bf, dbc_bf, xz_bf,
                                                      A2T, D_skip, Fbuf);
    // 8. out_proj + residual -> d_out (NJ=2, panel-major grid)
    gemm_bf16<2><<<dim3(32, 8, 3), blk, 0, stream>>>(
        xz_bf, outw_bf, 1024, 2048, 1024, 8388608L, 524288L,
        out, nullptr, 512, 2097152L, x_in, 2097152L, nullptr, 0, nullptr, 0L, 0);
}

// Round 12
// 308.822 us; speedup vs baseline: 1.1068x; 1.0055x over previous
//
#include <hip/hip_runtime.h>
#include <hip/hip_bf16.h>

#define MODS 3
#define BSZ 2
#define LSEQ 2048
#define DMODEL 512
#define DINNER 1024
#define DTRANK 32
#define NSTATE 16
#define DCONV 4
#define MROWS (BSZ*LSEQ)   // 4096
#define NCHUNK 64
#define CHUNK 32           // LSEQ / NCHUNK

#define LOG2E 1.44269504088896f
#define LN2   0.69314718055995f

typedef __attribute__((ext_vector_type(8))) short short8v;
typedef __attribute__((ext_vector_type(4))) short short4v;
typedef __attribute__((ext_vector_type(2))) short short2v;
typedef __attribute__((ext_vector_type(4))) float f32x4;

#if __has_builtin(__builtin_amdgcn_exp2f)
#define EXP2F __builtin_amdgcn_exp2f
#else
#define EXP2F exp2f
#endif
#if __has_builtin(__builtin_amdgcn_rcpf)
#define RCPF __builtin_amdgcn_rcpf
#else
#define RCPF(x) (1.0f / (x))
#endif

__device__ __forceinline__ short f2bf(float x) {
    __hip_bfloat16 h = __float2bfloat16(x);
    return __builtin_bit_cast(short, h);
}
__device__ __forceinline__ float bf2f(short s) {
    return __uint_as_float(((unsigned)(unsigned short)s) << 16);
}
__device__ __forceinline__ void gl_lds16(const short* g, short* l) {
    __builtin_amdgcn_global_load_lds(
        (const __attribute__((address_space(1))) unsigned int*)g,
        (__attribute__((address_space(3))) unsigned int*)l, 16, 0, 0);
}
__device__ __forceinline__ float sigmoid_f(float x) {
    return RCPF(1.f + EXP2F(-x * LOG2E));
}

// ---------------- bf16 MFMA GEMM NT, XOR-swizzled LDS, 2-phase prefetch dbuf ----------
// Tile 128 x (NJ*32), 4 waves 2x2. BK=64 (rows 128B, slot^=row&7 swizzle) halves the
// per-K barrier drains vs BK=32 and doubles compute per drain; dbuf keeps the
// stage(next)-before-compute(cur) overlap. BK=32 path retained for K=32 (dt GEMM).
// Grid: x = M-panel (fastest) for XCD A-panel L2 locality; y = N-tile, z = modality.
template<int NJ, int BK>
__global__ __launch_bounds__(256) void gemm_bf16(
    const __hip_bfloat16* __restrict__ A_, const __hip_bfloat16* __restrict__ B_,
    int K, int lda, int ldb, long sA, long sB,
    float* __restrict__ Cf, __hip_bfloat16* __restrict__ Cb, int ldc, long sC,
    const float* __restrict__ res, long sRes,
    const float* __restrict__ coef_base, int coef_stride,
    const float* __restrict__ bias, long sBias, int act)
{
    constexpr int BN = NJ * 32;
    constexpr int ASZ = 128 * BK;
    constexpr int BSZe = BN * BK;
    __shared__ alignas(16) short As[2 * ASZ];
    __shared__ alignas(16) short Bs[2 * BSZe];
    const int z = blockIdx.z;
    const int bm0 = blockIdx.x * 128;
    const int bn0 = blockIdx.y * BN;
    const short* Ag = (const short*)A_ + z * sA + (long)bm0 * lda;
    const short* Bg = (const short*)B_ + z * sB + (long)bn0 * ldb;
    const int tid = threadIdx.x;
    const int lane = tid & 63;
    const int w = tid >> 6;
    const int wr = w >> 1, wc = w & 1;
    const int lr = lane & 15;
    const int sidx = lane >> 4;                       // 16B slot group within K=32

    // staging decomposition: per gl_lds instr 256 lanes x 16B = 2048 elems
    constexpr int SLOTS = BK / 8;                     // 16B slots per LDS row
    const int srow = tid / SLOTS;                     // row within instr chunk
    const int sslot = tid % SLOTS;
    int swz;
    if constexpr (BK == 64) swz = srow & 7;           // 128B rows: 8-slot XOR
    else                    swz = (srow >> 1) & 3;    // 64B rows: 4-slot XOR
    const int sgcol = (sslot ^ swz) * 8;              // swizzled global elem col
    int fA;
    if constexpr (BK == 64) fA = lr & 7;
    else                    fA = (lr >> 1) & 3;

    constexpr int AINSTR = ASZ / 2048;                // BK=64: 4, BK=32: 2
    constexpr int BINSTR = BSZe / 2048;
    constexpr int RPI = 2048 / BK;                    // rows per instr

    f32x4 acc[4][NJ];
    #pragma unroll
    for (int i = 0; i < 4; ++i)
        #pragma unroll
        for (int j = 0; j < NJ; ++j)
            acc[i][j] = (f32x4){0.f, 0.f, 0.f, 0.f};

    auto stage = [&](int buf, int k0) {
        #pragma unroll
        for (int i = 0; i < AINSTR; ++i)
            gl_lds16(Ag + (long)(i * RPI + srow) * lda + k0 + sgcol,
                     As + buf * ASZ + i * 2048 + tid * 8);
        #pragma unroll
        for (int i = 0; i < BINSTR; ++i)
            gl_lds16(Bg + (long)(i * RPI + srow) * ldb + k0 + sgcol,
                     Bs + buf * BSZe + i * 2048 + tid * 8);
    };
    auto compute = [&](int buf) {
        #pragma unroll
        for (int kh = 0; kh < BK / 32; ++kh) {
            const int sl = ((kh * 4 + sidx) ^ fA) * 8;
            short8v af[4], bfr[NJ];
            #pragma unroll
            for (int i = 0; i < 4; ++i)
                af[i] = *(const short8v*)&As[buf * ASZ + (wr * 64 + i * 16 + lr) * BK + sl];
            #pragma unroll
            for (int j = 0; j < NJ; ++j)
                bfr[j] = *(const short8v*)&Bs[buf * BSZe + (wc * NJ * 16 + j * 16 + lr) * BK + sl];
            #pragma unroll
            for (int i = 0; i < 4; ++i)
                #pragma unroll
                for (int j = 0; j < NJ; ++j)
                    acc[i][j] = __builtin_amdgcn_mfma_f32_16x16x32_bf16(af[i], bfr[j], acc[i][j], 0, 0, 0);
        }
    };

    stage(0, 0);
    __syncthreads();
    int cur = 0;
    for (int k0 = BK; k0 < K; k0 += BK) {
        stage(cur ^ 1, k0);        // prefetch next tile (in flight during compute)
        compute(cur);
        __syncthreads();           // drains vmcnt+lgkmcnt -> next tile ready
        cur ^= 1;
    }
    compute(cur);

    const float alpha = coef_base ? coef_base[z * coef_stride] : 1.0f;
    const float* resz = res ? res + z * sRes : nullptr;
    const float* biasz = bias ? bias + z * sBias : nullptr;
    float* Cfz = Cf ? Cf + z * sC : nullptr;
    __hip_bfloat16* Cbz = Cb ? Cb + z * sC : nullptr;
    #pragma unroll
    for (int i = 0; i < 4; ++i) {
        #pragma unroll
        for (int r = 0; r < 4; ++r) {
            const int row = bm0 + wr * 64 + i * 16 + (lane >> 4) * 4 + r;
            #pragma unroll
            for (int j = 0; j < NJ; ++j) {
                const int col = bn0 + wc * NJ * 16 + j * 16 + lr;
                float val = acc[i][j][r];
                if (biasz) val += biasz[col];
                if (act == 1)
                    val = (val > 20.f) ? val : LN2 * __log2f(1.f + EXP2F(val * LOG2E));
                val *= alpha;
                if (resz) val += resz[(long)row * ldc + col];
                if (Cfz) Cfz[(long)row * ldc + col] = val;
                else     Cbz[(long)row * ldc + col] = __float2bfloat16(val);
            }
        }
    }
}

// ---------------- sec conversions: sec_bf = [a;t;v] bf16 ----------------
__global__ __launch_bounds__(256) void sec_cvt_kernel(
    const float* __restrict__ a, const float* __restrict__ t, const float* __restrict__ v,
    __hip_bfloat16* __restrict__ sec_bf)
{
    const long idx = (long)blockIdx.x * 256 + threadIdx.x;   // < 3*524288 float4
    const int m = (int)(idx >> 19);
    const long off = idx & 524287;
    const float* sec = (m == 0) ? a : (m == 1) ? t : v;
    float4 sv = ((const float4*)sec)[off];
    short4v s;
    s.x = f2bf(sv.x); s.y = f2bf(sv.y); s.z = f2bf(sv.z); s.w = f2bf(sv.w);
    ((short4v*)sec_bf)[idx] = s;
}

// ---------------- fused weight conversions: 5 segments f32 -> bf16 ----------------
__global__ __launch_bounds__(256) void cvt_all_kernel(
    const float* __restrict__ s0, __hip_bfloat16* __restrict__ d0, int n0,
    const float* __restrict__ s1, __hip_bfloat16* __restrict__ d1, int n1,
    const float* __restrict__ s2, __hip_bfloat16* __restrict__ d2, int n2,
    const float* __restrict__ s3, __hip_bfloat16* __restrict__ d3, int n3,
    const float* __restrict__ s4, __hip_bfloat16* __restrict__ d4, int n4)
{
    int idx = blockIdx.x * 256 + threadIdx.x;
    const float* s; __hip_bfloat16* d; int off = idx;
    if      (off < n0)                  { s = s0; d = d0; }
    else if ((off -= n0) < n1)          { s = s1; d = d1; }
    else if ((off -= n1) < n2)          { s = s2; d = d2; }
    else if ((off -= n2) < n3)          { s = s3; d = d3; }
    else if ((off -= n3) < n4)          { s = s4; d = d4; }
    else return;
    float4 vv = ((const float4*)s)[off];
    short4v o;
    o.x = f2bf(vv.x); o.y = f2bf(vv.y); o.z = f2bf(vv.z); o.w = f2bf(vv.w);
    ((short4v*)d)[off] = o;
}

// ---------------- small prep: conv-weight transpose + A2T ----------------
__global__ __launch_bounds__(256) void small_prep_kernel(const float* __restrict__ cw,
    float* __restrict__ cwT, const float* __restrict__ A_log, float* __restrict__ A2T)
{
    const int idx = blockIdx.x * 256 + threadIdx.x;
    if (idx < MODS * DINNER * DCONV) {
        const int k = idx & 3;
        const int c = (idx >> 2) & 1023;
        const int m = idx >> 12;
        cwT[(m * DCONV + k) * DINNER + c] = cw[idx];
    } else if (idx < MODS * DINNER * DCONV + MODS * NSTATE * DINNER) {
        const int j = idx - MODS * DINNER * DCONV;
        const int c = j & 1023;
        const int n = (j >> 10) & 15;
        const int m = j >> 14;
        A2T[j] = -EXP2F(A_log[((long)m * DINNER + c) * NSTATE + n] * LOG2E) * LOG2E;
    }
}

// ---------------- LayerNorm: f32 in -> bf16 out ----------------
__global__ __launch_bounds__(256) void ln_kernel(const float* __restrict__ x, __hip_bfloat16* __restrict__ xn,
                                                 const float* __restrict__ nw, const float* __restrict__ nb)
{
    const int row = blockIdx.x;
    const int m = row >> 12;
    const int tid = threadIdx.x;
    const float2 v = *reinterpret_cast<const float2*>(x + (long)row * DMODEL + tid * 2);
    float s = v.x + v.y;
    float sq = v.x * v.x + v.y * v.y;
    #pragma unroll
    for (int off = 32; off > 0; off >>= 1) {
        s  += __shfl_down(s, off);
        sq += __shfl_down(sq, off);
    }
    __shared__ float ws_s[4], ws_q[4];
    const int wid = tid >> 6, lane = tid & 63;
    if (lane == 0) { ws_s[wid] = s; ws_q[wid] = sq; }
    __syncthreads();
    if (tid == 0) {
        float ts = ws_s[0] + ws_s[1] + ws_s[2] + ws_s[3];
        float tq = ws_q[0] + ws_q[1] + ws_q[2] + ws_q[3];
        float mu = ts / DMODEL;
        float var = tq / DMODEL - mu * mu;
        ws_s[0] = mu;
        ws_q[0] = rsqrtf(var + 1e-5f);
    }
    __syncthreads();
    const float mu = ws_s[0], rstd = ws_q[0];
    const int e0 = tid * 2;
    float2 w  = *reinterpret_cast<const float2*>(nw + m * DMODEL + e0);
    float2 bb = *reinterpret_cast<const float2*>(nb + m * DMODEL + e0);
    short2v o;
    o.x = f2bf((v.x - mu) * rstd * w.x + bb.x);
    o.y = f2bf((v.y - mu) * rstd * w.y + bb.y);
    *reinterpret_cast<short2v*>((short*)xn + (long)row * DMODEL + e0) = o;
}

// ---------------- depthwise causal conv(4) + SiLU ----------------
__global__ __launch_bounds__(256) void conv_silu_kernel(const __hip_bfloat16* __restrict__ xz,
    const float* __restrict__ cwT, const float* __restrict__ cb, __hip_bfloat16* __restrict__ xc)
{
    const int idx = blockIdx.x * 256 + threadIdx.x;   // < 6*256*128 = 196608
    const int c8 = idx & 127;
    const int lt = (idx >> 7) & 255;
    const int mb = idx >> 15;
    const int m  = mb >> 1;
    const int c0 = c8 * 8;
    const int l0 = lt * 8;

    float4 wlo[DCONV], whi[DCONV];
    #pragma unroll
    for (int k = 0; k < DCONV; ++k) {
        wlo[k] = *(const float4*)&cwT[(m * DCONV + k) * DINNER + c0];
        whi[k] = *(const float4*)&cwT[(m * DCONV + k) * DINNER + c0 + 4];
    }
    const float4 blo = *(const float4*)&cb[m * DINNER + c0];
    const float4 bhi = *(const float4*)&cb[m * DINNER + c0 + 4];

    const short* base = (const short*)xz + (long)mb * LSEQ * 2048 + c0;
    short* obase = (short*)xc + (long)mb * LSEQ * DINNER + c0;

    short8v r0 = {}, r1 = {}, r2 = {};
    if (l0 - 3 >= 0) r0 = *(const short8v*)(base + (long)(l0 - 3) * 2048);
    if (l0 - 2 >= 0) r1 = *(const short8v*)(base + (long)(l0 - 2) * 2048);
    if (l0 - 1 >= 0) r2 = *(const short8v*)(base + (long)(l0 - 1) * 2048);

    #pragma unroll
    for (int i = 0; i < 8; ++i) {
        const short8v cur = *(const short8v*)(base + (long)(l0 + i) * 2048);
        float acc[8];
        #pragma unroll
        for (int j = 0; j < 4; ++j) {
            acc[j]     = ((const float*)&blo)[j];
            acc[4 + j] = ((const float*)&bhi)[j];
        }
        #pragma unroll
        for (int j = 0; j < 8; ++j) {
            const float w0 = (j < 4) ? ((const float*)&wlo[0])[j] : ((const float*)&whi[0])[j - 4];
            const float w1 = (j < 4) ? ((const float*)&wlo[1])[j] : ((const float*)&whi[1])[j - 4];
            const float w2 = (j < 4) ? ((const float*)&wlo[2])[j] : ((const float*)&whi[2])[j - 4];
            const float w3 = (j < 4) ? ((const float*)&wlo[3])[j] : ((const float*)&whi[3])[j - 4];
            acc[j] += w0 * bf2f(r0[j]) + w1 * bf2f(r1[j]) + w2 * bf2f(r2[j]) + w3 * bf2f(cur[j]);
        }
        short8v o;
        #pragma unroll
        for (int j = 0; j < 8; ++j)
            o[j] = f2bf(acc[j] * sigmoid_f(acc[j]));
        *(short8v*)(obase + (long)(l0 + i) * DINNER) = o;
        r0 = r1; r1 = r2; r2 = cur;
    }
}

// ---------------- chunk-parallel selective scan (bf16 activations) ----------------
__device__ __forceinline__ bool geo_check(const float* A2) {
    bool g = true;
    #pragma unroll
    for (int n = 1; n < NSTATE; ++n)
        g = g && (__builtin_fabsf(A2[n] - (float)(n + 1) * A2[0]) <= 1e-4f * __builtin_fabsf(A2[n]));
    return g;
}

__global__ __launch_bounds__(256) void scan_pass1_kernel(
    const __hip_bfloat16* __restrict__ delta, const __hip_bfloat16* __restrict__ xc,
    const __hip_bfloat16* __restrict__ dbc, const float* __restrict__ A2T,
    float* __restrict__ Fbuf, float* __restrict__ Dbuf)
{
    const int bx = blockIdx.x;             // mb(6) x cg(4) x chunk(64)
    const int chunk = bx & (NCHUNK - 1);
    const int cg = (bx >> 6) & 3;
    const int mb = bx >> 8;
    const int m = mb >> 1, b = mb & 1;
    const int tid = threadIdx.x;
    const int c = cg * 256 + tid;

    float A2[NSTATE];
    #pragma unroll
    for (int n = 0; n < NSTATE; ++n)
        A2[n] = A2T[((long)m * NSTATE + n) * DINNER + c];
    const bool geo = geo_check(A2);
    float h[NSTATE] = {};
    float sum_d = 0.f;

    __shared__ float sB[CHUNK][NSTATE];
    const short* dbc_mb = (const short*)dbc + (long)m * MROWS * 64 + (long)b * LSEQ * 64;
    const int t0 = chunk * CHUNK;
    for (int i = tid; i < CHUNK * NSTATE; i += 256) {
        int tt = i >> 4, j = i & 15;
        sB[tt][j] = bf2f(dbc_mb[(long)(t0 + tt) * 64 + 32 + j]);
    }
    __syncthreads();

    const short* dp = (const short*)delta;
    const short* up = (const short*)xc;
    const long base = ((long)mb * LSEQ + t0) * DINNER + c;
    if (geo) {
        #pragma unroll 4
        for (int tt = 0; tt < CHUNK; ++tt) {
            const float d = bf2f(dp[base + (long)tt * DINNER]);
            const float u = bf2f(up[base + (long)tt * DINNER]);
            const float du = d * u;
            sum_d += d;
            const float E = EXP2F(d * A2[0]);
            float e = 1.f;
            #pragma unroll
            for (int n = 0; n < NSTATE; ++n) {
                e *= E;
                h[n] = e * h[n] + du * sB[tt][n];
            }
        }
    } else {
        #pragma unroll 4
        for (int tt = 0; tt < CHUNK; ++tt) {
            const float d = bf2f(dp[base + (long)tt * DINNER]);
            const float u = bf2f(up[base + (long)tt * DINNER]);
            const float du = d * u;
            sum_d += d;
            #pragma unroll
            for (int n = 0; n < NSTATE; ++n) {
                float e = EXP2F(d * A2[n]);
                h[n] = e * h[n] + du * sB[tt][n];
            }
        }
    }
    const long ob = ((long)mb * NCHUNK + chunk) * (NSTATE * DINNER) + c;
    if (geo) {
        const float ED = EXP2F(sum_d * A2[0]);
        float e = 1.f;
        #pragma unroll
        for (int n = 0; n < NSTATE; ++n) {
            e *= ED;
            Fbuf[ob + n * DINNER] = h[n];
            Dbuf[ob + n * DINNER] = e;
        }
    } else {
        #pragma unroll
        for (int n = 0; n < NSTATE; ++n) {
            Fbuf[ob + n * DINNER] = h[n];
            Dbuf[ob + n * DINNER] = EXP2F(sum_d * A2[n]);
        }
    }
}

__global__ __launch_bounds__(256) void scan_pass2_kernel(float* __restrict__ Fbuf,
                                                         const float* __restrict__ Dbuf)
{
    const long idx = (long)blockIdx.x * 256 + threadIdx.x;  // < 6*16*1024
    const int mb = (int)(idx >> 14);
    const int cn = (int)(idx & 16383);
    float run = 0.f;
    #pragma unroll 4
    for (int k = 0; k < NCHUNK; ++k) {
        const long o = ((long)(mb * NCHUNK + k) << 14) + cn;
        const float f = Fbuf[o];
        const float p = Dbuf[o];
        Fbuf[o] = run;
        run = p * run + f;
    }
}

__global__ __launch_bounds__(256) void scan_pass3_kernel(
    const __hip_bfloat16* __restrict__ delta, const __hip_bfloat16* __restrict__ xc,
    const __hip_bfloat16* __restrict__ dbc, __hip_bfloat16* __restrict__ xz,
    const float* __restrict__ A2T, const float* __restrict__ D_skip,
    const float* __restrict__ Hin)
{
    const int bx = blockIdx.x;
    const int chunk = bx & (NCHUNK - 1);
    const int cg = (bx >> 6) & 3;
    const int mb = bx >> 8;
    const int m = mb >> 1, b = mb & 1;
    const int tid = threadIdx.x;
    const int c = cg * 256 + tid;

    float A2[NSTATE];
    #pragma unroll
    for (int n = 0; n < NSTATE; ++n)
        A2[n] = A2T[((long)m * NSTATE + n) * DINNER + c];
    const bool geo = geo_check(A2);
    const float Dsk = D_skip[m * DINNER + c];

    float h[NSTATE];
    const long ho = ((long)mb * NCHUNK + chunk) * (NSTATE * DINNER) + c;
    #pragma unroll
    for (int n = 0; n < NSTATE; ++n) h[n] = Hin[ho + n * DINNER];

    __shared__ float sBC[CHUNK][2 * NSTATE];
    const short* dbc_mb = (const short*)dbc + (long)m * MROWS * 64 + (long)b * LSEQ * 64;
    const int t0 = chunk * CHUNK;
    for (int i = tid; i < CHUNK * 2 * NSTATE; i += 256) {
        int tt = i >> 5, j = i & 31;
        sBC[tt][j] = bf2f(dbc_mb[(long)(t0 + tt) * 64 + 32 + j]);
    }
    __syncthreads();

    const short* dp = (const short*)delta;
    const short* up = (const short*)xc;
    short* xzp = (short*)xz;
    const long base = ((long)mb * LSEQ + t0) * DINNER + c;
    const long xbase = ((long)mb * LSEQ + t0) * 2048 + c;
    if (geo) {
        #pragma unroll 4
        for (int tt = 0; tt < CHUNK; ++tt) {
            const long idx = base + (long)tt * DINNER;
            const long xi  = xbase + (long)tt * 2048;
            const float d = bf2f(dp[idx]);
            const float u = bf2f(up[idx]);
            const float zv = bf2f(xzp[xi + 1024]);
            const float du = d * u;
            const float E = EXP2F(d * A2[0]);
            float e = 1.f;
            float y = 0.f;
            #pragma unroll
            for (int n = 0; n < NSTATE; ++n) {
                e *= E;
                h[n] = e * h[n] + du * sBC[tt][n];
                y += h[n] * sBC[tt][16 + n];
            }
            y += u * Dsk;
            xzp[xi] = f2bf(y * (zv * sigmoid_f(zv)));
        }
    } else {
        #pragma unroll 4
        for (int tt = 0; tt < CHUNK; ++tt) {
            const long idx = base + (long)tt * DINNER;
            const long xi  = xbase + (long)tt * 2048;
            const float d = bf2f(dp[idx]);
            const float u = bf2f(up[idx]);
            const float zv = bf2f(xzp[xi + 1024]);
            const float du = d * u;
            float y = 0.f;
            #pragma unroll
            for (int n = 0; n < NSTATE; ++n) {
                float e = EXP2F(d * A2[n]);
                h[n] = e * h[n] + du * sBC[tt][n];
                y += h[n] * sBC[tt][16 + n];
            }
            y += u * Dsk;
            xzp[xi] = f2bf(y * (zv * sigmoid_f(zv)));
        }
    }
}

extern "C" void kernel_launch(void* const* d_in, const int* in_sizes, int n_in,
                              void* d_out, int out_size, void* d_ws, size_t ws_size,
                              hipStream_t stream)
{
    const float* v       = (const float*)d_in[0];
    const float* a       = (const float*)d_in[1];
    const float* t       = (const float*)d_in[2];
    const float* norm_w  = (const float*)d_in[3];
    const float* norm_b  = (const float*)d_in[4];
    const float* in_w    = (const float*)d_in[5];
    const float* conv_w  = (const float*)d_in[6];
    const float* conv_b  = (const float*)d_in[7];
    const float* xproj_w = (const float*)d_in[8];
    const float* dt_w    = (const float*)d_in[9];
    const float* dt_b    = (const float*)d_in[10];
    const float* A_log   = (const float*)d_in[11];
    const float* D_skip  = (const float*)d_in[12];
    const float* out_w   = (const float*)d_in[13];
    const float* couple_w= (const float*)d_in[14];
    const float* coef    = (const float*)d_in[15];
    float* out = (float*)d_out;

    typedef __hip_bfloat16 bf;
    float* x_in   = (float*)d_ws;                       // [3][4096][512] f32
    bf* xn_bf     = (bf*)(x_in + 6291456);              // [3][4096][512]
    bf* sec_bf    = xn_bf + 6291456;                    // [3][4096][512]
    bf* xz_bf     = sec_bf + 6291456;                   // [3][4096][2048]  (xc-pre | z; later y | z)
    bf* xc_bf     = xz_bf + 25165824;                   // [3][4096][1024]
    bf* delta_bf  = xc_bf + 12582912;                   // [3][4096][1024]
    bf* dbc_bf    = delta_bf + 12582912;                // [3][4096][64]
    bf* cw_bf     = dbc_bf + 786432;                    // [3][512][512]
    bf* inw_bf    = cw_bf + 786432;                     // [3][2048][512]
    bf* xpw_bf    = inw_bf + 3145728;                   // [3][64][1024]
    bf* dtw_bf    = xpw_bf + 196608;                    // [3][1024][32]
    bf* outw_bf   = dtw_bf + 98304;                     // [3][512][1024]
    float* cwT    = (float*)(outw_bf + 1572864);        // [3][4][1024] f32
    float* A2T    = cwT + 12288;                        // [3][16][1024] f32
    float* Fbuf   = A2T + 49152;                        // [6][64][16][1024] f32

    float* Dbuf = out;                                  // [6][64][16][1024] — exactly out_size

    dim3 blk(256);

    // 0. prep: sec->bf16, weight conversions, conv-wT/A2T
    sec_cvt_kernel<<<6144, blk, 0, stream>>>(a, t, v, sec_bf);
    cvt_all_kernel<<<(196608 + 786432 + 49152 + 24576 + 393216 + 255) / 256, blk, 0, stream>>>(
        couple_w, cw_bf, 196608, in_w, inw_bf, 786432, xproj_w, xpw_bf, 49152,
        dt_w, dtw_bf, 24576, out_w, outw_bf, 393216);
    small_prep_kernel<<<(12288 + 49152 + 255) / 256, blk, 0, stream>>>(conv_w, cwT, A_log, A2T);

    // 1. coupling: x_in[m] = prim[m] + coef[m] * sec_bf[m] @ cw[m]^T (BK=64)
    const float* prim[3] = {v, a, t};
    for (int mI = 0; mI < 3; ++mI) {
        gemm_bf16<2, 64><<<dim3(32, 8, 1), blk, 0, stream>>>(
            sec_bf + (long)mI * 2097152, cw_bf + (long)mI * 262144, 512, 512, 512, 0L, 0L,
            x_in + (long)mI * 2097152, nullptr, 512, 0L,
            prim[mI], 0L, coef + mI, 0, nullptr, 0L, 0);
    }
    // 2. layernorm -> bf16
    ln_kernel<<<3*4096, blk, 0, stream>>>(x_in, xn_bf, norm_w, norm_b);
    // 3. in_proj (both halves, N=2048) -> xz  (NJ=4, BK=64)
    gemm_bf16<4, 64><<<dim3(32, 16, 3), blk, 0, stream>>>(
        xn_bf, inw_bf, 512, 512, 512, 2097152L, 1048576L,
        nullptr, xz_bf, 2048, 8388608L, nullptr, 0L, nullptr, 0, nullptr, 0L, 0);
    // 4. conv + SiLU (reads xz cols 0..1023)
    conv_silu_kernel<<<768, blk, 0, stream>>>(xz_bf, cwT, conv_b, xc_bf);
    // 5. x_proj -> dbc bf16 (BK=64)
    gemm_bf16<2, 64><<<dim3(32, 1, 3), blk, 0, stream>>>(
        xc_bf, xpw_bf, 1024, 1024, 1024, 4194304L, 65536L,
        nullptr, dbc_bf, 64, 262144L, nullptr, 0L, nullptr, 0, nullptr, 0L, 0);
    // 6. delta = softplus(dt @ dt_w^T + dt_b) -> bf16 (K=32: BK=32 single tile)
    gemm_bf16<4, 32><<<dim3(32, 8, 3), blk, 0, stream>>>(
        dbc_bf, dtw_bf, 32, 64, 32, 262144L, 32768L,
        nullptr, delta_bf, 1024, 4194304L, nullptr, 0L, nullptr, 0, dt_b, 1024L, 1);
    // 7. chunk-parallel scan
    scan_pass1_kernel<<<6*4*NCHUNK, blk, 0, stream>>>(delta_bf, xc_bf, dbc_bf, A2T, Fbuf, Dbuf);
    scan_pass2_kernel<<<(6*1024*16)/256, blk, 0, stream>>>(Fbuf, Dbuf);
    scan_pass3_kernel<<<6*4*NCHUNK, blk, 0, stream>>>(delta_bf, xc_bf, dbc_bf, xz_bf,
                                                      A2T, D_skip, Fbuf);
    // 8. out_proj + residual -> d_out (NJ=2, BK=64)
    gemm_bf16<2, 64><<<dim3(32, 8, 3), blk, 0, stream>>>(
        xz_bf, outw_bf, 1024, 2048, 1024, 8388608L, 524288L,
        out, nullptr, 512, 2097152L, x_in, 2097152L, nullptr, 0, nullptr, 0L, 0);
}

// Round 13
// 273.026 us; speedup vs baseline: 1.2519x; 1.1311x over previous
//
#include <hip/hip_runtime.h>
#include <hip/hip_bf16.h>

#define MODS 3
#define BSZ 2
#define LSEQ 2048
#define DMODEL 512
#define DINNER 1024
#define DTRANK 32
#define NSTATE 16
#define DCONV 4
#define MROWS (BSZ*LSEQ)   // 4096
#define NCHUNK 64
#define CHUNK 32           // LSEQ / NCHUNK

#define LOG2E 1.44269504088896f
#define LN2   0.69314718055995f

typedef __attribute__((ext_vector_type(8))) short short8v;
typedef __attribute__((ext_vector_type(4))) short short4v;
typedef __attribute__((ext_vector_type(2))) short short2v;
typedef __attribute__((ext_vector_type(4))) float f32x4;

#if __has_builtin(__builtin_amdgcn_exp2f)
#define EXP2F __builtin_amdgcn_exp2f
#else
#define EXP2F exp2f
#endif
#if __has_builtin(__builtin_amdgcn_rcpf)
#define RCPF __builtin_amdgcn_rcpf
#else
#define RCPF(x) (1.0f / (x))
#endif

__device__ __forceinline__ short f2bf(float x) {
    __hip_bfloat16 h = __float2bfloat16(x);
    return __builtin_bit_cast(short, h);
}
__device__ __forceinline__ float bf2f(short s) {
    return __uint_as_float(((unsigned)(unsigned short)s) << 16);
}
__device__ __forceinline__ void gl_lds16(const short* g, short* l) {
    __builtin_amdgcn_global_load_lds(
        (const __attribute__((address_space(1))) unsigned int*)g,
        (__attribute__((address_space(3))) unsigned int*)l, 16, 0, 0);
}
__device__ __forceinline__ float sigmoid_f(float x) {
    return RCPF(1.f + EXP2F(-x * LOG2E));
}

// ---------------- bf16 MFMA GEMM NT, BK=32, XOR-swizzled LDS, 2-phase prefetch dbuf ----
// Tile 128 x (NJ*32), 4 waves 2x2. Grid: x = M-panel (fastest) for XCD A-panel L2
// locality; y = N-tile, z = modality. If resB != nullptr, residual pointer is
// selected per-z from {res, resB, resC} (merged cross-modal coupling).
template<int NJ, int BK>
__global__ __launch_bounds__(256) void gemm_bf16(
    const __hip_bfloat16* __restrict__ A_, const __hip_bfloat16* __restrict__ B_,
    int K, int lda, int ldb, long sA, long sB,
    float* __restrict__ Cf, __hip_bfloat16* __restrict__ Cb, int ldc, long sC,
    const float* __restrict__ res, long sRes,
    const float* __restrict__ resB, const float* __restrict__ resC,
    const float* __restrict__ coef_base, int coef_stride,
    const float* __restrict__ bias, long sBias, int act)
{
    constexpr int BN = NJ * 32;
    constexpr int ASZ = 128 * BK;
    constexpr int BSZe = BN * BK;
    __shared__ alignas(16) short As[2 * ASZ];
    __shared__ alignas(16) short Bs[2 * BSZe];
    const int z = blockIdx.z;
    const int bm0 = blockIdx.x * 128;
    const int bn0 = blockIdx.y * BN;
    const short* Ag = (const short*)A_ + z * sA + (long)bm0 * lda;
    const short* Bg = (const short*)B_ + z * sB + (long)bn0 * ldb;
    const int tid = threadIdx.x;
    const int lane = tid & 63;
    const int w = tid >> 6;
    const int wr = w >> 1, wc = w & 1;
    const int lr = lane & 15;
    const int sidx = lane >> 4;

    constexpr int SLOTS = BK / 8;
    const int srow = tid / SLOTS;
    const int sslot = tid % SLOTS;
    int swz;
    if constexpr (BK == 64) swz = srow & 7;
    else                    swz = (srow >> 1) & 3;
    const int sgcol = (sslot ^ swz) * 8;
    int fA;
    if constexpr (BK == 64) fA = lr & 7;
    else                    fA = (lr >> 1) & 3;

    constexpr int AINSTR = ASZ / 2048;
    constexpr int BINSTR = BSZe / 2048;
    constexpr int RPI = 2048 / BK;

    f32x4 acc[4][NJ];
    #pragma unroll
    for (int i = 0; i < 4; ++i)
        #pragma unroll
        for (int j = 0; j < NJ; ++j)
            acc[i][j] = (f32x4){0.f, 0.f, 0.f, 0.f};

    auto stage = [&](int buf, int k0) {
        #pragma unroll
        for (int i = 0; i < AINSTR; ++i)
            gl_lds16(Ag + (long)(i * RPI + srow) * lda + k0 + sgcol,
                     As + buf * ASZ + i * 2048 + tid * 8);
        #pragma unroll
        for (int i = 0; i < BINSTR; ++i)
            gl_lds16(Bg + (long)(i * RPI + srow) * ldb + k0 + sgcol,
                     Bs + buf * BSZe + i * 2048 + tid * 8);
    };
    auto compute = [&](int buf) {
        #pragma unroll
        for (int kh = 0; kh < BK / 32; ++kh) {
            const int sl = ((kh * 4 + sidx) ^ fA) * 8;
            short8v af[4], bfr[NJ];
            #pragma unroll
            for (int i = 0; i < 4; ++i)
                af[i] = *(const short8v*)&As[buf * ASZ + (wr * 64 + i * 16 + lr) * BK + sl];
            #pragma unroll
            for (int j = 0; j < NJ; ++j)
                bfr[j] = *(const short8v*)&Bs[buf * BSZe + (wc * NJ * 16 + j * 16 + lr) * BK + sl];
            #pragma unroll
            for (int i = 0; i < 4; ++i)
                #pragma unroll
                for (int j = 0; j < NJ; ++j)
                    acc[i][j] = __builtin_amdgcn_mfma_f32_16x16x32_bf16(af[i], bfr[j], acc[i][j], 0, 0, 0);
        }
    };

    stage(0, 0);
    __syncthreads();
    int cur = 0;
    for (int k0 = BK; k0 < K; k0 += BK) {
        stage(cur ^ 1, k0);
        compute(cur);
        __syncthreads();
        cur ^= 1;
    }
    compute(cur);

    const float alpha = coef_base ? coef_base[z * coef_stride] : 1.0f;
    const float* resz = nullptr;
    if (res) {
        if (resB) resz = (z == 0) ? res : ((z == 1) ? resB : resC);
        else      resz = res + z * sRes;
    }
    const float* biasz = bias ? bias + z * sBias : nullptr;
    float* Cfz = Cf ? Cf + z * sC : nullptr;
    __hip_bfloat16* Cbz = Cb ? Cb + z * sC : nullptr;
    #pragma unroll
    for (int i = 0; i < 4; ++i) {
        #pragma unroll
        for (int r = 0; r < 4; ++r) {
            const int row = bm0 + wr * 64 + i * 16 + (lane >> 4) * 4 + r;
            #pragma unroll
            for (int j = 0; j < NJ; ++j) {
                const int col = bn0 + wc * NJ * 16 + j * 16 + lr;
                float val = acc[i][j][r];
                if (biasz) val += biasz[col];
                if (act == 1)
                    val = (val > 20.f) ? val : LN2 * __log2f(1.f + EXP2F(val * LOG2E));
                val *= alpha;
                if (resz) val += resz[(long)row * ldc + col];
                if (Cfz) Cfz[(long)row * ldc + col] = val;
                else     Cbz[(long)row * ldc + col] = __float2bfloat16(val);
            }
        }
    }
}

// ---------------- fused prep: sec->bf16 + weight cvts + conv-wT + A2T ----------------
// ranges (in order): sec 1,572,864 f4 | weights 1,449,984 f4 | cwT 12,288 | A2T 49,152
__global__ __launch_bounds__(256) void prep_kernel(
    const float* __restrict__ a, const float* __restrict__ t, const float* __restrict__ v,
    __hip_bfloat16* __restrict__ sec_bf,
    const float* __restrict__ couple_w, __hip_bfloat16* __restrict__ cw_bf,
    const float* __restrict__ in_w, __hip_bfloat16* __restrict__ inw_bf,
    const float* __restrict__ xproj_w, __hip_bfloat16* __restrict__ xpw_bf,
    const float* __restrict__ dt_w, __hip_bfloat16* __restrict__ dtw_bf,
    const float* __restrict__ out_w, __hip_bfloat16* __restrict__ outw_bf,
    const float* __restrict__ conv_w, float* __restrict__ cwT,
    const float* __restrict__ A_log, float* __restrict__ A2T)
{
    long idx = (long)blockIdx.x * 256 + threadIdx.x;
    if (idx < 1572864) {                       // sec_bf: [a;t;v] f32 -> bf16, float4 units
        const int m = (int)(idx >> 19);
        const long off = idx & 524287;
        const float* sec = (m == 0) ? a : (m == 1) ? t : v;
        float4 sv = ((const float4*)sec)[off];
        short4v s;
        s.x = f2bf(sv.x); s.y = f2bf(sv.y); s.z = f2bf(sv.z); s.w = f2bf(sv.w);
        ((short4v*)sec_bf)[idx] = s;
        return;
    }
    idx -= 1572864;
    if (idx < 1449984) {                       // weight conversions, float4 units
        const float* s; __hip_bfloat16* d; long off = idx;
        if      (off < 196608)              { s = couple_w; d = cw_bf; }
        else if ((off -= 196608) < 786432)  { s = in_w;     d = inw_bf; }
        else if ((off -= 786432) < 49152)   { s = xproj_w;  d = xpw_bf; }
        else if ((off -= 49152) < 24576)    { s = dt_w;     d = dtw_bf; }
        else    { off -= 24576;               s = out_w;    d = outw_bf; }
        float4 vv = ((const float4*)s)[off];
        short4v o;
        o.x = f2bf(vv.x); o.y = f2bf(vv.y); o.z = f2bf(vv.z); o.w = f2bf(vv.w);
        ((short4v*)d)[off] = o;
        return;
    }
    idx -= 1449984;
    if (idx < 12288) {                         // cwT[m][k][c] = conv_w[m][c][k]
        const int k = (int)(idx & 3);
        const int c = (int)((idx >> 2) & 1023);
        const int m = (int)(idx >> 12);
        cwT[(m * DCONV + k) * DINNER + c] = conv_w[idx];
        return;
    }
    idx -= 12288;
    if (idx < 49152) {                         // A2T[m][n][c] = -exp(A_log[m][c][n])*log2e
        const int c = (int)(idx & 1023);
        const int n = (int)((idx >> 10) & 15);
        const int m = (int)(idx >> 14);
        A2T[idx] = -EXP2F(A_log[((long)m * DINNER + c) * NSTATE + n] * LOG2E) * LOG2E;
    }
}

// ---------------- LayerNorm: f32 in -> bf16 out ----------------
__global__ __launch_bounds__(256) void ln_kernel(const float* __restrict__ x, __hip_bfloat16* __restrict__ xn,
                                                 const float* __restrict__ nw, const float* __restrict__ nb)
{
    const int row = blockIdx.x;
    const int m = row >> 12;
    const int tid = threadIdx.x;
    const float2 v = *reinterpret_cast<const float2*>(x + (long)row * DMODEL + tid * 2);
    float s = v.x + v.y;
    float sq = v.x * v.x + v.y * v.y;
    #pragma unroll
    for (int off = 32; off > 0; off >>= 1) {
        s  += __shfl_down(s, off);
        sq += __shfl_down(sq, off);
    }
    __shared__ float ws_s[4], ws_q[4];
    const int wid = tid >> 6, lane = tid & 63;
    if (lane == 0) { ws_s[wid] = s; ws_q[wid] = sq; }
    __syncthreads();
    if (tid == 0) {
        float ts = ws_s[0] + ws_s[1] + ws_s[2] + ws_s[3];
        float tq = ws_q[0] + ws_q[1] + ws_q[2] + ws_q[3];
        float mu = ts / DMODEL;
        float var = tq / DMODEL - mu * mu;
        ws_s[0] = mu;
        ws_q[0] = rsqrtf(var + 1e-5f);
    }
    __syncthreads();
    const float mu = ws_s[0], rstd = ws_q[0];
    const int e0 = tid * 2;
    float2 w  = *reinterpret_cast<const float2*>(nw + m * DMODEL + e0);
    float2 bb = *reinterpret_cast<const float2*>(nb + m * DMODEL + e0);
    short2v o;
    o.x = f2bf((v.x - mu) * rstd * w.x + bb.x);
    o.y = f2bf((v.y - mu) * rstd * w.y + bb.y);
    *reinterpret_cast<short2v*>((short*)xn + (long)row * DMODEL + e0) = o;
}

// ---------------- depthwise causal conv(4) + SiLU ----------------
__global__ __launch_bounds__(256) void conv_silu_kernel(const __hip_bfloat16* __restrict__ xz,
    const float* __restrict__ cwT, const float* __restrict__ cb, __hip_bfloat16* __restrict__ xc)
{
    const int idx = blockIdx.x * 256 + threadIdx.x;   // < 6*256*128 = 196608
    const int c8 = idx & 127;
    const int lt = (idx >> 7) & 255;
    const int mb = idx >> 15;
    const int m  = mb >> 1;
    const int c0 = c8 * 8;
    const int l0 = lt * 8;

    float4 wlo[DCONV], whi[DCONV];
    #pragma unroll
    for (int k = 0; k < DCONV; ++k) {
        wlo[k] = *(const float4*)&cwT[(m * DCONV + k) * DINNER + c0];
        whi[k] = *(const float4*)&cwT[(m * DCONV + k) * DINNER + c0 + 4];
    }
    const float4 blo = *(const float4*)&cb[m * DINNER + c0];
    const float4 bhi = *(const float4*)&cb[m * DINNER + c0 + 4];

    const short* base = (const short*)xz + (long)mb * LSEQ * 2048 + c0;
    short* obase = (short*)xc + (long)mb * LSEQ * DINNER + c0;

    short8v r0 = {}, r1 = {}, r2 = {};
    if (l0 - 3 >= 0) r0 = *(const short8v*)(base + (long)(l0 - 3) * 2048);
    if (l0 - 2 >= 0) r1 = *(const short8v*)(base + (long)(l0 - 2) * 2048);
    if (l0 - 1 >= 0) r2 = *(const short8v*)(base + (long)(l0 - 1) * 2048);

    #pragma unroll
    for (int i = 0; i < 8; ++i) {
        const short8v cur = *(const short8v*)(base + (long)(l0 + i) * 2048);
        float acc[8];
        #pragma unroll
        for (int j = 0; j < 4; ++j) {
            acc[j]     = ((const float*)&blo)[j];
            acc[4 + j] = ((const float*)&bhi)[j];
        }
        #pragma unroll
        for (int j = 0; j < 8; ++j) {
            const float w0 = (j < 4) ? ((const float*)&wlo[0])[j] : ((const float*)&whi[0])[j - 4];
            const float w1 = (j < 4) ? ((const float*)&wlo[1])[j] : ((const float*)&whi[1])[j - 4];
            const float w2 = (j < 4) ? ((const float*)&wlo[2])[j] : ((const float*)&whi[2])[j - 4];
            const float w3 = (j < 4) ? ((const float*)&wlo[3])[j] : ((const float*)&whi[3])[j - 4];
            acc[j] += w0 * bf2f(r0[j]) + w1 * bf2f(r1[j]) + w2 * bf2f(r2[j]) + w3 * bf2f(cur[j]);
        }
        short8v o;
        #pragma unroll
        for (int j = 0; j < 8; ++j)
            o[j] = f2bf(acc[j] * sigmoid_f(acc[j]));
        *(short8v*)(obase + (long)(l0 + i) * DINNER) = o;
        r0 = r1; r1 = r2; r2 = cur;
    }
}

// ---------------- chunk-parallel selective scan (bf16 activations) ----------------
__device__ __forceinline__ bool geo_check(const float* A2) {
    bool g = true;
    #pragma unroll
    for (int n = 1; n < NSTATE; ++n)
        g = g && (__builtin_fabsf(A2[n] - (float)(n + 1) * A2[0]) <= 1e-4f * __builtin_fabsf(A2[n]));
    return g;
}

__global__ __launch_bounds__(256) void scan_pass1_kernel(
    const __hip_bfloat16* __restrict__ delta, const __hip_bfloat16* __restrict__ xc,
    const __hip_bfloat16* __restrict__ dbc, const float* __restrict__ A2T,
    float* __restrict__ Fbuf, float* __restrict__ Dbuf)
{
    const int bx = blockIdx.x;             // mb(6) x cg(4) x chunk(64)
    const int chunk = bx & (NCHUNK - 1);
    const int cg = (bx >> 6) & 3;
    const int mb = bx >> 8;
    const int m = mb >> 1, b = mb & 1;
    const int tid = threadIdx.x;
    const int c = cg * 256 + tid;

    float A2[NSTATE];
    #pragma unroll
    for (int n = 0; n < NSTATE; ++n)
        A2[n] = A2T[((long)m * NSTATE + n) * DINNER + c];
    const bool geo = geo_check(A2);
    float h[NSTATE] = {};
    float sum_d = 0.f;

    __shared__ float sB[CHUNK][NSTATE];
    const short* dbc_mb = (const short*)dbc + (long)m * MROWS * 64 + (long)b * LSEQ * 64;
    const int t0 = chunk * CHUNK;
    for (int i = tid; i < CHUNK * NSTATE; i += 256) {
        int tt = i >> 4, j = i & 15;
        sB[tt][j] = bf2f(dbc_mb[(long)(t0 + tt) * 64 + 32 + j]);
    }
    __syncthreads();

    const short* dp = (const short*)delta;
    const short* up = (const short*)xc;
    const long base = ((long)mb * LSEQ + t0) * DINNER + c;
    if (geo) {
        #pragma unroll 4
        for (int tt = 0; tt < CHUNK; ++tt) {
            const float d = bf2f(dp[base + (long)tt * DINNER]);
            const float u = bf2f(up[base + (long)tt * DINNER]);
            const float du = d * u;
            sum_d += d;
            const float E = EXP2F(d * A2[0]);
            float e = 1.f;
            #pragma unroll
            for (int n = 0; n < NSTATE; ++n) {
                e *= E;
                h[n] = e * h[n] + du * sB[tt][n];
            }
        }
    } else {
        #pragma unroll 4
        for (int tt = 0; tt < CHUNK; ++tt) {
            const float d = bf2f(dp[base + (long)tt * DINNER]);
            const float u = bf2f(up[base + (long)tt * DINNER]);
            const float du = d * u;
            sum_d += d;
            #pragma unroll
            for (int n = 0; n < NSTATE; ++n) {
                float e = EXP2F(d * A2[n]);
                h[n] = e * h[n] + du * sB[tt][n];
            }
        }
    }
    const long ob = ((long)mb * NCHUNK + chunk) * (NSTATE * DINNER) + c;
    if (geo) {
        const float ED = EXP2F(sum_d * A2[0]);
        float e = 1.f;
        #pragma unroll
        for (int n = 0; n < NSTATE; ++n) {
            e *= ED;
            Fbuf[ob + n * DINNER] = h[n];
            Dbuf[ob + n * DINNER] = e;
        }
    } else {
        #pragma unroll
        for (int n = 0; n < NSTATE; ++n) {
            Fbuf[ob + n * DINNER] = h[n];
            Dbuf[ob + n * DINNER] = EXP2F(sum_d * A2[n]);
        }
    }
}

__global__ __launch_bounds__(256) void scan_pass2_kernel(float* __restrict__ Fbuf,
                                                         const float* __restrict__ Dbuf)
{
    const long idx = (long)blockIdx.x * 256 + threadIdx.x;  // < 6*16*1024
    const int mb = (int)(idx >> 14);
    const int cn = (int)(idx & 16383);
    float run = 0.f;
    #pragma unroll 4
    for (int k = 0; k < NCHUNK; ++k) {
        const long o = ((long)(mb * NCHUNK + k) << 14) + cn;
        const float f = Fbuf[o];
        const float p = Dbuf[o];
        Fbuf[o] = run;
        run = p * run + f;
    }
}

__global__ __launch_bounds__(256) void scan_pass3_kernel(
    const __hip_bfloat16* __restrict__ delta, const __hip_bfloat16* __restrict__ xc,
    const __hip_bfloat16* __restrict__ dbc, __hip_bfloat16* __restrict__ xz,
    const float* __restrict__ A2T, const float* __restrict__ D_skip,
    const float* __restrict__ Hin)
{
    const int bx = blockIdx.x;
    const int chunk = bx & (NCHUNK - 1);
    const int cg = (bx >> 6) & 3;
    const int mb = bx >> 8;
    const int m = mb >> 1, b = mb & 1;
    const int tid = threadIdx.x;
    const int c = cg * 256 + tid;

    float A2[NSTATE];
    #pragma unroll
    for (int n = 0; n < NSTATE; ++n)
        A2[n] = A2T[((long)m * NSTATE + n) * DINNER + c];
    const bool geo = geo_check(A2);
    const float Dsk = D_skip[m * DINNER + c];

    float h[NSTATE];
    const long ho = ((long)mb * NCHUNK + chunk) * (NSTATE * DINNER) + c;
    #pragma unroll
    for (int n = 0; n < NSTATE; ++n) h[n] = Hin[ho + n * DINNER];

    __shared__ float sBC[CHUNK][2 * NSTATE];
    const short* dbc_mb = (const short*)dbc + (long)m * MROWS * 64 + (long)b * LSEQ * 64;
    const int t0 = chunk * CHUNK;
    for (int i = tid; i < CHUNK * 2 * NSTATE; i += 256) {
        int tt = i >> 5, j = i & 31;
        sBC[tt][j] = bf2f(dbc_mb[(long)(t0 + tt) * 64 + 32 + j]);
    }
    __syncthreads();

    const short* dp = (const short*)delta;
    const short* up = (const short*)xc;
    short* xzp = (short*)xz;
    const long base = ((long)mb * LSEQ + t0) * DINNER + c;
    const long xbase = ((long)mb * LSEQ + t0) * 2048 + c;
    if (geo) {
        #pragma unroll 4
        for (int tt = 0; tt < CHUNK; ++tt) {
            const long idx = base + (long)tt * DINNER;
            const long xi  = xbase + (long)tt * 2048;
            const float d = bf2f(dp[idx]);
            const float u = bf2f(up[idx]);
            const float zv = bf2f(xzp[xi + 1024]);
            const float du = d * u;
            const float E = EXP2F(d * A2[0]);
            float e = 1.f;
            float y = 0.f;
            #pragma unroll
            for (int n = 0; n < NSTATE; ++n) {
                e *= E;
                h[n] = e * h[n] + du * sBC[tt][n];
                y += h[n] * sBC[tt][16 + n];
            }
            y += u * Dsk;
            xzp[xi] = f2bf(y * (zv * sigmoid_f(zv)));
        }
    } else {
        #pragma unroll 4
        for (int tt = 0; tt < CHUNK; ++tt) {
            const long idx = base + (long)tt * DINNER;
            const long xi  = xbase + (long)tt * 2048;
            const float d = bf2f(dp[idx]);
            const float u = bf2f(up[idx]);
            const float zv = bf2f(xzp[xi + 1024]);
            const float du = d * u;
            float y = 0.f;
            #pragma unroll
            for (int n = 0; n < NSTATE; ++n) {
                float e = EXP2F(d * A2[n]);
                h[n] = e * h[n] + du * sBC[tt][n];
                y += h[n] * sBC[tt][16 + n];
            }
            y += u * Dsk;
            xzp[xi] = f2bf(y * (zv * sigmoid_f(zv)));
        }
    }
}

extern "C" void kernel_launch(void* const* d_in, const int* in_sizes, int n_in,
                              void* d_out, int out_size, void* d_ws, size_t ws_size,
                              hipStream_t stream)
{
    const float* v       = (const float*)d_in[0];
    const float* a       = (const float*)d_in[1];
    const float* t       = (const float*)d_in[2];
    const float* norm_w  = (const float*)d_in[3];
    const float* norm_b  = (const float*)d_in[4];
    const float* in_w    = (const float*)d_in[5];
    const float* conv_w  = (const float*)d_in[6];
    const float* conv_b  = (const float*)d_in[7];
    const float* xproj_w = (const float*)d_in[8];
    const float* dt_w    = (const float*)d_in[9];
    const float* dt_b    = (const float*)d_in[10];
    const float* A_log   = (const float*)d_in[11];
    const float* D_skip  = (const float*)d_in[12];
    const float* out_w   = (const float*)d_in[13];
    const float* couple_w= (const float*)d_in[14];
    const float* coef    = (const float*)d_in[15];
    float* out = (float*)d_out;

    typedef __hip_bfloat16 bf;
    float* x_in   = (float*)d_ws;                       // [3][4096][512] f32
    bf* xn_bf     = (bf*)(x_in + 6291456);              // [3][4096][512]
    bf* sec_bf    = xn_bf + 6291456;                    // [3][4096][512]
    bf* xz_bf     = sec_bf + 6291456;                   // [3][4096][2048]  (xc-pre | z; later y | z)
    bf* xc_bf     = xz_bf + 25165824;                   // [3][4096][1024]
    bf* delta_bf  = xc_bf + 12582912;                   // [3][4096][1024]
    bf* dbc_bf    = delta_bf + 12582912;                // [3][4096][64]
    bf* cw_bf     = dbc_bf + 786432;                    // [3][512][512]
    bf* inw_bf    = cw_bf + 786432;                     // [3][2048][512]
    bf* xpw_bf    = inw_bf + 3145728;                   // [3][64][1024]
    bf* dtw_bf    = xpw_bf + 196608;                    // [3][1024][32]
    bf* outw_bf   = dtw_bf + 98304;                     // [3][512][1024]
    float* cwT    = (float*)(outw_bf + 1572864);        // [3][4][1024] f32
    float* A2T    = cwT + 12288;                        // [3][16][1024] f32
    float* Fbuf   = A2T + 49152;                        // [6][64][16][1024] f32

    float* Dbuf = out;                                  // [6][64][16][1024] — exactly out_size

    dim3 blk(256);

    // 0. fused prep: sec->bf16 + weight cvts + conv-wT + A2T (one dispatch)
    prep_kernel<<<(1572864 + 1449984 + 12288 + 49152 + 255) / 256, blk, 0, stream>>>(
        a, t, v, sec_bf, couple_w, cw_bf, in_w, inw_bf, xproj_w, xpw_bf,
        dt_w, dtw_bf, out_w, outw_bf, conv_w, cwT, A_log, A2T);

    // 1. coupling (merged z=3): x_in[z] = prim[z] + coef[z] * sec_bf[z] @ cw[z]^T
    gemm_bf16<2, 32><<<dim3(32, 8, 3), blk, 0, stream>>>(
        sec_bf, cw_bf, 512, 512, 512, 2097152L, 262144L,
        x_in, nullptr, 512, 2097152L,
        v, 0L, a, t, coef, 1, nullptr, 0L, 0);
    // 2. layernorm -> bf16
    ln_kernel<<<3*4096, blk, 0, stream>>>(x_in, xn_bf, norm_w, norm_b);
    // 3. in_proj (both halves, N=2048) -> xz  (NJ=4, BK=32)
    gemm_bf16<4, 32><<<dim3(32, 16, 3), blk, 0, stream>>>(
        xn_bf, inw_bf, 512, 512, 512, 2097152L, 1048576L,
        nullptr, xz_bf, 2048, 8388608L, nullptr, 0L, nullptr, nullptr, nullptr, 0, nullptr, 0L, 0);
    // 4. conv + SiLU (reads xz cols 0..1023)
    conv_silu_kernel<<<768, blk, 0, stream>>>(xz_bf, cwT, conv_b, xc_bf);
    // 5. x_proj -> dbc bf16
    gemm_bf16<2, 32><<<dim3(32, 1, 3), blk, 0, stream>>>(
        xc_bf, xpw_bf, 1024, 1024, 1024, 4194304L, 65536L,
        nullptr, dbc_bf, 64, 262144L, nullptr, 0L, nullptr, nullptr, nullptr, 0, nullptr, 0L, 0);
    // 6. delta = softplus(dt @ dt_w^T + dt_b) -> bf16
    gemm_bf16<4, 32><<<dim3(32, 8, 3), blk, 0, stream>>>(
        dbc_bf, dtw_bf, 32, 64, 32, 262144L, 32768L,
        nullptr, delta_bf, 1024, 4194304L, nullptr, 0L, nullptr, nullptr, nullptr, 0, dt_b, 1024L, 1);
    // 7. chunk-parallel scan
    scan_pass1_kernel<<<6*4*NCHUNK, blk, 0, stream>>>(delta_bf, xc_bf, dbc_bf, A2T, Fbuf, Dbuf);
    scan_pass2_kernel<<<(6*1024*16)/256, blk, 0, stream>>>(Fbuf, Dbuf);
    scan_pass3_kernel<<<6*4*NCHUNK, blk, 0, stream>>>(delta_bf, xc_bf, dbc_bf, xz_bf,
                                                      A2T, D_skip, Fbuf);
    // 8. out_proj + residual -> d_out (NJ=2, BK=32)
    gemm_bf16<2, 32><<<dim3(32, 8, 3), blk, 0, stream>>>(
        xz_bf, outw_bf, 1024, 2048, 1024, 8388608L, 524288L,
        out, nullptr, 512, 2097152L, x_in, 2097152L, nullptr, nullptr, nullptr, 0, nullptr, 0L, 0);
}

// Round 15
// 269.377 us; speedup vs baseline: 1.2689x; 1.0135x over previous
//
#include <hip/hip_runtime.h>
#include <hip/hip_bf16.h>

#define MODS 3
#define BSZ 2
#define LSEQ 2048
#define DMODEL 512
#define DINNER 1024
#define DTRANK 32
#define NSTATE 16
#define DCONV 4
#define MROWS (BSZ*LSEQ)   // 4096
#define NCHUNK 64
#define CHUNK 32           // LSEQ / NCHUNK

#define LOG2E 1.44269504088896f
#define LN2   0.69314718055995f

typedef __attribute__((ext_vector_type(8))) short short8v;
typedef __attribute__((ext_vector_type(4))) short short4v;
typedef __attribute__((ext_vector_type(2))) short short2v;
typedef __attribute__((ext_vector_type(4))) float f32x4;

#if __has_builtin(__builtin_amdgcn_exp2f)
#define EXP2F __builtin_amdgcn_exp2f
#else
#define EXP2F exp2f
#endif
#if __has_builtin(__builtin_amdgcn_rcpf)
#define RCPF __builtin_amdgcn_rcpf
#else
#define RCPF(x) (1.0f / (x))
#endif

__device__ __forceinline__ short f2bf(float x) {
    __hip_bfloat16 h = __float2bfloat16(x);
    return __builtin_bit_cast(short, h);
}
__device__ __forceinline__ float bf2f(short s) {
    return __uint_as_float(((unsigned)(unsigned short)s) << 16);
}
__device__ __forceinline__ void gl_lds16(const short* g, short* l) {
    __builtin_amdgcn_global_load_lds(
        (const __attribute__((address_space(1))) unsigned int*)g,
        (__attribute__((address_space(3))) unsigned int*)l, 16, 0, 0);
}
__device__ __forceinline__ float sigmoid_f(float x) {
    return RCPF(1.f + EXP2F(-x * LOG2E));
}

// ---------------- bf16 MFMA GEMM NT, BK=32, XOR-swizzled LDS, 2-phase prefetch dbuf ----
// Tile 128 x (NJ*32), 4 waves 2x2. Grid: x = M-panel (fastest) for XCD A-panel L2
// locality; y = N-tile, z = modality. If resB != nullptr, residual pointer is
// selected per-z from {res, resB, resC} (merged cross-modal coupling).
template<int NJ, int BK>
__global__ __launch_bounds__(256) void gemm_bf16(
    const __hip_bfloat16* __restrict__ A_, const __hip_bfloat16* __restrict__ B_,
    int K, int lda, int ldb, long sA, long sB,
    float* __restrict__ Cf, __hip_bfloat16* __restrict__ Cb, int ldc, long sC,
    const float* __restrict__ res, long sRes,
    const float* __restrict__ resB, const float* __restrict__ resC,
    const float* __restrict__ coef_base, int coef_stride,
    const float* __restrict__ bias, long sBias, int act)
{
    constexpr int BN = NJ * 32;
    constexpr int ASZ = 128 * BK;
    constexpr int BSZe = BN * BK;
    __shared__ alignas(16) short As[2 * ASZ];
    __shared__ alignas(16) short Bs[2 * BSZe];
    const int z = blockIdx.z;
    const int bm0 = blockIdx.x * 128;
    const int bn0 = blockIdx.y * BN;
    const short* Ag = (const short*)A_ + z * sA + (long)bm0 * lda;
    const short* Bg = (const short*)B_ + z * sB + (long)bn0 * ldb;
    const int tid = threadIdx.x;
    const int lane = tid & 63;
    const int w = tid >> 6;
    const int wr = w >> 1, wc = w & 1;
    const int lr = lane & 15;
    const int sidx = lane >> 4;

    constexpr int SLOTS = BK / 8;
    const int srow = tid / SLOTS;
    const int sslot = tid % SLOTS;
    int swz;
    if constexpr (BK == 64) swz = srow & 7;
    else                    swz = (srow >> 1) & 3;
    const int sgcol = (sslot ^ swz) * 8;
    int fA;
    if constexpr (BK == 64) fA = lr & 7;
    else                    fA = (lr >> 1) & 3;

    constexpr int AINSTR = ASZ / 2048;
    constexpr int BINSTR = BSZe / 2048;
    constexpr int RPI = 2048 / BK;

    f32x4 acc[4][NJ];
    #pragma unroll
    for (int i = 0; i < 4; ++i)
        #pragma unroll
        for (int j = 0; j < NJ; ++j)
            acc[i][j] = (f32x4){0.f, 0.f, 0.f, 0.f};

    auto stage = [&](int buf, int k0) {
        #pragma unroll
        for (int i = 0; i < AINSTR; ++i)
            gl_lds16(Ag + (long)(i * RPI + srow) * lda + k0 + sgcol,
                     As + buf * ASZ + i * 2048 + tid * 8);
        #pragma unroll
        for (int i = 0; i < BINSTR; ++i)
            gl_lds16(Bg + (long)(i * RPI + srow) * ldb + k0 + sgcol,
                     Bs + buf * BSZe + i * 2048 + tid * 8);
    };
    auto compute = [&](int buf) {
        #pragma unroll
        for (int kh = 0; kh < BK / 32; ++kh) {
            const int sl = ((kh * 4 + sidx) ^ fA) * 8;
            short8v af[4], bfr[NJ];
            #pragma unroll
            for (int i = 0; i < 4; ++i)
                af[i] = *(const short8v*)&As[buf * ASZ + (wr * 64 + i * 16 + lr) * BK + sl];
            #pragma unroll
            for (int j = 0; j < NJ; ++j)
                bfr[j] = *(const short8v*)&Bs[buf * BSZe + (wc * NJ * 16 + j * 16 + lr) * BK + sl];
            #pragma unroll
            for (int i = 0; i < 4; ++i)
                #pragma unroll
                for (int j = 0; j < NJ; ++j)
                    acc[i][j] = __builtin_amdgcn_mfma_f32_16x16x32_bf16(af[i], bfr[j], acc[i][j], 0, 0, 0);
        }
    };

    stage(0, 0);
    __syncthreads();
    int cur = 0;
    for (int k0 = BK; k0 < K; k0 += BK) {
        stage(cur ^ 1, k0);
        compute(cur);
        __syncthreads();
        cur ^= 1;
    }
    compute(cur);

    const float alpha = coef_base ? coef_base[z * coef_stride] : 1.0f;
    const float* resz = nullptr;
    if (res) {
        if (resB) resz = (z == 0) ? res : ((z == 1) ? resB : resC);
        else      resz = res + z * sRes;
    }
    const float* biasz = bias ? bias + z * sBias : nullptr;
    float* Cfz = Cf ? Cf + (long)z * sC : nullptr;
    __hip_bfloat16* Cbz = Cb ? Cb + (long)z * sC : nullptr;
    #pragma unroll
    for (int i = 0; i < 4; ++i) {
        #pragma unroll
        for (int r = 0; r < 4; ++r) {
            const int row = bm0 + wr * 64 + i * 16 + (lane >> 4) * 4 + r;
            #pragma unroll
            for (int j = 0; j < NJ; ++j) {
                const int col = bn0 + wc * NJ * 16 + j * 16 + lr;
                float val = acc[i][j][r];
                if (biasz) val += biasz[col];
                if (act == 1)
                    val = (val > 20.f) ? val : LN2 * __log2f(1.f + EXP2F(val * LOG2E));
                val *= alpha;
                if (resz) val += resz[(long)row * ldc + col];
                if (Cfz) Cfz[(long)row * ldc + col] = val;
                else     Cbz[(long)row * ldc + col] = __float2bfloat16(val);
            }
        }
    }
}

// ---------------- fused prep: sec->bf16 + weight cvts + conv-wT + A2T ----------------
__global__ __launch_bounds__(256) void prep_kernel(
    const float* __restrict__ a, const float* __restrict__ t, const float* __restrict__ v,
    __hip_bfloat16* __restrict__ sec_bf,
    const float* __restrict__ couple_w, __hip_bfloat16* __restrict__ cw_bf,
    const float* __restrict__ in_w, __hip_bfloat16* __restrict__ inw_bf,
    const float* __restrict__ xproj_w, __hip_bfloat16* __restrict__ xpw_bf,
    const float* __restrict__ dt_w, __hip_bfloat16* __restrict__ dtw_bf,
    const float* __restrict__ out_w, __hip_bfloat16* __restrict__ outw_bf,
    const float* __restrict__ conv_w, float* __restrict__ cwT,
    const float* __restrict__ A_log, float* __restrict__ A2T)
{
    long idx = (long)blockIdx.x * 256 + threadIdx.x;
    if (idx < 1572864) {
        const int m = (int)(idx >> 19);
        const long off = idx & 524287;
        const float* sec = (m == 0) ? a : (m == 1) ? t : v;
        float4 sv = ((const float4*)sec)[off];
        short4v s;
        s.x = f2bf(sv.x); s.y = f2bf(sv.y); s.z = f2bf(sv.z); s.w = f2bf(sv.w);
        ((short4v*)sec_bf)[idx] = s;
        return;
    }
    idx -= 1572864;
    if (idx < 1449984) {
        const float* s; __hip_bfloat16* d; long off = idx;
        if      (off < 196608)              { s = couple_w; d = cw_bf; }
        else if ((off -= 196608) < 786432)  { s = in_w;     d = inw_bf; }
        else if ((off -= 786432) < 49152)   { s = xproj_w;  d = xpw_bf; }
        else if ((off -= 49152) < 24576)    { s = dt_w;     d = dtw_bf; }
        else    { off -= 24576;               s = out_w;    d = outw_bf; }
        float4 vv = ((const float4*)s)[off];
        short4v o;
        o.x = f2bf(vv.x); o.y = f2bf(vv.y); o.z = f2bf(vv.z); o.w = f2bf(vv.w);
        ((short4v*)d)[off] = o;
        return;
    }
    idx -= 1449984;
    if (idx < 12288) {
        const int k = (int)(idx & 3);
        const int c = (int)((idx >> 2) & 1023);
        const int m = (int)(idx >> 12);
        cwT[(m * DCONV + k) * DINNER + c] = conv_w[idx];
        return;
    }
    idx -= 12288;
    if (idx < 49152) {
        const int c = (int)(idx & 1023);
        const int n = (int)((idx >> 10) & 15);
        const int m = (int)(idx >> 14);
        A2T[idx] = -EXP2F(A_log[((long)m * DINNER + c) * NSTATE + n] * LOG2E) * LOG2E;
    }
}

// ---------------- LayerNorm: f32 in -> bf16 out ----------------
__global__ __launch_bounds__(256) void ln_kernel(const float* __restrict__ x, __hip_bfloat16* __restrict__ xn,
                                                 const float* __restrict__ nw, const float* __restrict__ nb)
{
    const int row = blockIdx.x;
    const int m = row >> 12;
    const int tid = threadIdx.x;
    const float2 v = *reinterpret_cast<const float2*>(x + (long)row * DMODEL + tid * 2);
    float s = v.x + v.y;
    float sq = v.x * v.x + v.y * v.y;
    #pragma unroll
    for (int off = 32; off > 0; off >>= 1) {
        s  += __shfl_down(s, off);
        sq += __shfl_down(sq, off);
    }
    __shared__ float ws_s[4], ws_q[4];
    const int wid = tid >> 6, lane = tid & 63;
    if (lane == 0) { ws_s[wid] = s; ws_q[wid] = sq; }
    __syncthreads();
    if (tid == 0) {
        float ts = ws_s[0] + ws_s[1] + ws_s[2] + ws_s[3];
        float tq = ws_q[0] + ws_q[1] + ws_q[2] + ws_q[3];
        float mu = ts / DMODEL;
        float var = tq / DMODEL - mu * mu;
        ws_s[0] = mu;
        ws_q[0] = rsqrtf(var + 1e-5f);
    }
    __syncthreads();
    const float mu = ws_s[0], rstd = ws_q[0];
    const int e0 = tid * 2;
    float2 w  = *reinterpret_cast<const float2*>(nw + m * DMODEL + e0);
    float2 bb = *reinterpret_cast<const float2*>(nb + m * DMODEL + e0);
    short2v o;
    o.x = f2bf((v.x - mu) * rstd * w.x + bb.x);
    o.y = f2bf((v.y - mu) * rstd * w.y + bb.y);
    *reinterpret_cast<short2v*>((short*)xn + (long)row * DMODEL + e0) = o;
}

// ---------------- depthwise causal conv(4) + SiLU ----------------
__global__ __launch_bounds__(256) void conv_silu_kernel(const __hip_bfloat16* __restrict__ xz,
    const float* __restrict__ cwT, const float* __restrict__ cb, __hip_bfloat16* __restrict__ xc)
{
    const int idx = blockIdx.x * 256 + threadIdx.x;   // < 6*256*128 = 196608
    const int c8 = idx & 127;
    const int lt = (idx >> 7) & 255;
    const int mb = idx >> 15;
    const int m  = mb >> 1;
    const int c0 = c8 * 8;
    const int l0 = lt * 8;

    float4 wlo[DCONV], whi[DCONV];
    #pragma unroll
    for (int k = 0; k < DCONV; ++k) {
        wlo[k] = *(const float4*)&cwT[(m * DCONV + k) * DINNER + c0];
        whi[k] = *(const float4*)&cwT[(m * DCONV + k) * DINNER + c0 + 4];
    }
    const float4 blo = *(const float4*)&cb[m * DINNER + c0];
    const float4 bhi = *(const float4*)&cb[m * DINNER + c0 + 4];

    const short* base = (const short*)xz + (long)mb * LSEQ * 2048 + c0;
    short* obase = (short*)xc + (long)mb * LSEQ * DINNER + c0;

    short8v r0 = {}, r1 = {}, r2 = {};
    if (l0 - 3 >= 0) r0 = *(const short8v*)(base + (long)(l0 - 3) * 2048);
    if (l0 - 2 >= 0) r1 = *(const short8v*)(base + (long)(l0 - 2) * 2048);
    if (l0 - 1 >= 0) r2 = *(const short8v*)(base + (long)(l0 - 1) * 2048);

    #pragma unroll
    for (int i = 0; i < 8; ++i) {
        const short8v cur = *(const short8v*)(base + (long)(l0 + i) * 2048);
        float acc[8];
        #pragma unroll
        for (int j = 0; j < 4; ++j) {
            acc[j]     = ((const float*)&blo)[j];
            acc[4 + j] = ((const float*)&bhi)[j];
        }
        #pragma unroll
        for (int j = 0; j < 8; ++j) {
            const float w0 = (j < 4) ? ((const float*)&wlo[0])[j] : ((const float*)&whi[0])[j - 4];
            const float w1 = (j < 4) ? ((const float*)&wlo[1])[j] : ((const float*)&whi[1])[j - 4];
            const float w2 = (j < 4) ? ((const float*)&wlo[2])[j] : ((const float*)&whi[2])[j - 4];
            const float w3 = (j < 4) ? ((const float*)&wlo[3])[j] : ((const float*)&whi[3])[j - 4];
            acc[j] += w0 * bf2f(r0[j]) + w1 * bf2f(r1[j]) + w2 * bf2f(r2[j]) + w3 * bf2f(cur[j]);
        }
        short8v o;
        #pragma unroll
        for (int j = 0; j < 8; ++j)
            o[j] = f2bf(acc[j] * sigmoid_f(acc[j]));
        *(short8v*)(obase + (long)(l0 + i) * DINNER) = o;
        r0 = r1; r1 = r2; r2 = cur;
    }
}

// ---------------- chunk-parallel selective scan (bf16 activations) ----------------
__device__ __forceinline__ bool geo_check(const float* A2) {
    bool g = true;
    #pragma unroll
    for (int n = 1; n < NSTATE; ++n)
        g = g && (__builtin_fabsf(A2[n] - (float)(n + 1) * A2[0]) <= 1e-4f * __builtin_fabsf(A2[n]));
    return g;
}

// Pass 1: local scan -> F states + per-chunk delta-sum (decay recomputed in pass2)
__global__ __launch_bounds__(256) void scan_pass1_kernel(
    const __hip_bfloat16* __restrict__ delta, const __hip_bfloat16* __restrict__ xc,
    const __hip_bfloat16* __restrict__ dbc, const float* __restrict__ A2T,
    float* __restrict__ Fbuf, float* __restrict__ sumd)
{
    const int bx = blockIdx.x;             // mb(6) x cg(4) x chunk(64)
    const int chunk = bx & (NCHUNK - 1);
    const int cg = (bx >> 6) & 3;
    const int mb = bx >> 8;
    const int m = mb >> 1, b = mb & 1;
    const int tid = threadIdx.x;
    const int c = cg * 256 + tid;

    float A2[NSTATE];
    #pragma unroll
    for (int n = 0; n < NSTATE; ++n)
        A2[n] = A2T[((long)m * NSTATE + n) * DINNER + c];
    const bool geo = geo_check(A2);
    float h[NSTATE] = {};
    float sum_d = 0.f;

    __shared__ float sB[CHUNK][NSTATE];
    const short* dbc_mb = (const short*)dbc + (long)m * MROWS * 64 + (long)b * LSEQ * 64;
    const int t0 = chunk * CHUNK;
    for (int i = tid; i < CHUNK * NSTATE; i += 256) {
        int tt = i >> 4, j = i & 15;
        sB[tt][j] = bf2f(dbc_mb[(long)(t0 + tt) * 64 + 32 + j]);
    }
    __syncthreads();

    const short* dp = (const short*)delta;
    const short* up = (const short*)xc;
    const long base = ((long)mb * LSEQ + t0) * DINNER + c;
    if (geo) {
        #pragma unroll 4
        for (int tt = 0; tt < CHUNK; ++tt) {
            const float d = bf2f(dp[base + (long)tt * DINNER]);
            const float u = bf2f(up[base + (long)tt * DINNER]);
            const float du = d * u;
            sum_d += d;
            const float E = EXP2F(d * A2[0]);
            float e = 1.f;
            #pragma unroll
            for (int n = 0; n < NSTATE; ++n) {
                e *= E;
                h[n] = e * h[n] + du * sB[tt][n];
            }
        }
    } else {
        #pragma unroll 4
        for (int tt = 0; tt < CHUNK; ++tt) {
            const float d = bf2f(dp[base + (long)tt * DINNER]);
            const float u = bf2f(up[base + (long)tt * DINNER]);
            const float du = d * u;
            sum_d += d;
            #pragma unroll
            for (int n = 0; n < NSTATE; ++n) {
                float e = EXP2F(d * A2[n]);
                h[n] = e * h[n] + du * sB[tt][n];
            }
        }
    }
    const long ob = ((long)mb * NCHUNK + chunk) * (NSTATE * DINNER) + c;
    #pragma unroll
    for (int n = 0; n < NSTATE; ++n)
        Fbuf[ob + n * DINNER] = h[n];
    sumd[(((long)mb * NCHUNK + chunk) << 10) + c] = sum_d;
}

// Pass 2: sequential chunk combine; decay p = exp2(sum_d * A2[n]) recomputed on the fly
__global__ __launch_bounds__(256) void scan_pass2_kernel(float* __restrict__ Fbuf,
                                                         const float* __restrict__ sumd,
                                                         const float* __restrict__ A2T)
{
    const long idx = (long)blockIdx.x * 256 + threadIdx.x;  // < 6*16*1024
    const int mb = (int)(idx >> 14);
    const int cn = (int)(idx & 16383);        // n*1024 + c
    const int n = cn >> 10;
    const int c = cn & 1023;
    const int m = mb >> 1;
    const float A2n = A2T[((long)m * NSTATE + n) * DINNER + c];
    float run = 0.f;
    #pragma unroll 4
    for (int k = 0; k < NCHUNK; ++k) {
        const long o = ((long)(mb * NCHUNK + k) << 14) + cn;
        const float f = Fbuf[o];
        const float p = EXP2F(sumd[(((long)mb * NCHUNK + k) << 10) + c] * A2n);
        Fbuf[o] = run;
        run = p * run + f;
    }
}

__global__ __launch_bounds__(256) void scan_pass3_kernel(
    const __hip_bfloat16* __restrict__ delta, const __hip_bfloat16* __restrict__ xc,
    const __hip_bfloat16* __restrict__ dbc, __hip_bfloat16* __restrict__ xz,
    const float* __restrict__ A2T, const float* __restrict__ D_skip,
    const float* __restrict__ Hin)
{
    const int bx = blockIdx.x;
    const int chunk = bx & (NCHUNK - 1);
    const int cg = (bx >> 6) & 3;
    const int mb = bx >> 8;
    const int m = mb >> 1, b = mb & 1;
    const int tid = threadIdx.x;
    const int c = cg * 256 + tid;

    float A2[NSTATE];
    #pragma unroll
    for (int n = 0; n < NSTATE; ++n)
        A2[n] = A2T[((long)m * NSTATE + n) * DINNER + c];
    const bool geo = geo_check(A2);
    const float Dsk = D_skip[m * DINNER + c];

    float h[NSTATE];
    const long ho = ((long)mb * NCHUNK + chunk) * (NSTATE * DINNER) + c;
    #pragma unroll
    for (int n = 0; n < NSTATE; ++n) h[n] = Hin[ho + n * DINNER];

    __shared__ float sBC[CHUNK][2 * NSTATE];
    const short* dbc_mb = (const short*)dbc + (long)m * MROWS * 64 + (long)b * LSEQ * 64;
    const int t0 = chunk * CHUNK;
    for (int i = tid; i < CHUNK * 2 * NSTATE; i += 256) {
        int tt = i >> 5, j = i & 31;
        sBC[tt][j] = bf2f(dbc_mb[(long)(t0 + tt) * 64 + 32 + j]);
    }
    __syncthreads();

    const short* dp = (const short*)delta;
    const short* up = (const short*)xc;
    short* xzp = (short*)xz;
    const long base = ((long)mb * LSEQ + t0) * DINNER + c;
    const long xbase = ((long)mb * LSEQ + t0) * 2048 + c;
    if (geo) {
        #pragma unroll 4
        for (int tt = 0; tt < CHUNK; ++tt) {
            const long idx = base + (long)tt * DINNER;
            const long xi  = xbase + (long)tt * 2048;
            const float d = bf2f(dp[idx]);
            const float u = bf2f(up[idx]);
            const float zv = bf2f(xzp[xi + 1024]);
            const float du = d * u;
            const float E = EXP2F(d * A2[0]);
            float e = 1.f;
            float y = 0.f;
            #pragma unroll
            for (int n = 0; n < NSTATE; ++n) {
                e *= E;
                h[n] = e * h[n] + du * sBC[tt][n];
                y += h[n] * sBC[tt][16 + n];
            }
            y += u * Dsk;
            xzp[xi] = f2bf(y * (zv * sigmoid_f(zv)));
        }
    } else {
        #pragma unroll 4
        for (int tt = 0; tt < CHUNK; ++tt) {
            const long idx = base + (long)tt * DINNER;
            const long xi  = xbase + (long)tt * 2048;
            const float d = bf2f(dp[idx]);
            const float u = bf2f(up[idx]);
            const float zv = bf2f(xzp[xi + 1024]);
            const float du = d * u;
            float y = 0.f;
            #pragma unroll
            for (int n = 0; n < NSTATE; ++n) {
                float e = EXP2F(d * A2[n]);
                h[n] = e * h[n] + du * sBC[tt][n];
                y += h[n] * sBC[tt][16 + n];
            }
            y += u * Dsk;
            xzp[xi] = f2bf(y * (zv * sigmoid_f(zv)));
        }
    }
}

extern "C" void kernel_launch(void* const* d_in, const int* in_sizes, int n_in,
                              void* d_out, int out_size, void* d_ws, size_t ws_size,
                              hipStream_t stream)
{
    const float* v       = (const float*)d_in[0];
    const float* a       = (const float*)d_in[1];
    const float* t       = (const float*)d_in[2];
    const float* norm_w  = (const float*)d_in[3];
    const float* norm_b  = (const float*)d_in[4];
    const float* in_w    = (const float*)d_in[5];
    const float* conv_w  = (const float*)d_in[6];
    const float* conv_b  = (const float*)d_in[7];
    const float* xproj_w = (const float*)d_in[8];
    const float* dt_w    = (const float*)d_in[9];
    const float* dt_b    = (const float*)d_in[10];
    const float* A_log   = (const float*)d_in[11];
    const float* D_skip  = (const float*)d_in[12];
    const float* out_w   = (const float*)d_in[13];
    const float* couple_w= (const float*)d_in[14];
    const float* coef    = (const float*)d_in[15];
    float* out = (float*)d_out;

    typedef __hip_bfloat16 bf;
    float* x_in   = (float*)d_ws;                       // [3][4096][512] f32
    bf* xn_bf     = (bf*)(x_in + 6291456);              // [3][4096][512]
    bf* sec_bf    = xn_bf + 6291456;                    // [3][4096][512]
    bf* xz_bf     = sec_bf + 6291456;                   // [3][4096][2048]  (xc-pre | z; later y | z)
    bf* xc_bf     = xz_bf + 25165824;                   // [3][4096][1024]
    bf* delta_bf  = xc_bf + 12582912;                   // [3][4096][1024]
    bf* dbc_bf    = delta_bf + 12582912;                // [3][4096][64]
    bf* cw_bf     = dbc_bf + 786432;                    // [3][512][512]
    bf* inw_bf    = cw_bf + 786432;                     // [3][2048][512]
    bf* xpw_bf    = inw_bf + 3145728;                   // [3][64][1024]
    bf* dtw_bf    = xpw_bf + 196608;                    // [3][1024][32]
    bf* outw_bf   = dtw_bf + 98304;                     // [3][512][1024]
    float* cwT    = (float*)(outw_bf + 1572864);        // [3][4][1024] f32
    float* A2T    = cwT + 12288;                        // [3][16][1024] f32
    float* Fbuf   = A2T + 49152;                        // [6][64][16][1024] f32
    float* sumd   = Fbuf + 6291456;                     // [6][64][1024] f32 (ws; total 191.2 MiB)

    dim3 blk(256);

    // 0. fused prep
    prep_kernel<<<(1572864 + 1449984 + 12288 + 49152 + 255) / 256, blk, 0, stream>>>(
        a, t, v, sec_bf, couple_w, cw_bf, in_w, inw_bf, xproj_w, xpw_bf,
        dt_w, dtw_bf, out_w, outw_bf, conv_w, cwT, A_log, A2T);

    // 1. coupling (merged z=3): x_in[z] = prim[z] + coef[z] * sec_bf[z] @ cw[z]^T
    gemm_bf16<2, 32><<<dim3(32, 8, 3), blk, 0, stream>>>(
        sec_bf, cw_bf, 512, 512, 512, 2097152L, 262144L,
        x_in, nullptr, 512, 2097152L,
        v, 0L, a, t, coef, 1, nullptr, 0L, 0);
    // 2. layernorm -> bf16
    ln_kernel<<<3*4096, blk, 0, stream>>>(x_in, xn_bf, norm_w, norm_b);
    // 3. in_proj (both halves, N=2048) -> xz
    gemm_bf16<4, 32><<<dim3(32, 16, 3), blk, 0, stream>>>(
        xn_bf, inw_bf, 512, 512, 512, 2097152L, 1048576L,
        nullptr, xz_bf, 2048, 8388608L, nullptr, 0L, nullptr, nullptr, nullptr, 0, nullptr, 0L, 0);
    // 4. conv + SiLU
    conv_silu_kernel<<<768, blk, 0, stream>>>(xz_bf, cwT, conv_b, xc_bf);
    // 5. x_proj -> dbc bf16
    gemm_bf16<2, 32><<<dim3(32, 1, 3), blk, 0, stream>>>(
        xc_bf, xpw_bf, 1024, 1024, 1024, 4194304L, 65536L,
        nullptr, dbc_bf, 64, 262144L, nullptr, 0L, nullptr, nullptr, nullptr, 0, nullptr, 0L, 0);
    // 6. delta = softplus(dt @ dt_w^T + dt_b) -> bf16
    gemm_bf16<4, 32><<<dim3(32, 8, 3), blk, 0, stream>>>(
        dbc_bf, dtw_bf, 32, 64, 32, 262144L, 32768L,
        nullptr, delta_bf, 1024, 4194304L, nullptr, 0L, nullptr, nullptr, nullptr, 0, dt_b, 1024L, 1);
    // 7. chunk-parallel scan (decay recomputed from sum_d in pass2; all scratch in d_ws)
    scan_pass1_kernel<<<6*4*NCHUNK, blk, 0, stream>>>(delta_bf, xc_bf, dbc_bf, A2T, Fbuf, sumd);
    scan_pass2_kernel<<<(6*1024*16)/256, blk, 0, stream>>>(Fbuf, sumd, A2T);
    scan_pass3_kernel<<<6*4*NCHUNK, blk, 0, stream>>>(delta_bf, xc_bf, dbc_bf, xz_bf,
                                                      A2T, D_skip, Fbuf);
    // 8. out_proj + residual -> d_out
    gemm_bf16<2, 32><<<dim3(32, 8, 3), blk, 0, stream>>>(
        xz_bf, outw_bf, 1024, 2048, 1024, 8388608L, 524288L,
        out, nullptr, 512, 2097152L, x_in, 2097152L, nullptr, nullptr, nullptr, 0, nullptr, 0L, 0);
}

// Round 17
// 259.927 us; speedup vs baseline: 1.3150x; 1.0364x over previous
//
#include <hip/hip_runtime.h>
#include <hip/hip_bf16.h>

#define MODS 3
#define BSZ 2
#define LSEQ 2048
#define DMODEL 512
#define DINNER 1024
#define DTRANK 32
#define NSTATE 16
#define DCONV 4
#define MROWS (BSZ*LSEQ)   // 4096
#define NCHUNK 64
#define CHUNK 32           // LSEQ / NCHUNK

#define LOG2E 1.44269504088896f
#define LN2   0.69314718055995f

typedef __attribute__((ext_vector_type(8))) short short8v;
typedef __attribute__((ext_vector_type(4))) short short4v;
typedef __attribute__((ext_vector_type(2))) short short2v;
typedef __attribute__((ext_vector_type(4))) float f32x4;

#if __has_builtin(__builtin_amdgcn_exp2f)
#define EXP2F __builtin_amdgcn_exp2f
#else
#define EXP2F exp2f
#endif
#if __has_builtin(__builtin_amdgcn_rcpf)
#define RCPF __builtin_amdgcn_rcpf
#else
#define RCPF(x) (1.0f / (x))
#endif

__device__ __forceinline__ short f2bf(float x) {
    __hip_bfloat16 h = __float2bfloat16(x);
    return __builtin_bit_cast(short, h);
}
__device__ __forceinline__ float bf2f(short s) {
    return __uint_as_float(((unsigned)(unsigned short)s) << 16);
}
__device__ __forceinline__ void gl_lds16(const short* g, short* l) {
    __builtin_amdgcn_global_load_lds(
        (const __attribute__((address_space(1))) unsigned int*)g,
        (__attribute__((address_space(3))) unsigned int*)l, 16, 0, 0);
}
__device__ __forceinline__ float sigmoid_f(float x) {
    return RCPF(1.f + EXP2F(-x * LOG2E));
}

// ============ 8-phase 256x256 pipelined GEMM for in_proj (M=4096,N=2048,K=512) ======
// 512 threads = 8 waves (2 row x 4 col). BK=64, 2 LDS buffers (128 KiB).
// Per phase: stage(next half) -> counted vmcnt -> s_barrier (ALL waves drained ->
// the half THIS phase reads is fully visible) -> ds_read -> MFMA -> s_barrier.
// Counted waits: steady vmcnt(6); last tile 4/2/0; P3 re-reads an old half (no wait).
#define MFMAQ(QR, QC)                                                              \
    _Pragma("unroll")                                                              \
    for (int rf = 0; rf < 4; ++rf)                                                 \
        _Pragma("unroll")                                                          \
        for (int cf = 0; cf < 2; ++cf)                                             \
            _Pragma("unroll")                                                      \
            for (int kh = 0; kh < 2; ++kh)                                         \
                acc[QR][QC][rf][cf] = __builtin_amdgcn_mfma_f32_16x16x32_bf16(     \
                    afr[rf][kh], bfr[cf][kh], acc[QR][QC][rf][cf], 0, 0, 0);

__global__ __launch_bounds__(512, 2) void gemm8p_inproj(
    const __hip_bfloat16* __restrict__ A_, const __hip_bfloat16* __restrict__ B_,
    __hip_bfloat16* __restrict__ C_)
{
    constexpr int NT = 8;                 // K=512 / BK=64
    __shared__ alignas(16) short As[2 * 16384];   // 2 buf x [256 rows][64 k]
    __shared__ alignas(16) short Bs[2 * 16384];
    const int z = blockIdx.z;
    const int bm0 = blockIdx.x * 256;
    const int bn0 = blockIdx.y * 256;
    const short* Ag = (const short*)A_ + (long)z * 2097152 + (long)bm0 * 512;
    const short* Bg = (const short*)B_ + (long)z * 1048576 + (long)bn0 * 512;
    short* Cg = (short*)C_ + (long)z * 8388608;
    const int tid = threadIdx.x;
    const int lane = tid & 63;
    const int w = tid >> 6;               // 0..7
    const int wr = w >> 2;                // 0..1
    const int wc = w & 3;                 // 0..3
    const int lr = lane & 15;
    const int sidx = lane >> 4;           // 0..3
    const int srow_l = tid >> 3;          // 0..63
    const int sgoff = ((tid & 7) ^ (srow_l & 7)) * 8;   // pre-swizzled global slot

    f32x4 acc[2][2][4][2];
    #pragma unroll
    for (int a = 0; a < 2; ++a)
        #pragma unroll
        for (int b = 0; b < 2; ++b)
            #pragma unroll
            for (int c = 0; c < 4; ++c)
                #pragma unroll
                for (int d = 0; d < 2; ++d)
                    acc[a][b][c][d] = (f32x4){0.f, 0.f, 0.f, 0.f};

    short8v afr[4][2];
    short8v bfr[2][2];

    auto stageA = [&](int buf, int half, int t) {
        #pragma unroll
        for (int j = 0; j < 2; ++j) {
            const int row = half * 128 + j * 64 + srow_l;
            gl_lds16(Ag + (long)row * 512 + t * 64 + sgoff,
                     As + buf * 16384 + half * 8192 + j * 4096 + tid * 8);
        }
    };
    auto stageB = [&](int buf, int half, int t) {
        #pragma unroll
        for (int j = 0; j < 2; ++j) {
            const int row = half * 128 + j * 64 + srow_l;
            gl_lds16(Bg + (long)row * 512 + t * 64 + sgoff,
                     Bs + buf * 16384 + half * 8192 + j * 4096 + tid * 8);
        }
    };
    auto loadA = [&](int buf, int qr) {
        #pragma unroll
        for (int rf = 0; rf < 4; ++rf)
            #pragma unroll
            for (int kh = 0; kh < 2; ++kh) {
                const int ra = qr * 128 + wr * 64 + rf * 16 + lr;
                const int g = kh * 4 + sidx;
                afr[rf][kh] = *(const short8v*)&As[buf * 16384 + ra * 64 + ((g ^ (ra & 7)) << 3)];
            }
    };
    auto loadB = [&](int buf, int qc) {
        #pragma unroll
        for (int cf = 0; cf < 2; ++cf)
            #pragma unroll
            for (int kh = 0; kh < 2; ++kh) {
                const int rb = qc * 128 + wc * 32 + cf * 16 + lr;
                const int g = kh * 4 + sidx;
                bfr[cf][kh] = *(const short8v*)&Bs[buf * 16384 + rb * 64 + ((g ^ (rb & 7)) << 3)];
            }
    };

    // prologue: stage tile 0 (queue order Ah0, Bh0, Ah1, Bh1; 8 loads/wave)
    stageA(0, 0, 0); stageB(0, 0, 0); stageA(0, 1, 0); stageB(0, 1, 0);

    for (int t = 0; t < NT; ++t) {
        const int p = t & 1;
        const bool stg = (t + 1) < NT;
        // ---- P0: quadrant (0,0), reads A-h0 + B-h0 of tile t
        if (stg) { stageA(p ^ 1, 0, t + 1);
                   asm volatile("s_waitcnt vmcnt(6)" ::: "memory"); }
        else       asm volatile("s_waitcnt vmcnt(4)" ::: "memory");
        asm volatile("s_barrier" ::: "memory");
        loadA(p, 0); loadB(p, 0);
        MFMAQ(0, 0)
        asm volatile("s_barrier" ::: "memory");
        // ---- P1: quadrant (1,0), reads A-h1 (B-h0 in regs)
        if (stg) { stageB(p ^ 1, 0, t + 1);
                   asm volatile("s_waitcnt vmcnt(6)" ::: "memory"); }
        else       asm volatile("s_waitcnt vmcnt(2)" ::: "memory");
        asm volatile("s_barrier" ::: "memory");
        loadA(p, 1);
        MFMAQ(1, 0)
        asm volatile("s_barrier" ::: "memory");
        // ---- P2: quadrant (1,1), reads B-h1 (A-h1 in regs)
        if (stg) { stageA(p ^ 1, 1, t + 1);
                   asm volatile("s_waitcnt vmcnt(6)" ::: "memory"); }
        else       asm volatile("s_waitcnt vmcnt(0)" ::: "memory");
        asm volatile("s_barrier" ::: "memory");
        loadB(p, 1);
        MFMAQ(1, 1)
        asm volatile("s_barrier" ::: "memory");
        // ---- P3: quadrant (0,1), re-reads A-h0 (already visible since P0)
        if (stg) stageB(p ^ 1, 1, t + 1);
        asm volatile("s_barrier" ::: "memory");
        loadA(p, 0);
        MFMAQ(0, 1)
        asm volatile("s_barrier" ::: "memory");
    }

    // epilogue: C bf16, ldc = 2048
    #pragma unroll
    for (int qr = 0; qr < 2; ++qr)
        #pragma unroll
        for (int qc = 0; qc < 2; ++qc)
            #pragma unroll
            for (int rf = 0; rf < 4; ++rf)
                #pragma unroll
                for (int r = 0; r < 4; ++r) {
                    const int row = bm0 + qr * 128 + wr * 64 + rf * 16 + (lane >> 4) * 4 + r;
                    #pragma unroll
                    for (int cf = 0; cf < 2; ++cf) {
                        const int col = bn0 + qc * 128 + wc * 32 + cf * 16 + lr;
                        Cg[(long)row * 2048 + col] = f2bf(acc[qr][qc][rf][cf][r]);
                    }
                }
}

// ---------------- bf16 MFMA GEMM NT, BK=32, XOR-swizzled LDS, 2-phase prefetch dbuf ----
template<int NJ, int BK>
__global__ __launch_bounds__(256) void gemm_bf16(
    const __hip_bfloat16* __restrict__ A_, const __hip_bfloat16* __restrict__ B_,
    int K, int lda, int ldb, long sA, long sB,
    float* __restrict__ Cf, __hip_bfloat16* __restrict__ Cb, int ldc, long sC,
    const float* __restrict__ res, long sRes,
    const float* __restrict__ resB, const float* __restrict__ resC,
    const float* __restrict__ coef_base, int coef_stride,
    const float* __restrict__ bias, long sBias, int act)
{
    constexpr int BN = NJ * 32;
    constexpr int ASZ = 128 * BK;
    constexpr int BSZe = BN * BK;
    __shared__ alignas(16) short As[2 * ASZ];
    __shared__ alignas(16) short Bs[2 * BSZe];
    const int z = blockIdx.z;
    const int bm0 = blockIdx.x * 128;
    const int bn0 = blockIdx.y * BN;
    const short* Ag = (const short*)A_ + z * sA + (long)bm0 * lda;
    const short* Bg = (const short*)B_ + z * sB + (long)bn0 * ldb;
    const int tid = threadIdx.x;
    const int lane = tid & 63;
    const int w = tid >> 6;
    const int wr = w >> 1, wc = w & 1;
    const int lr = lane & 15;
    const int sidx = lane >> 4;

    constexpr int SLOTS = BK / 8;
    const int srow = tid / SLOTS;
    const int sslot = tid % SLOTS;
    int swz;
    if constexpr (BK == 64) swz = srow & 7;
    else                    swz = (srow >> 1) & 3;
    const int sgcol = (sslot ^ swz) * 8;
    int fA;
    if constexpr (BK == 64) fA = lr & 7;
    else                    fA = (lr >> 1) & 3;

    constexpr int AINSTR = ASZ / 2048;
    constexpr int BINSTR = BSZe / 2048;
    constexpr int RPI = 2048 / BK;

    f32x4 acc[4][NJ];
    #pragma unroll
    for (int i = 0; i < 4; ++i)
        #pragma unroll
        for (int j = 0; j < NJ; ++j)
            acc[i][j] = (f32x4){0.f, 0.f, 0.f, 0.f};

    auto stage = [&](int buf, int k0) {
        #pragma unroll
        for (int i = 0; i < AINSTR; ++i)
            gl_lds16(Ag + (long)(i * RPI + srow) * lda + k0 + sgcol,
                     As + buf * ASZ + i * 2048 + tid * 8);
        #pragma unroll
        for (int i = 0; i < BINSTR; ++i)
            gl_lds16(Bg + (long)(i * RPI + srow) * ldb + k0 + sgcol,
                     Bs + buf * BSZe + i * 2048 + tid * 8);
    };
    auto compute = [&](int buf) {
        #pragma unroll
        for (int kh = 0; kh < BK / 32; ++kh) {
            const int sl = ((kh * 4 + sidx) ^ fA) * 8;
            short8v af[4], bfr2[NJ];
            #pragma unroll
            for (int i = 0; i < 4; ++i)
                af[i] = *(const short8v*)&As[buf * ASZ + (wr * 64 + i * 16 + lr) * BK + sl];
            #pragma unroll
            for (int j = 0; j < NJ; ++j)
                bfr2[j] = *(const short8v*)&Bs[buf * BSZe + (wc * NJ * 16 + j * 16 + lr) * BK + sl];
            #pragma unroll
            for (int i = 0; i < 4; ++i)
                #pragma unroll
                for (int j = 0; j < NJ; ++j)
                    acc[i][j] = __builtin_amdgcn_mfma_f32_16x16x32_bf16(af[i], bfr2[j], acc[i][j], 0, 0, 0);
        }
    };

    stage(0, 0);
    __syncthreads();
    int cur = 0;
    for (int k0 = BK; k0 < K; k0 += BK) {
        stage(cur ^ 1, k0);
        compute(cur);
        __syncthreads();
        cur ^= 1;
    }
    compute(cur);

    const float alpha = coef_base ? coef_base[z * coef_stride] : 1.0f;
    const float* resz = nullptr;
    if (res) {
        if (resB) resz = (z == 0) ? res : ((z == 1) ? resB : resC);
        else      resz = res + z * sRes;
    }
    const float* biasz = bias ? bias + z * sBias : nullptr;
    float* Cfz = Cf ? Cf + (long)z * sC : nullptr;
    __hip_bfloat16* Cbz = Cb ? Cb + (long)z * sC : nullptr;
    #pragma unroll
    for (int i = 0; i < 4; ++i) {
        #pragma unroll
        for (int r = 0; r < 4; ++r) {
            const int row = bm0 + wr * 64 + i * 16 + (lane >> 4) * 4 + r;
            #pragma unroll
            for (int j = 0; j < NJ; ++j) {
                const int col = bn0 + wc * NJ * 16 + j * 16 + lr;
                float val = acc[i][j][r];
                if (biasz) val += biasz[col];
                if (act == 1)
                    val = (val > 20.f) ? val : LN2 * __log2f(1.f + EXP2F(val * LOG2E));
                val *= alpha;
                if (resz) val += resz[(long)row * ldc + col];
                if (Cfz) Cfz[(long)row * ldc + col] = val;
                else     Cbz[(long)row * ldc + col] = __float2bfloat16(val);
            }
        }
    }
}

// ---------------- fused prep: sec->bf16 + weight cvts + conv-wT + A2T ----------------
__global__ __launch_bounds__(256) void prep_kernel(
    const float* __restrict__ a, const float* __restrict__ t, const float* __restrict__ v,
    __hip_bfloat16* __restrict__ sec_bf,
    const float* __restrict__ couple_w, __hip_bfloat16* __restrict__ cw_bf,
    const float* __restrict__ in_w, __hip_bfloat16* __restrict__ inw_bf,
    const float* __restrict__ xproj_w, __hip_bfloat16* __restrict__ xpw_bf,
    const float* __restrict__ dt_w, __hip_bfloat16* __restrict__ dtw_bf,
    const float* __restrict__ out_w, __hip_bfloat16* __restrict__ outw_bf,
    const float* __restrict__ conv_w, float* __restrict__ cwT,
    const float* __restrict__ A_log, float* __restrict__ A2T)
{
    long idx = (long)blockIdx.x * 256 + threadIdx.x;
    if (idx < 1572864) {
        const int m = (int)(idx >> 19);
        const long off = idx & 524287;
        const float* sec = (m == 0) ? a : (m == 1) ? t : v;
        float4 sv = ((const float4*)sec)[off];
        short4v s;
        s.x = f2bf(sv.x); s.y = f2bf(sv.y); s.z = f2bf(sv.z); s.w = f2bf(sv.w);
        ((short4v*)sec_bf)[idx] = s;
        return;
    }
    idx -= 1572864;
    if (idx < 1449984) {
        const float* s; __hip_bfloat16* d; long off = idx;
        if      (off < 196608)              { s = couple_w; d = cw_bf; }
        else if ((off -= 196608) < 786432)  { s = in_w;     d = inw_bf; }
        else if ((off -= 786432) < 49152)   { s = xproj_w;  d = xpw_bf; }
        else if ((off -= 49152) < 24576)    { s = dt_w;     d = dtw_bf; }
        else    { off -= 24576;               s = out_w;    d = outw_bf; }
        float4 vv = ((const float4*)s)[off];
        short4v o;
        o.x = f2bf(vv.x); o.y = f2bf(vv.y); o.z = f2bf(vv.z); o.w = f2bf(vv.w);
        ((short4v*)d)[off] = o;
        return;
    }
    idx -= 1449984;
    if (idx < 12288) {
        const int k = (int)(idx & 3);
        const int c = (int)((idx >> 2) & 1023);
        const int m = (int)(idx >> 12);
        cwT[(m * DCONV + k) * DINNER + c] = conv_w[idx];
        return;
    }
    idx -= 12288;
    if (idx < 49152) {
        const int c = (int)(idx & 1023);
        const int n = (int)((idx >> 10) & 15);
        const int m = (int)(idx >> 14);
        A2T[idx] = -EXP2F(A_log[((long)m * DINNER + c) * NSTATE + n] * LOG2E) * LOG2E;
    }
}

// ---------------- LayerNorm: f32 in -> bf16 out ----------------
__global__ __launch_bounds__(256) void ln_kernel(const float* __restrict__ x, __hip_bfloat16* __restrict__ xn,
                                                 const float* __restrict__ nw, const float* __restrict__ nb)
{
    const int row = blockIdx.x;
    const int m = row >> 12;
    const int tid = threadIdx.x;
    const float2 v = *reinterpret_cast<const float2*>(x + (long)row * DMODEL + tid * 2);
    float s = v.x + v.y;
    float sq = v.x * v.x + v.y * v.y;
    #pragma unroll
    for (int off = 32; off > 0; off >>= 1) {
        s  += __shfl_down(s, off);
        sq += __shfl_down(sq, off);
    }
    __shared__ float ws_s[4], ws_q[4];
    const int wid = tid >> 6, lane = tid & 63;
    if (lane == 0) { ws_s[wid] = s; ws_q[wid] = sq; }
    __syncthreads();
    if (tid == 0) {
        float ts = ws_s[0] + ws_s[1] + ws_s[2] + ws_s[3];
        float tq = ws_q[0] + ws_q[1] + ws_q[2] + ws_q[3];
        float mu = ts / DMODEL;
        float var = tq / DMODEL - mu * mu;
        ws_s[0] = mu;
        ws_q[0] = rsqrtf(var + 1e-5f);
    }
    __syncthreads();
    const float mu = ws_s[0], rstd = ws_q[0];
    const int e0 = tid * 2;
    float2 w  = *reinterpret_cast<const float2*>(nw + m * DMODEL + e0);
    float2 bb = *reinterpret_cast<const float2*>(nb + m * DMODEL + e0);
    short2v o;
    o.x = f2bf((v.x - mu) * rstd * w.x + bb.x);
    o.y = f2bf((v.y - mu) * rstd * w.y + bb.y);
    *reinterpret_cast<short2v*>((short*)xn + (long)row * DMODEL + e0) = o;
}

// ---------------- depthwise causal conv(4) + SiLU ----------------
__global__ __launch_bounds__(256) void conv_silu_kernel(const __hip_bfloat16* __restrict__ xz,
    const float* __restrict__ cwT, const float* __restrict__ cb, __hip_bfloat16* __restrict__ xc)
{
    const int idx = blockIdx.x * 256 + threadIdx.x;   // < 6*256*128 = 196608
    const int c8 = idx & 127;
    const int lt = (idx >> 7) & 255;
    const int mb = idx >> 15;
    const int m  = mb >> 1;
    const int c0 = c8 * 8;
    const int l0 = lt * 8;

    float4 wlo[DCONV], whi[DCONV];
    #pragma unroll
    for (int k = 0; k < DCONV; ++k) {
        wlo[k] = *(const float4*)&cwT[(m * DCONV + k) * DINNER + c0];
        whi[k] = *(const float4*)&cwT[(m * DCONV + k) * DINNER + c0 + 4];
    }
    const float4 blo = *(const float4*)&cb[m * DINNER + c0];
    const float4 bhi = *(const float4*)&cb[m * DINNER + c0 + 4];

    const short* base = (const short*)xz + (long)mb * LSEQ * 2048 + c0;
    short* obase = (short*)xc + (long)mb * LSEQ * DINNER + c0;

    short8v r0 = {}, r1 = {}, r2 = {};
    if (l0 - 3 >= 0) r0 = *(const short8v*)(base + (long)(l0 - 3) * 2048);
    if (l0 - 2 >= 0) r1 = *(const short8v*)(base + (long)(l0 - 2) * 2048);
    if (l0 - 1 >= 0) r2 = *(const short8v*)(base + (long)(l0 - 1) * 2048);

    #pragma unroll
    for (int i = 0; i < 8; ++i) {
        const short8v cur = *(const short8v*)(base + (long)(l0 + i) * 2048);
        float acc[8];
        #pragma unroll
        for (int j = 0; j < 4; ++j) {
            acc[j]     = ((const float*)&blo)[j];
            acc[4 + j] = ((const float*)&bhi)[j];
        }
        #pragma unroll
        for (int j = 0; j < 8; ++j) {
            const float w0 = (j < 4) ? ((const float*)&wlo[0])[j] : ((const float*)&whi[0])[j - 4];
            const float w1 = (j < 4) ? ((const float*)&wlo[1])[j] : ((const float*)&whi[1])[j - 4];
            const float w2 = (j < 4) ? ((const float*)&wlo[2])[j] : ((const float*)&whi[2])[j - 4];
            const float w3 = (j < 4) ? ((const float*)&wlo[3])[j] : ((const float*)&whi[3])[j - 4];
            acc[j] += w0 * bf2f(r0[j]) + w1 * bf2f(r1[j]) + w2 * bf2f(r2[j]) + w3 * bf2f(cur[j]);
        }
        short8v o;
        #pragma unroll
        for (int j = 0; j < 8; ++j)
            o[j] = f2bf(acc[j] * sigmoid_f(acc[j]));
        *(short8v*)(obase + (long)(l0 + i) * DINNER) = o;
        r0 = r1; r1 = r2; r2 = cur;
    }
}

// ---------------- chunk-parallel selective scan (bf16 activations) ----------------
__device__ __forceinline__ bool geo_check(const float* A2) {
    bool g = true;
    #pragma unroll
    for (int n = 1; n < NSTATE; ++n)
        g = g && (__builtin_fabsf(A2[n] - (float)(n + 1) * A2[0]) <= 1e-4f * __builtin_fabsf(A2[n]));
    return g;
}

__global__ __launch_bounds__(256) void scan_pass1_kernel(
    const __hip_bfloat16* __restrict__ delta, const __hip_bfloat16* __restrict__ xc,
    const __hip_bfloat16* __restrict__ dbc, const float* __restrict__ A2T,
    float* __restrict__ Fbuf, float* __restrict__ sumd)
{
    const int bx = blockIdx.x;             // mb(6) x cg(4) x chunk(64)
    const int chunk = bx & (NCHUNK - 1);
    const int cg = (bx >> 6) & 3;
    const int mb = bx >> 8;
    const int m = mb >> 1, b = mb & 1;
    const int tid = threadIdx.x;
    const int c = cg * 256 + tid;

    float A2[NSTATE];
    #pragma unroll
    for (int n = 0; n < NSTATE; ++n)
        A2[n] = A2T[((long)m * NSTATE + n) * DINNER + c];
    const bool geo = geo_check(A2);
    float h[NSTATE] = {};
    float sum_d = 0.f;

    __shared__ float sB[CHUNK][NSTATE];
    const short* dbc_mb = (const short*)dbc + (long)m * MROWS * 64 + (long)b * LSEQ * 64;
    const int t0 = chunk * CHUNK;
    for (int i = tid; i < CHUNK * NSTATE; i += 256) {
        int tt = i >> 4, j = i & 15;
        sB[tt][j] = bf2f(dbc_mb[(long)(t0 + tt) * 64 + 32 + j]);
    }
    __syncthreads();

    const short* dp = (const short*)delta;
    const short* up = (const short*)xc;
    const long base = ((long)mb * LSEQ + t0) * DINNER + c;
    if (geo) {
        #pragma unroll 4
        for (int tt = 0; tt < CHUNK; ++tt) {
            const float d = bf2f(dp[base + (long)tt * DINNER]);
            const float u = bf2f(up[base + (long)tt * DINNER]);
            const float du = d * u;
            sum_d += d;
            const float E = EXP2F(d * A2[0]);
            float e = 1.f;
            #pragma unroll
            for (int n = 0; n < NSTATE; ++n) {
                e *= E;
                h[n] = e * h[n] + du * sB[tt][n];
            }
        }
    } else {
        #pragma unroll 4
        for (int tt = 0; tt < CHUNK; ++tt) {
            const float d = bf2f(dp[base + (long)tt * DINNER]);
            const float u = bf2f(up[base + (long)tt * DINNER]);
            const float du = d * u;
            sum_d += d;
            #pragma unroll
            for (int n = 0; n < NSTATE; ++n) {
                float e = EXP2F(d * A2[n]);
                h[n] = e * h[n] + du * sB[tt][n];
            }
        }
    }
    const long ob = ((long)mb * NCHUNK + chunk) * (NSTATE * DINNER) + c;
    #pragma unroll
    for (int n = 0; n < NSTATE; ++n)
        Fbuf[ob + n * DINNER] = h[n];
    sumd[(((long)mb * NCHUNK + chunk) << 10) + c] = sum_d;
}

__global__ __launch_bounds__(256) void scan_pass2_kernel(float* __restrict__ Fbuf,
                                                         const float* __restrict__ sumd,
                                                         const float* __restrict__ A2T)
{
    const long idx = (long)blockIdx.x * 256 + threadIdx.x;  // < 6*16*1024
    const int mb = (int)(idx >> 14);
    const int cn = (int)(idx & 16383);        // n*1024 + c
    const int n = cn >> 10;
    const int c = cn & 1023;
    const int m = mb >> 1;
    const float A2n = A2T[((long)m * NSTATE + n) * DINNER + c];
    float run = 0.f;
    #pragma unroll 4
    for (int k = 0; k < NCHUNK; ++k) {
        const long o = ((long)(mb * NCHUNK + k) << 14) + cn;
        const float f = Fbuf[o];
        const float p = EXP2F(sumd[(((long)mb * NCHUNK + k) << 10) + c] * A2n);
        Fbuf[o] = run;
        run = p * run + f;
    }
}

__global__ __launch_bounds__(256) void scan_pass3_kernel(
    const __hip_bfloat16* __restrict__ delta, const __hip_bfloat16* __restrict__ xc,
    const __hip_bfloat16* __restrict__ dbc, __hip_bfloat16* __restrict__ xz,
    const float* __restrict__ A2T, const float* __restrict__ D_skip,
    const float* __restrict__ Hin)
{
    const int bx = blockIdx.x;
    const int chunk = bx & (NCHUNK - 1);
    const int cg = (bx >> 6) & 3;
    const int mb = bx >> 8;
    const int m = mb >> 1, b = mb & 1;
    const int tid = threadIdx.x;
    const int c = cg * 256 + tid;

    float A2[NSTATE];
    #pragma unroll
    for (int n = 0; n < NSTATE; ++n)
        A2[n] = A2T[((long)m * NSTATE + n) * DINNER + c];
    const bool geo = geo_check(A2);
    const float Dsk = D_skip[m * DINNER + c];

    float h[NSTATE];
    const long ho = ((long)mb * NCHUNK + chunk) * (NSTATE * DINNER) + c;
    #pragma unroll
    for (int n = 0; n < NSTATE; ++n) h[n] = Hin[ho + n * DINNER];

    __shared__ float sBC[CHUNK][2 * NSTATE];
    const short* dbc_mb = (const short*)dbc + (long)m * MROWS * 64 + (long)b * LSEQ * 64;
    const int t0 = chunk * CHUNK;
    for (int i = tid; i < CHUNK * 2 * NSTATE; i += 256) {
        int tt = i >> 5, j = i & 31;
        sBC[tt][j] = bf2f(dbc_mb[(long)(t0 + tt) * 64 + 32 + j]);
    }
    __syncthreads();

    const short* dp = (const short*)delta;
    const short* up = (const short*)xc;
    short* xzp = (short*)xz;
    const long base = ((long)mb * LSEQ + t0) * DINNER + c;
    const long xbase = ((long)mb * LSEQ + t0) * 2048 + c;
    if (geo) {
        #pragma unroll 4
        for (int tt = 0; tt < CHUNK; ++tt) {
            const long idx = base + (long)tt * DINNER;
            const long xi  = xbase + (long)tt * 2048;
            const float d = bf2f(dp[idx]);
            const float u = bf2f(up[idx]);
            const float zv = bf2f(xzp[xi + 1024]);
            const float du = d * u;
            const float E = EXP2F(d * A2[0]);
            float e = 1.f;
            float y = 0.f;
            #pragma unroll
            for (int n = 0; n < NSTATE; ++n) {
                e *= E;
                h[n] = e * h[n] + du * sBC[tt][n];
                y += h[n] * sBC[tt][16 + n];
            }
            y += u * Dsk;
            xzp[xi] = f2bf(y * (zv * sigmoid_f(zv)));
        }
    } else {
        #pragma unroll 4
        for (int tt = 0; tt < CHUNK; ++tt) {
            const long idx = base + (long)tt * DINNER;
            const long xi  = xbase + (long)tt * 2048;
            const float d = bf2f(dp[idx]);
            const float u = bf2f(up[idx]);
            const float zv = bf2f(xzp[xi + 1024]);
            const float du = d * u;
            float y = 0.f;
            #pragma unroll
            for (int n = 0; n < NSTATE; ++n) {
                float e = EXP2F(d * A2[n]);
                h[n] = e * h[n] + du * sBC[tt][n];
                y += h[n] * sBC[tt][16 + n];
            }
            y += u * Dsk;
            xzp[xi] = f2bf(y * (zv * sigmoid_f(zv)));
        }
    }
}

extern "C" void kernel_launch(void* const* d_in, const int* in_sizes, int n_in,
                              void* d_out, int out_size, void* d_ws, size_t ws_size,
                              hipStream_t stream)
{
    const float* v       = (const float*)d_in[0];
    const float* a       = (const float*)d_in[1];
    const float* t       = (const float*)d_in[2];
    const float* norm_w  = (const float*)d_in[3];
    const float* norm_b  = (const float*)d_in[4];
    const float* in_w    = (const float*)d_in[5];
    const float* conv_w  = (const float*)d_in[6];
    const float* conv_b  = (const float*)d_in[7];
    const float* xproj_w = (const float*)d_in[8];
    const float* dt_w    = (const float*)d_in[9];
    const float* dt_b    = (const float*)d_in[10];
    const float* A_log   = (const float*)d_in[11];
    const float* D_skip  = (const float*)d_in[12];
    const float* out_w   = (const float*)d_in[13];
    const float* couple_w= (const float*)d_in[14];
    const float* coef    = (const float*)d_in[15];
    float* out = (float*)d_out;

    typedef __hip_bfloat16 bf;
    float* x_in   = (float*)d_ws;                       // [3][4096][512] f32
    bf* xn_bf     = (bf*)(x_in + 6291456);              // [3][4096][512]
    bf* sec_bf    = xn_bf + 6291456;                    // [3][4096][512]
    bf* xz_bf     = sec_bf + 6291456;                   // [3][4096][2048]  (xc-pre | z; later y | z)
    bf* xc_bf     = xz_bf + 25165824;                   // [3][4096][1024]
    bf* delta_bf  = xc_bf + 12582912;                   // [3][4096][1024]
    bf* dbc_bf    = delta_bf + 12582912;                // [3][4096][64]
    bf* cw_bf     = dbc_bf + 786432;                    // [3][512][512]
    bf* inw_bf    = cw_bf + 786432;                     // [3][2048][512]
    bf* xpw_bf    = inw_bf + 3145728;                   // [3][64][1024]
    bf* dtw_bf    = xpw_bf + 196608;                    // [3][1024][32]
    bf* outw_bf   = dtw_bf + 98304;                     // [3][512][1024]
    float* cwT    = (float*)(outw_bf + 1572864);        // [3][4][1024] f32
    float* A2T    = cwT + 12288;                        // [3][16][1024] f32
    float* Fbuf   = A2T + 49152;                        // [6][64][16][1024] f32
    float* sumd   = Fbuf + 6291456;                     // [6][64][1024] f32

    dim3 blk(256);

    // 0. fused prep
    prep_kernel<<<(1572864 + 1449984 + 12288 + 49152 + 255) / 256, blk, 0, stream>>>(
        a, t, v, sec_bf, couple_w, cw_bf, in_w, inw_bf, xproj_w, xpw_bf,
        dt_w, dtw_bf, out_w, outw_bf, conv_w, cwT, A_log, A2T);

    // 1. coupling (merged z=3)
    gemm_bf16<2, 32><<<dim3(32, 8, 3), blk, 0, stream>>>(
        sec_bf, cw_bf, 512, 512, 512, 2097152L, 262144L,
        x_in, nullptr, 512, 2097152L,
        v, 0L, a, t, coef, 1, nullptr, 0L, 0);
    // 2. layernorm -> bf16
    ln_kernel<<<3*4096, blk, 0, stream>>>(x_in, xn_bf, norm_w, norm_b);
    // 3. in_proj (both halves, N=2048) -> xz  — 8-phase 256x256 pipelined kernel
    gemm8p_inproj<<<dim3(16, 8, 3), 512, 0, stream>>>(xn_bf, inw_bf, xz_bf);
    // 4. conv + SiLU
    conv_silu_kernel<<<768, blk, 0, stream>>>(xz_bf, cwT, conv_b, xc_bf);
    // 5. x_proj -> dbc bf16
    gemm_bf16<2, 32><<<dim3(32, 1, 3), blk, 0, stream>>>(
        xc_bf, xpw_bf, 1024, 1024, 1024, 4194304L, 65536L,
        nullptr, dbc_bf, 64, 262144L, nullptr, 0L, nullptr, nullptr, nullptr, 0, nullptr, 0L, 0);
    // 6. delta = softplus(dt @ dt_w^T + dt_b) -> bf16
    gemm_bf16<4, 32><<<dim3(32, 8, 3), blk, 0, stream>>>(
        dbc_bf, dtw_bf, 32, 64, 32, 262144L, 32768L,
        nullptr, delta_bf, 1024, 4194304L, nullptr, 0L, nullptr, nullptr, nullptr, 0, dt_b, 1024L, 1);
    // 7. chunk-parallel scan
    scan_pass1_kernel<<<6*4*NCHUNK, blk, 0, stream>>>(delta_bf, xc_bf, dbc_bf, A2T, Fbuf, sumd);
    scan_pass2_kernel<<<(6*1024*16)/256, blk, 0, stream>>>(Fbuf, sumd, A2T);
    scan_pass3_kernel<<<6*4*NCHUNK, blk, 0, stream>>>(delta_bf, xc_bf, dbc_bf, xz_bf,
                                                      A2T, D_skip, Fbuf);
    // 8. out_proj + residual -> d_out
    gemm_bf16<2, 32><<<dim3(32, 8, 3), blk, 0, stream>>>(
        xz_bf, outw_bf, 1024, 2048, 1024, 8388608L, 524288L,
        out, nullptr, 512, 2097152L, x_in, 2097152L, nullptr, nullptr, nullptr, 0, nullptr, 0L, 0);
}

// Round 18
// 254.217 us; speedup vs baseline: 1.3445x; 1.0225x over previous
//
#include <hip/hip_runtime.h>
#include <hip/hip_bf16.h>

#define MODS 3
#define BSZ 2
#define LSEQ 2048
#define DMODEL 512
#define DINNER 1024
#define DTRANK 32
#define NSTATE 16
#define DCONV 4
#define MROWS (BSZ*LSEQ)   // 4096
#define NCHUNK 64
#define CHUNK 32           // LSEQ / NCHUNK

#define LOG2E 1.44269504088896f
#define LN2   0.69314718055995f

typedef __attribute__((ext_vector_type(8))) short short8v;
typedef __attribute__((ext_vector_type(4))) short short4v;
typedef __attribute__((ext_vector_type(2))) short short2v;
typedef __attribute__((ext_vector_type(4))) float f32x4;

#if __has_builtin(__builtin_amdgcn_exp2f)
#define EXP2F __builtin_amdgcn_exp2f
#else
#define EXP2F exp2f
#endif
#if __has_builtin(__builtin_amdgcn_rcpf)
#define RCPF __builtin_amdgcn_rcpf
#else
#define RCPF(x) (1.0f / (x))
#endif

__device__ __forceinline__ short f2bf(float x) {
    __hip_bfloat16 h = __float2bfloat16(x);
    return __builtin_bit_cast(short, h);
}
__device__ __forceinline__ float bf2f(short s) {
    return __uint_as_float(((unsigned)(unsigned short)s) << 16);
}
__device__ __forceinline__ void gl_lds16(const short* g, short* l) {
    __builtin_amdgcn_global_load_lds(
        (const __attribute__((address_space(1))) unsigned int*)g,
        (__attribute__((address_space(3))) unsigned int*)l, 16, 0, 0);
}
__device__ __forceinline__ float sigmoid_f(float x) {
    return RCPF(1.f + EXP2F(-x * LOG2E));
}

// ============ 8-phase 256x256 pipelined GEMM for in_proj (M=4096,N=2048,K=512) ======
#define MFMAQ(QR, QC)                                                              \
    _Pragma("unroll")                                                              \
    for (int rf = 0; rf < 4; ++rf)                                                 \
        _Pragma("unroll")                                                          \
        for (int cf = 0; cf < 2; ++cf)                                             \
            _Pragma("unroll")                                                      \
            for (int kh = 0; kh < 2; ++kh)                                         \
                acc[QR][QC][rf][cf] = __builtin_amdgcn_mfma_f32_16x16x32_bf16(     \
                    afr[rf][kh], bfr[cf][kh], acc[QR][QC][rf][cf], 0, 0, 0);

__global__ __launch_bounds__(512, 2) void gemm8p_inproj(
    const __hip_bfloat16* __restrict__ A_, const __hip_bfloat16* __restrict__ B_,
    __hip_bfloat16* __restrict__ C_)
{
    constexpr int NT = 8;                 // K=512 / BK=64
    __shared__ alignas(16) short As[2 * 16384];
    __shared__ alignas(16) short Bs[2 * 16384];
    const int z = blockIdx.z;
    const int bm0 = blockIdx.x * 256;
    const int bn0 = blockIdx.y * 256;
    const short* Ag = (const short*)A_ + (long)z * 2097152 + (long)bm0 * 512;
    const short* Bg = (const short*)B_ + (long)z * 1048576 + (long)bn0 * 512;
    short* Cg = (short*)C_ + (long)z * 8388608;
    const int tid = threadIdx.x;
    const int lane = tid & 63;
    const int w = tid >> 6;
    const int wr = w >> 2;
    const int wc = w & 3;
    const int lr = lane & 15;
    const int sidx = lane >> 4;
    const int srow_l = tid >> 3;
    const int sgoff = ((tid & 7) ^ (srow_l & 7)) * 8;

    f32x4 acc[2][2][4][2];
    #pragma unroll
    for (int a = 0; a < 2; ++a)
        #pragma unroll
        for (int b = 0; b < 2; ++b)
            #pragma unroll
            for (int c = 0; c < 4; ++c)
                #pragma unroll
                for (int d = 0; d < 2; ++d)
                    acc[a][b][c][d] = (f32x4){0.f, 0.f, 0.f, 0.f};

    short8v afr[4][2];
    short8v bfr[2][2];

    auto stageA = [&](int buf, int half, int t) {
        #pragma unroll
        for (int j = 0; j < 2; ++j) {
            const int row = half * 128 + j * 64 + srow_l;
            gl_lds16(Ag + (long)row * 512 + t * 64 + sgoff,
                     As + buf * 16384 + half * 8192 + j * 4096 + tid * 8);
        }
    };
    auto stageB = [&](int buf, int half, int t) {
        #pragma unroll
        for (int j = 0; j < 2; ++j) {
            const int row = half * 128 + j * 64 + srow_l;
            gl_lds16(Bg + (long)row * 512 + t * 64 + sgoff,
                     Bs + buf * 16384 + half * 8192 + j * 4096 + tid * 8);
        }
    };
    auto loadA = [&](int buf, int qr) {
        #pragma unroll
        for (int rf = 0; rf < 4; ++rf)
            #pragma unroll
            for (int kh = 0; kh < 2; ++kh) {
                const int ra = qr * 128 + wr * 64 + rf * 16 + lr;
                const int g = kh * 4 + sidx;
                afr[rf][kh] = *(const short8v*)&As[buf * 16384 + ra * 64 + ((g ^ (ra & 7)) << 3)];
            }
    };
    auto loadB = [&](int buf, int qc) {
        #pragma unroll
        for (int cf = 0; cf < 2; ++cf)
            #pragma unroll
            for (int kh = 0; kh < 2; ++kh) {
                const int rb = qc * 128 + wc * 32 + cf * 16 + lr;
                const int g = kh * 4 + sidx;
                bfr[cf][kh] = *(const short8v*)&Bs[buf * 16384 + rb * 64 + ((g ^ (rb & 7)) << 3)];
            }
    };

    stageA(0, 0, 0); stageB(0, 0, 0); stageA(0, 1, 0); stageB(0, 1, 0);

    for (int t = 0; t < NT; ++t) {
        const int p = t & 1;
        const bool stg = (t + 1) < NT;
        if (stg) { stageA(p ^ 1, 0, t + 1);
                   asm volatile("s_waitcnt vmcnt(6)" ::: "memory"); }
        else       asm volatile("s_waitcnt vmcnt(4)" ::: "memory");
        asm volatile("s_barrier" ::: "memory");
        loadA(p, 0); loadB(p, 0);
        MFMAQ(0, 0)
        asm volatile("s_barrier" ::: "memory");
        if (stg) { stageB(p ^ 1, 0, t + 1);
                   asm volatile("s_waitcnt vmcnt(6)" ::: "memory"); }
        else       asm volatile("s_waitcnt vmcnt(2)" ::: "memory");
        asm volatile("s_barrier" ::: "memory");
        loadA(p, 1);
        MFMAQ(1, 0)
        asm volatile("s_barrier" ::: "memory");
        if (stg) { stageA(p ^ 1, 1, t + 1);
                   asm volatile("s_waitcnt vmcnt(6)" ::: "memory"); }
        else       asm volatile("s_waitcnt vmcnt(0)" ::: "memory");
        asm volatile("s_barrier" ::: "memory");
        loadB(p, 1);
        MFMAQ(1, 1)
        asm volatile("s_barrier" ::: "memory");
        if (stg) stageB(p ^ 1, 1, t + 1);
        asm volatile("s_barrier" ::: "memory");
        loadA(p, 0);
        MFMAQ(0, 1)
        asm volatile("s_barrier" ::: "memory");
    }

    #pragma unroll
    for (int qr = 0; qr < 2; ++qr)
        #pragma unroll
        for (int qc = 0; qc < 2; ++qc)
            #pragma unroll
            for (int rf = 0; rf < 4; ++rf)
                #pragma unroll
                for (int r = 0; r < 4; ++r) {
                    const int row = bm0 + qr * 128 + wr * 64 + rf * 16 + (lane >> 4) * 4 + r;
                    #pragma unroll
                    for (int cf = 0; cf < 2; ++cf) {
                        const int col = bn0 + qc * 128 + wc * 32 + cf * 16 + lr;
                        Cg[(long)row * 2048 + col] = f2bf(acc[qr][qc][rf][cf][r]);
                    }
                }
}

// ---------------- bf16 MFMA GEMM NT, BK=32, XOR-swizzled LDS, 2-phase prefetch dbuf ----
template<int NJ, int BK>
__global__ __launch_bounds__(256) void gemm_bf16(
    const __hip_bfloat16* __restrict__ A_, const __hip_bfloat16* __restrict__ B_,
    int K, int lda, int ldb, long sA, long sB,
    float* __restrict__ Cf, __hip_bfloat16* __restrict__ Cb, int ldc, long sC,
    const float* __restrict__ res, long sRes,
    const float* __restrict__ resB, const float* __restrict__ resC,
    const float* __restrict__ coef_base, int coef_stride,
    const float* __restrict__ bias, long sBias, int act)
{
    constexpr int BN = NJ * 32;
    constexpr int ASZ = 128 * BK;
    constexpr int BSZe = BN * BK;
    __shared__ alignas(16) short As[2 * ASZ];
    __shared__ alignas(16) short Bs[2 * BSZe];
    const int z = blockIdx.z;
    const int bm0 = blockIdx.x * 128;
    const int bn0 = blockIdx.y * BN;
    const short* Ag = (const short*)A_ + z * sA + (long)bm0 * lda;
    const short* Bg = (const short*)B_ + z * sB + (long)bn0 * ldb;
    const int tid = threadIdx.x;
    const int lane = tid & 63;
    const int w = tid >> 6;
    const int wr = w >> 1, wc = w & 1;
    const int lr = lane & 15;
    const int sidx = lane >> 4;

    constexpr int SLOTS = BK / 8;
    const int srow = tid / SLOTS;
    const int sslot = tid % SLOTS;
    int swz;
    if constexpr (BK == 64) swz = srow & 7;
    else                    swz = (srow >> 1) & 3;
    const int sgcol = (sslot ^ swz) * 8;
    int fA;
    if constexpr (BK == 64) fA = lr & 7;
    else                    fA = (lr >> 1) & 3;

    constexpr int AINSTR = ASZ / 2048;
    constexpr int BINSTR = BSZe / 2048;
    constexpr int RPI = 2048 / BK;

    f32x4 acc[4][NJ];
    #pragma unroll
    for (int i = 0; i < 4; ++i)
        #pragma unroll
        for (int j = 0; j < NJ; ++j)
            acc[i][j] = (f32x4){0.f, 0.f, 0.f, 0.f};

    auto stage = [&](int buf, int k0) {
        #pragma unroll
        for (int i = 0; i < AINSTR; ++i)
            gl_lds16(Ag + (long)(i * RPI + srow) * lda + k0 + sgcol,
                     As + buf * ASZ + i * 2048 + tid * 8);
        #pragma unroll
        for (int i = 0; i < BINSTR; ++i)
            gl_lds16(Bg + (long)(i * RPI + srow) * ldb + k0 + sgcol,
                     Bs + buf * BSZe + i * 2048 + tid * 8);
    };
    auto compute = [&](int buf) {
        #pragma unroll
        for (int kh = 0; kh < BK / 32; ++kh) {
            const int sl = ((kh * 4 + sidx) ^ fA) * 8;
            short8v af[4], bfr2[NJ];
            #pragma unroll
            for (int i = 0; i < 4; ++i)
                af[i] = *(const short8v*)&As[buf * ASZ + (wr * 64 + i * 16 + lr) * BK + sl];
            #pragma unroll
            for (int j = 0; j < NJ; ++j)
                bfr2[j] = *(const short8v*)&Bs[buf * BSZe + (wc * NJ * 16 + j * 16 + lr) * BK + sl];
            #pragma unroll
            for (int i = 0; i < 4; ++i)
                #pragma unroll
                for (int j = 0; j < NJ; ++j)
                    acc[i][j] = __builtin_amdgcn_mfma_f32_16x16x32_bf16(af[i], bfr2[j], acc[i][j], 0, 0, 0);
        }
    };

    stage(0, 0);
    __syncthreads();
    int cur = 0;
    for (int k0 = BK; k0 < K; k0 += BK) {
        stage(cur ^ 1, k0);
        compute(cur);
        __syncthreads();
        cur ^= 1;
    }
    compute(cur);

    const float alpha = coef_base ? coef_base[z * coef_stride] : 1.0f;
    const float* resz = nullptr;
    if (res) {
        if (resB) resz = (z == 0) ? res : ((z == 1) ? resB : resC);
        else      resz = res + z * sRes;
    }
    const float* biasz = bias ? bias + z * sBias : nullptr;
    float* Cfz = Cf ? Cf + (long)z * sC : nullptr;
    __hip_bfloat16* Cbz = Cb ? Cb + (long)z * sC : nullptr;
    #pragma unroll
    for (int i = 0; i < 4; ++i) {
        #pragma unroll
        for (int r = 0; r < 4; ++r) {
            const int row = bm0 + wr * 64 + i * 16 + (lane >> 4) * 4 + r;
            #pragma unroll
            for (int j = 0; j < NJ; ++j) {
                const int col = bn0 + wc * NJ * 16 + j * 16 + lr;
                float val = acc[i][j][r];
                if (biasz) val += biasz[col];
                if (act == 1)
                    val = (val > 20.f) ? val : LN2 * __log2f(1.f + EXP2F(val * LOG2E));
                val *= alpha;
                if (resz) val += resz[(long)row * ldc + col];
                if (Cfz) Cfz[(long)row * ldc + col] = val;
                else     Cbz[(long)row * ldc + col] = __float2bfloat16(val);
            }
        }
    }
}

// ---------------- fused prep: sec->bf16 + weight cvts + conv-wT + A2T ----------------
__global__ __launch_bounds__(256) void prep_kernel(
    const float* __restrict__ a, const float* __restrict__ t, const float* __restrict__ v,
    __hip_bfloat16* __restrict__ sec_bf,
    const float* __restrict__ couple_w, __hip_bfloat16* __restrict__ cw_bf,
    const float* __restrict__ in_w, __hip_bfloat16* __restrict__ inw_bf,
    const float* __restrict__ xproj_w, __hip_bfloat16* __restrict__ xpw_bf,
    const float* __restrict__ dt_w, __hip_bfloat16* __restrict__ dtw_bf,
    const float* __restrict__ out_w, __hip_bfloat16* __restrict__ outw_bf,
    const float* __restrict__ conv_w, float* __restrict__ cwT,
    const float* __restrict__ A_log, float* __restrict__ A2T)
{
    long idx = (long)blockIdx.x * 256 + threadIdx.x;
    if (idx < 1572864) {
        const int m = (int)(idx >> 19);
        const long off = idx & 524287;
        const float* sec = (m == 0) ? a : (m == 1) ? t : v;
        float4 sv = ((const float4*)sec)[off];
        short4v s;
        s.x = f2bf(sv.x); s.y = f2bf(sv.y); s.z = f2bf(sv.z); s.w = f2bf(sv.w);
        ((short4v*)sec_bf)[idx] = s;
        return;
    }
    idx -= 1572864;
    if (idx < 1449984) {
        const float* s; __hip_bfloat16* d; long off = idx;
        if      (off < 196608)              { s = couple_w; d = cw_bf; }
        else if ((off -= 196608) < 786432)  { s = in_w;     d = inw_bf; }
        else if ((off -= 786432) < 49152)   { s = xproj_w;  d = xpw_bf; }
        else if ((off -= 49152) < 24576)    { s = dt_w;     d = dtw_bf; }
        else    { off -= 24576;               s = out_w;    d = outw_bf; }
        float4 vv = ((const float4*)s)[off];
        short4v o;
        o.x = f2bf(vv.x); o.y = f2bf(vv.y); o.z = f2bf(vv.z); o.w = f2bf(vv.w);
        ((short4v*)d)[off] = o;
        return;
    }
    idx -= 1449984;
    if (idx < 12288) {
        const int k = (int)(idx & 3);
        const int c = (int)((idx >> 2) & 1023);
        const int m = (int)(idx >> 12);
        cwT[(m * DCONV + k) * DINNER + c] = conv_w[idx];
        return;
    }
    idx -= 12288;
    if (idx < 49152) {
        const int c = (int)(idx & 1023);
        const int n = (int)((idx >> 10) & 15);
        const int m = (int)(idx >> 14);
        A2T[idx] = -EXP2F(A_log[((long)m * DINNER + c) * NSTATE + n] * LOG2E) * LOG2E;
    }
}

// ---------------- LayerNorm: f32 in -> bf16 out ----------------
__global__ __launch_bounds__(256) void ln_kernel(const float* __restrict__ x, __hip_bfloat16* __restrict__ xn,
                                                 const float* __restrict__ nw, const float* __restrict__ nb)
{
    const int row = blockIdx.x;
    const int m = row >> 12;
    const int tid = threadIdx.x;
    const float2 v = *reinterpret_cast<const float2*>(x + (long)row * DMODEL + tid * 2);
    float s = v.x + v.y;
    float sq = v.x * v.x + v.y * v.y;
    #pragma unroll
    for (int off = 32; off > 0; off >>= 1) {
        s  += __shfl_down(s, off);
        sq += __shfl_down(sq, off);
    }
    __shared__ float ws_s[4], ws_q[4];
    const int wid = tid >> 6, lane = tid & 63;
    if (lane == 0) { ws_s[wid] = s; ws_q[wid] = sq; }
    __syncthreads();
    if (tid == 0) {
        float ts = ws_s[0] + ws_s[1] + ws_s[2] + ws_s[3];
        float tq = ws_q[0] + ws_q[1] + ws_q[2] + ws_q[3];
        float mu = ts / DMODEL;
        float var = tq / DMODEL - mu * mu;
        ws_s[0] = mu;
        ws_q[0] = rsqrtf(var + 1e-5f);
    }
    __syncthreads();
    const float mu = ws_s[0], rstd = ws_q[0];
    const int e0 = tid * 2;
    float2 w  = *reinterpret_cast<const float2*>(nw + m * DMODEL + e0);
    float2 bb = *reinterpret_cast<const float2*>(nb + m * DMODEL + e0);
    short2v o;
    o.x = f2bf((v.x - mu) * rstd * w.x + bb.x);
    o.y = f2bf((v.y - mu) * rstd * w.y + bb.y);
    *reinterpret_cast<short2v*>((short*)xn + (long)row * DMODEL + e0) = o;
}

// ---------------- depthwise causal conv(4) + SiLU ----------------
__global__ __launch_bounds__(256) void conv_silu_kernel(const __hip_bfloat16* __restrict__ xz,
    const float* __restrict__ cwT, const float* __restrict__ cb, __hip_bfloat16* __restrict__ xc)
{
    const int idx = blockIdx.x * 256 + threadIdx.x;   // < 6*256*128 = 196608
    const int c8 = idx & 127;
    const int lt = (idx >> 7) & 255;
    const int mb = idx >> 15;
    const int m  = mb >> 1;
    const int c0 = c8 * 8;
    const int l0 = lt * 8;

    float4 wlo[DCONV], whi[DCONV];
    #pragma unroll
    for (int k = 0; k < DCONV; ++k) {
        wlo[k] = *(const float4*)&cwT[(m * DCONV + k) * DINNER + c0];
        whi[k] = *(const float4*)&cwT[(m * DCONV + k) * DINNER + c0 + 4];
    }
    const float4 blo = *(const float4*)&cb[m * DINNER + c0];
    const float4 bhi = *(const float4*)&cb[m * DINNER + c0 + 4];

    const short* base = (const short*)xz + (long)mb * LSEQ * 2048 + c0;
    short* obase = (short*)xc + (long)mb * LSEQ * DINNER + c0;

    short8v r0 = {}, r1 = {}, r2 = {};
    if (l0 - 3 >= 0) r0 = *(const short8v*)(base + (long)(l0 - 3) * 2048);
    if (l0 - 2 >= 0) r1 = *(const short8v*)(base + (long)(l0 - 2) * 2048);
    if (l0 - 1 >= 0) r2 = *(const short8v*)(base + (long)(l0 - 1) * 2048);

    #pragma unroll
    for (int i = 0; i < 8; ++i) {
        const short8v cur = *(const short8v*)(base + (long)(l0 + i) * 2048);
        float acc[8];
        #pragma unroll
        for (int j = 0; j < 4; ++j) {
            acc[j]     = ((const float*)&blo)[j];
            acc[4 + j] = ((const float*)&bhi)[j];
        }
        #pragma unroll
        for (int j = 0; j < 8; ++j) {
            const float w0 = (j < 4) ? ((const float*)&wlo[0])[j] : ((const float*)&whi[0])[j - 4];
            const float w1 = (j < 4) ? ((const float*)&wlo[1])[j] : ((const float*)&whi[1])[j - 4];
            const float w2 = (j < 4) ? ((const float*)&wlo[2])[j] : ((const float*)&whi[2])[j - 4];
            const float w3 = (j < 4) ? ((const float*)&wlo[3])[j] : ((const float*)&whi[3])[j - 4];
            acc[j] += w0 * bf2f(r0[j]) + w1 * bf2f(r1[j]) + w2 * bf2f(r2[j]) + w3 * bf2f(cur[j]);
        }
        short8v o;
        #pragma unroll
        for (int j = 0; j < 8; ++j)
            o[j] = f2bf(acc[j] * sigmoid_f(acc[j]));
        *(short8v*)(obase + (long)(l0 + i) * DINNER) = o;
        r0 = r1; r1 = r2; r2 = cur;
    }
}

// ---------------- chunk-parallel selective scan: 2 channels/thread for ILP ----------
__device__ __forceinline__ bool geo_check(const float* A2) {
    bool g = true;
    #pragma unroll
    for (int n = 1; n < NSTATE; ++n)
        g = g && (__builtin_fabsf(A2[n] - (float)(n + 1) * A2[0]) <= 1e-4f * __builtin_fabsf(A2[n]));
    return g;
}

// Pass 1: grid mb(6) x cg(2) x chunk(64) = 768 blocks; thread owns c0 and c0+512.
__global__ __launch_bounds__(256) void scan_pass1_kernel(
    const __hip_bfloat16* __restrict__ delta, const __hip_bfloat16* __restrict__ xc,
    const __hip_bfloat16* __restrict__ dbc, const float* __restrict__ A2T,
    float* __restrict__ Fbuf, float* __restrict__ sumd)
{
    const int bx = blockIdx.x;
    const int chunk = bx & (NCHUNK - 1);
    const int cg = (bx >> 6) & 1;
    const int mb = bx >> 7;
    const int m = mb >> 1, b = mb & 1;
    const int tid = threadIdx.x;
    const int c0 = cg * 256 + tid;         // [0,512)
    const int c1 = c0 + 512;

    float A2a[NSTATE], A2b[NSTATE];
    #pragma unroll
    for (int n = 0; n < NSTATE; ++n) {
        A2a[n] = A2T[((long)m * NSTATE + n) * DINNER + c0];
        A2b[n] = A2T[((long)m * NSTATE + n) * DINNER + c1];
    }
    const bool geo = geo_check(A2a) && geo_check(A2b);
    float h0[NSTATE] = {}, h1[NSTATE] = {};
    float sd0 = 0.f, sd1 = 0.f;

    __shared__ float sB[CHUNK][NSTATE];
    const short* dbc_mb = (const short*)dbc + (long)m * MROWS * 64 + (long)b * LSEQ * 64;
    const int t0 = chunk * CHUNK;
    for (int i = tid; i < CHUNK * NSTATE; i += 256) {
        int tt = i >> 4, j = i & 15;
        sB[tt][j] = bf2f(dbc_mb[(long)(t0 + tt) * 64 + 32 + j]);
    }
    __syncthreads();

    const short* dp = (const short*)delta;
    const short* up = (const short*)xc;
    const long base = ((long)mb * LSEQ + t0) * DINNER + c0;
    if (geo) {
        #pragma unroll 2
        for (int tt = 0; tt < CHUNK; ++tt) {
            const long ix = base + (long)tt * DINNER;
            const float d0 = bf2f(dp[ix]),       u0 = bf2f(up[ix]);
            const float d1 = bf2f(dp[ix + 512]), u1 = bf2f(up[ix + 512]);
            const float du0 = d0 * u0, du1 = d1 * u1;
            sd0 += d0; sd1 += d1;
            const float E0 = EXP2F(d0 * A2a[0]);
            const float E1 = EXP2F(d1 * A2b[0]);
            float e0 = 1.f, e1 = 1.f;
            #pragma unroll
            for (int n = 0; n < NSTATE; ++n) {
                e0 *= E0; e1 *= E1;
                h0[n] = e0 * h0[n] + du0 * sB[tt][n];
                h1[n] = e1 * h1[n] + du1 * sB[tt][n];
            }
        }
    } else {
        #pragma unroll 2
        for (int tt = 0; tt < CHUNK; ++tt) {
            const long ix = base + (long)tt * DINNER;
            const float d0 = bf2f(dp[ix]),       u0 = bf2f(up[ix]);
            const float d1 = bf2f(dp[ix + 512]), u1 = bf2f(up[ix + 512]);
            const float du0 = d0 * u0, du1 = d1 * u1;
            sd0 += d0; sd1 += d1;
            #pragma unroll
            for (int n = 0; n < NSTATE; ++n) {
                h0[n] = EXP2F(d0 * A2a[n]) * h0[n] + du0 * sB[tt][n];
                h1[n] = EXP2F(d1 * A2b[n]) * h1[n] + du1 * sB[tt][n];
            }
        }
    }
    const long ob = ((long)mb * NCHUNK + chunk) * (NSTATE * DINNER) + c0;
    #pragma unroll
    for (int n = 0; n < NSTATE; ++n) {
        Fbuf[ob + n * DINNER] = h0[n];
        Fbuf[ob + n * DINNER + 512] = h1[n];
    }
    const long so = (((long)mb * NCHUNK + chunk) << 10) + c0;
    sumd[so] = sd0;
    sumd[so + 512] = sd1;
}

__global__ __launch_bounds__(256) void scan_pass2_kernel(float* __restrict__ Fbuf,
                                                         const float* __restrict__ sumd,
                                                         const float* __restrict__ A2T)
{
    const long idx = (long)blockIdx.x * 256 + threadIdx.x;  // < 6*16*1024
    const int mb = (int)(idx >> 14);
    const int cn = (int)(idx & 16383);
    const int n = cn >> 10;
    const int c = cn & 1023;
    const int m = mb >> 1;
    const float A2n = A2T[((long)m * NSTATE + n) * DINNER + c];
    float run = 0.f;
    #pragma unroll 4
    for (int k = 0; k < NCHUNK; ++k) {
        const long o = ((long)(mb * NCHUNK + k) << 14) + cn;
        const float f = Fbuf[o];
        const float p = EXP2F(sumd[(((long)mb * NCHUNK + k) << 10) + c] * A2n);
        Fbuf[o] = run;
        run = p * run + f;
    }
}

// Pass 3: grid mb(6) x cg(2) x chunk(64) = 768 blocks; thread owns c0 and c0+512.
__global__ __launch_bounds__(256) void scan_pass3_kernel(
    const __hip_bfloat16* __restrict__ delta, const __hip_bfloat16* __restrict__ xc,
    const __hip_bfloat16* __restrict__ dbc, __hip_bfloat16* __restrict__ xz,
    const float* __restrict__ A2T, const float* __restrict__ D_skip,
    const float* __restrict__ Hin)
{
    const int bx = blockIdx.x;
    const int chunk = bx & (NCHUNK - 1);
    const int cg = (bx >> 6) & 1;
    const int mb = bx >> 7;
    const int m = mb >> 1, b = mb & 1;
    const int tid = threadIdx.x;
    const int c0 = cg * 256 + tid;
    const int c1 = c0 + 512;

    float A2a[NSTATE], A2b[NSTATE];
    #pragma unroll
    for (int n = 0; n < NSTATE; ++n) {
        A2a[n] = A2T[((long)m * NSTATE + n) * DINNER + c0];
        A2b[n] = A2T[((long)m * NSTATE + n) * DINNER + c1];
    }
    const bool geo = geo_check(A2a) && geo_check(A2b);
    const float Dsk0 = D_skip[m * DINNER + c0];
    const float Dsk1 = D_skip[m * DINNER + c1];

    float h0[NSTATE], h1[NSTATE];
    const long ho = ((long)mb * NCHUNK + chunk) * (NSTATE * DINNER) + c0;
    #pragma unroll
    for (int n = 0; n < NSTATE; ++n) {
        h0[n] = Hin[ho + n * DINNER];
        h1[n] = Hin[ho + n * DINNER + 512];
    }

    __shared__ float sBC[CHUNK][2 * NSTATE];
    const short* dbc_mb = (const short*)dbc + (long)m * MROWS * 64 + (long)b * LSEQ * 64;
    const int t0 = chunk * CHUNK;
    for (int i = tid; i < CHUNK * 2 * NSTATE; i += 256) {
        int tt = i >> 5, j = i & 31;
        sBC[tt][j] = bf2f(dbc_mb[(long)(t0 + tt) * 64 + 32 + j]);
    }
    __syncthreads();

    const short* dp = (const short*)delta;
    const short* up = (const short*)xc;
    short* xzp = (short*)xz;
    const long base = ((long)mb * LSEQ + t0) * DINNER + c0;
    const long xbase = ((long)mb * LSEQ + t0) * 2048 + c0;
    if (geo) {
        #pragma unroll 2
        for (int tt = 0; tt < CHUNK; ++tt) {
            const long ix = base + (long)tt * DINNER;
            const long xi = xbase + (long)tt * 2048;
            const float d0 = bf2f(dp[ix]),       u0 = bf2f(up[ix]);
            const float d1 = bf2f(dp[ix + 512]), u1 = bf2f(up[ix + 512]);
            const float zv0 = bf2f(xzp[xi + 1024]);
            const float zv1 = bf2f(xzp[xi + 1536]);
            const float du0 = d0 * u0, du1 = d1 * u1;
            const float E0 = EXP2F(d0 * A2a[0]);
            const float E1 = EXP2F(d1 * A2b[0]);
            float e0 = 1.f, e1 = 1.f;
            float y0 = 0.f, y1 = 0.f;
            #pragma unroll
            for (int n = 0; n < NSTATE; ++n) {
                e0 *= E0; e1 *= E1;
                h0[n] = e0 * h0[n] + du0 * sBC[tt][n];
                h1[n] = e1 * h1[n] + du1 * sBC[tt][n];
                y0 += h0[n] * sBC[tt][16 + n];
                y1 += h1[n] * sBC[tt][16 + n];
            }
            y0 += u0 * Dsk0;
            y1 += u1 * Dsk1;
            xzp[xi]       = f2bf(y0 * (zv0 * sigmoid_f(zv0)));
            xzp[xi + 512] = f2bf(y1 * (zv1 * sigmoid_f(zv1)));
        }
    } else {
        #pragma unroll 2
        for (int tt = 0; tt < CHUNK; ++tt) {
            const long ix = base + (long)tt * DINNER;
            const long xi = xbase + (long)tt * 2048;
            const float d0 = bf2f(dp[ix]),       u0 = bf2f(up[ix]);
            const float d1 = bf2f(dp[ix + 512]), u1 = bf2f(up[ix + 512]);
            const float zv0 = bf2f(xzp[xi + 1024]);
            const float zv1 = bf2f(xzp[xi + 1536]);
            const float du0 = d0 * u0, du1 = d1 * u1;
            float y0 = 0.f, y1 = 0.f;
            #pragma unroll
            for (int n = 0; n < NSTATE; ++n) {
                h0[n] = EXP2F(d0 * A2a[n]) * h0[n] + du0 * sBC[tt][n];
                h1[n] = EXP2F(d1 * A2b[n]) * h1[n] + du1 * sBC[tt][n];
                y0 += h0[n] * sBC[tt][16 + n];
                y1 += h1[n] * sBC[tt][16 + n];
            }
            y0 += u0 * Dsk0;
            y1 += u1 * Dsk1;
            xzp[xi]       = f2bf(y0 * (zv0 * sigmoid_f(zv0)));
            xzp[xi + 512] = f2bf(y1 * (zv1 * sigmoid_f(zv1)));
        }
    }
}

extern "C" void kernel_launch(void* const* d_in, const int* in_sizes, int n_in,
                              void* d_out, int out_size, void* d_ws, size_t ws_size,
                              hipStream_t stream)
{
    const float* v       = (const float*)d_in[0];
    const float* a       = (const float*)d_in[1];
    const float* t       = (const float*)d_in[2];
    const float* norm_w  = (const float*)d_in[3];
    const float* norm_b  = (const float*)d_in[4];
    const float* in_w    = (const float*)d_in[5];
    const float* conv_w  = (const float*)d_in[6];
    const float* conv_b  = (const float*)d_in[7];
    const float* xproj_w = (const float*)d_in[8];
    const float* dt_w    = (const float*)d_in[9];
    const float* dt_b    = (const float*)d_in[10];
    const float* A_log   = (const float*)d_in[11];
    const float* D_skip  = (const float*)d_in[12];
    const float* out_w   = (const float*)d_in[13];
    const float* couple_w= (const float*)d_in[14];
    const float* coef    = (const float*)d_in[15];
    float* out = (float*)d_out;

    typedef __hip_bfloat16 bf;
    float* x_in   = (float*)d_ws;                       // [3][4096][512] f32
    bf* xn_bf     = (bf*)(x_in + 6291456);              // [3][4096][512]
    bf* sec_bf    = xn_bf + 6291456;                    // [3][4096][512]
    bf* xz_bf     = sec_bf + 6291456;                   // [3][4096][2048]  (xc-pre | z; later y | z)
    bf* xc_bf     = xz_bf + 25165824;                   // [3][4096][1024]
    bf* delta_bf  = xc_bf + 12582912;                   // [3][4096][1024]
    bf* dbc_bf    = delta_bf + 12582912;                // [3][4096][64]
    bf* cw_bf     = dbc_bf + 786432;                    // [3][512][512]
    bf* inw_bf    = cw_bf + 786432;                     // [3][2048][512]
    bf* xpw_bf    = inw_bf + 3145728;                   // [3][64][1024]
    bf* dtw_bf    = xpw_bf + 196608;                    // [3][1024][32]
    bf* outw_bf   = dtw_bf + 98304;                     // [3][512][1024]
    float* cwT    = (float*)(outw_bf + 1572864);        // [3][4][1024] f32
    float* A2T    = cwT + 12288;                        // [3][16][1024] f32
    float* Fbuf   = A2T + 49152;                        // [6][64][16][1024] f32
    float* sumd   = Fbuf + 6291456;                     // [6][64][1024] f32

    dim3 blk(256);

    // 0. fused prep
    prep_kernel<<<(1572864 + 1449984 + 12288 + 49152 + 255) / 256, blk, 0, stream>>>(
        a, t, v, sec_bf, couple_w, cw_bf, in_w, inw_bf, xproj_w, xpw_bf,
        dt_w, dtw_bf, out_w, outw_bf, conv_w, cwT, A_log, A2T);

    // 1. coupling (merged z=3)
    gemm_bf16<2, 32><<<dim3(32, 8, 3), blk, 0, stream>>>(
        sec_bf, cw_bf, 512, 512, 512, 2097152L, 262144L,
        x_in, nullptr, 512, 2097152L,
        v, 0L, a, t, coef, 1, nullptr, 0L, 0);
    // 2. layernorm -> bf16
    ln_kernel<<<3*4096, blk, 0, stream>>>(x_in, xn_bf, norm_w, norm_b);
    // 3. in_proj (both halves, N=2048) -> xz  — 8-phase 256x256 pipelined kernel
    gemm8p_inproj<<<dim3(16, 8, 3), 512, 0, stream>>>(xn_bf, inw_bf, xz_bf);
    // 4. conv + SiLU
    conv_silu_kernel<<<768, blk, 0, stream>>>(xz_bf, cwT, conv_b, xc_bf);
    // 5. x_proj -> dbc bf16
    gemm_bf16<2, 32><<<dim3(32, 1, 3), blk, 0, stream>>>(
        xc_bf, xpw_bf, 1024, 1024, 1024, 4194304L, 65536L,
        nullptr, dbc_bf, 64, 262144L, nullptr, 0L, nullptr, nullptr, nullptr, 0, nullptr, 0L, 0);
    // 6. delta = softplus(dt @ dt_w^T + dt_b) -> bf16
    gemm_bf16<4, 32><<<dim3(32, 8, 3), blk, 0, stream>>>(
        dbc_bf, dtw_bf, 32, 64, 32, 262144L, 32768L,
        nullptr, delta_bf, 1024, 4194304L, nullptr, 0L, nullptr, nullptr, nullptr, 0, dt_b, 1024L, 1);
    // 7. chunk-parallel scan (2 channels/thread)
    scan_pass1_kernel<<<6*2*NCHUNK, blk, 0, stream>>>(delta_bf, xc_bf, dbc_bf, A2T, Fbuf, sumd);
    scan_pass2_kernel<<<(6*1024*16)/256, blk, 0, stream>>>(Fbuf, sumd, A2T);
    scan_pass3_kernel<<<6*2*NCHUNK, blk, 0, stream>>>(delta_bf, xc_bf, dbc_bf, xz_bf,
                                                      A2T, D_skip, Fbuf);
    // 8. out_proj + residual -> d_out
    gemm_bf16<2, 32><<<dim3(32, 8, 3), blk, 0, stream>>>(
        xz_bf, outw_bf, 1024, 2048, 1024, 8388608L, 524288L,
        out, nullptr, 512, 2097152L, x_in, 2097152L, nullptr, nullptr, nullptr, 0, nullptr, 0L, 0);
}

// Round 19
// 252.389 us; speedup vs baseline: 1.3543x; 1.0072x over previous
//
#include <hip/hip_runtime.h>
#include <hip/hip_bf16.h>

#define MODS 3
#define BSZ 2
#define LSEQ 2048
#define DMODEL 512
#define DINNER 1024
#define DTRANK 32
#define NSTATE 16
#define DCONV 4
#define MROWS (BSZ*LSEQ)   // 4096
#define NCHUNK 64
#define CHUNK 32           // LSEQ / NCHUNK

#define LOG2E 1.44269504088896f
#define LN2   0.69314718055995f

typedef __attribute__((ext_vector_type(8))) short short8v;
typedef __attribute__((ext_vector_type(4))) short short4v;
typedef __attribute__((ext_vector_type(2))) short short2v;
typedef __attribute__((ext_vector_type(4))) float f32x4;

#if __has_builtin(__builtin_amdgcn_exp2f)
#define EXP2F __builtin_amdgcn_exp2f
#else
#define EXP2F exp2f
#endif
#if __has_builtin(__builtin_amdgcn_rcpf)
#define RCPF __builtin_amdgcn_rcpf
#else
#define RCPF(x) (1.0f / (x))
#endif

__device__ __forceinline__ short f2bf(float x) {
    __hip_bfloat16 h = __float2bfloat16(x);
    return __builtin_bit_cast(short, h);
}
__device__ __forceinline__ float bf2f(short s) {
    return __uint_as_float(((unsigned)(unsigned short)s) << 16);
}
__device__ __forceinline__ void gl_lds16(const short* g, short* l) {
    __builtin_amdgcn_global_load_lds(
        (const __attribute__((address_space(1))) unsigned int*)g,
        (__attribute__((address_space(3))) unsigned int*)l, 16, 0, 0);
}
__device__ __forceinline__ float sigmoid_f(float x) {
    return RCPF(1.f + EXP2F(-x * LOG2E));
}

// ============ 8-phase 256x256 pipelined GEMM for in_proj (M=4096,N=2048,K=512) ======
// 1024 threads = 16 waves (4x4) -> 4 waves/SIMD at 1 block/CU (128 KiB LDS):
// doubles per-SIMD latency hiding vs the 512-thread variant. Phase order:
// stage(next half, 1 gl_lds) -> counted vmcnt -> s_barrier -> ds_read -> MFMA -> s_barrier.
// Waits (queue Ah0,Bh0,Ah1,Bh1; 1 load/stage): steady vmcnt(3); last tile 2/1/0.
#define MFMAQ(QR, QC)                                                              \
    _Pragma("unroll")                                                              \
    for (int rf = 0; rf < 2; ++rf)                                                 \
        _Pragma("unroll")                                                          \
        for (int cf = 0; cf < 2; ++cf)                                             \
            _Pragma("unroll")                                                      \
            for (int kh = 0; kh < 2; ++kh)                                         \
                acc[QR][QC][rf][cf] = __builtin_amdgcn_mfma_f32_16x16x32_bf16(     \
                    afr[rf][kh], bfr[cf][kh], acc[QR][QC][rf][cf], 0, 0, 0);

__global__ __launch_bounds__(1024) void gemm8p_inproj(
    const __hip_bfloat16* __restrict__ A_, const __hip_bfloat16* __restrict__ B_,
    __hip_bfloat16* __restrict__ C_)
{
    constexpr int NT = 8;                 // K=512 / BK=64
    __shared__ alignas(16) short As[2 * 16384];   // 2 buf x [256 rows][64 k]
    __shared__ alignas(16) short Bs[2 * 16384];
    const int z = blockIdx.z;
    const int bm0 = blockIdx.x * 256;
    const int bn0 = blockIdx.y * 256;
    const short* Ag = (const short*)A_ + (long)z * 2097152 + (long)bm0 * 512;
    const short* Bg = (const short*)B_ + (long)z * 1048576 + (long)bn0 * 512;
    short* Cg = (short*)C_ + (long)z * 8388608;
    const int tid = threadIdx.x;
    const int lane = tid & 63;
    const int w = tid >> 6;               // 0..15
    const int wr = w >> 2;                // 0..3
    const int wc = w & 3;                 // 0..3
    const int lr = lane & 15;
    const int sidx = lane >> 4;           // 0..3
    const int srow_l = tid >> 3;          // 0..127
    const int sgoff = ((tid & 7) ^ (srow_l & 7)) * 8;   // pre-swizzled global slot

    f32x4 acc[2][2][2][2];
    #pragma unroll
    for (int a = 0; a < 2; ++a)
        #pragma unroll
        for (int b = 0; b < 2; ++b)
            #pragma unroll
            for (int c = 0; c < 2; ++c)
                #pragma unroll
                for (int d = 0; d < 2; ++d)
                    acc[a][b][c][d] = (f32x4){0.f, 0.f, 0.f, 0.f};

    short8v afr[2][2];
    short8v bfr[2][2];

    // staging: 1024 thr x 16B = 16 KiB = one 128-row half per call (dest linear)
    auto stageA = [&](int buf, int half, int t) {
        const int row = half * 128 + srow_l;
        gl_lds16(Ag + (long)row * 512 + t * 64 + sgoff,
                 As + buf * 16384 + half * 8192 + tid * 8);
    };
    auto stageB = [&](int buf, int half, int t) {
        const int row = half * 128 + srow_l;
        gl_lds16(Bg + (long)row * 512 + t * 64 + sgoff,
                 Bs + buf * 16384 + half * 8192 + tid * 8);
    };
    auto loadA = [&](int buf, int qr) {
        #pragma unroll
        for (int rf = 0; rf < 2; ++rf)
            #pragma unroll
            for (int kh = 0; kh < 2; ++kh) {
                const int ra = qr * 128 + wr * 32 + rf * 16 + lr;
                const int g = kh * 4 + sidx;
                afr[rf][kh] = *(const short8v*)&As[buf * 16384 + ra * 64 + ((g ^ (ra & 7)) << 3)];
            }
    };
    auto loadB = [&](int buf, int qc) {
        #pragma unroll
        for (int cf = 0; cf < 2; ++cf)
            #pragma unroll
            for (int kh = 0; kh < 2; ++kh) {
                const int rb = qc * 128 + wc * 32 + cf * 16 + lr;
                const int g = kh * 4 + sidx;
                bfr[cf][kh] = *(const short8v*)&Bs[buf * 16384 + rb * 64 + ((g ^ (rb & 7)) << 3)];
            }
    };

    // prologue: stage tile 0 (queue order Ah0, Bh0, Ah1, Bh1; 4 loads/wave)
    stageA(0, 0, 0); stageB(0, 0, 0); stageA(0, 1, 0); stageB(0, 1, 0);

    for (int t = 0; t < NT; ++t) {
        const int p = t & 1;
        const bool stg = (t + 1) < NT;
        // ---- P0: quadrant (0,0), reads A-h0 + B-h0 of tile t
        if (stg) { stageA(p ^ 1, 0, t + 1);
                   asm volatile("s_waitcnt vmcnt(3)" ::: "memory"); }
        else       asm volatile("s_waitcnt vmcnt(2)" ::: "memory");
        asm volatile("s_barrier" ::: "memory");
        loadA(p, 0); loadB(p, 0);
        MFMAQ(0, 0)
        asm volatile("s_barrier" ::: "memory");
        // ---- P1: quadrant (1,0), reads A-h1 (B-h0 in regs)
        if (stg) { stageB(p ^ 1, 0, t + 1);
                   asm volatile("s_waitcnt vmcnt(3)" ::: "memory"); }
        else       asm volatile("s_waitcnt vmcnt(1)" ::: "memory");
        asm volatile("s_barrier" ::: "memory");
        loadA(p, 1);
        MFMAQ(1, 0)
        asm volatile("s_barrier" ::: "memory");
        // ---- P2: quadrant (1,1), reads B-h1 (A-h1 in regs)
        if (stg) { stageA(p ^ 1, 1, t + 1);
                   asm volatile("s_waitcnt vmcnt(3)" ::: "memory"); }
        else       asm volatile("s_waitcnt vmcnt(0)" ::: "memory");
        asm volatile("s_barrier" ::: "memory");
        loadB(p, 1);
        MFMAQ(1, 1)
        asm volatile("s_barrier" ::: "memory");
        // ---- P3: quadrant (0,1), re-reads A-h0 (visible since P0)
        if (stg) stageB(p ^ 1, 1, t + 1);
        asm volatile("s_barrier" ::: "memory");
        loadA(p, 0);
        MFMAQ(0, 1)
        asm volatile("s_barrier" ::: "memory");
    }

    // epilogue: C bf16, ldc = 2048
    #pragma unroll
    for (int qr = 0; qr < 2; ++qr)
        #pragma unroll
        for (int qc = 0; qc < 2; ++qc)
            #pragma unroll
            for (int rf = 0; rf < 2; ++rf)
                #pragma unroll
                for (int r = 0; r < 4; ++r) {
                    const int row = bm0 + qr * 128 + wr * 32 + rf * 16 + (lane >> 4) * 4 + r;
                    #pragma unroll
                    for (int cf = 0; cf < 2; ++cf) {
                        const int col = bn0 + qc * 128 + wc * 32 + cf * 16 + lr;
                        Cg[(long)row * 2048 + col] = f2bf(acc[qr][qc][rf][cf][r]);
                    }
                }
}

// ---------------- bf16 MFMA GEMM NT, BK=32, XOR-swizzled LDS, 2-phase prefetch dbuf ----
template<int NJ, int BK>
__global__ __launch_bounds__(256) void gemm_bf16(
    const __hip_bfloat16* __restrict__ A_, const __hip_bfloat16* __restrict__ B_,
    int K, int lda, int ldb, long sA, long sB,
    float* __restrict__ Cf, __hip_bfloat16* __restrict__ Cb, int ldc, long sC,
    const float* __restrict__ res, long sRes,
    const float* __restrict__ resB, const float* __restrict__ resC,
    const float* __restrict__ coef_base, int coef_stride,
    const float* __restrict__ bias, long sBias, int act)
{
    constexpr int BN = NJ * 32;
    constexpr int ASZ = 128 * BK;
    constexpr int BSZe = BN * BK;
    __shared__ alignas(16) short As[2 * ASZ];
    __shared__ alignas(16) short Bs[2 * BSZe];
    const int z = blockIdx.z;
    const int bm0 = blockIdx.x * 128;
    const int bn0 = blockIdx.y * BN;
    const short* Ag = (const short*)A_ + z * sA + (long)bm0 * lda;
    const short* Bg = (const short*)B_ + z * sB + (long)bn0 * ldb;
    const int tid = threadIdx.x;
    const int lane = tid & 63;
    const int w = tid >> 6;
    const int wr = w >> 1, wc = w & 1;
    const int lr = lane & 15;
    const int sidx = lane >> 4;

    constexpr int SLOTS = BK / 8;
    const int srow = tid / SLOTS;
    const int sslot = tid % SLOTS;
    int swz;
    if constexpr (BK == 64) swz = srow & 7;
    else                    swz = (srow >> 1) & 3;
    const int sgcol = (sslot ^ swz) * 8;
    int fA;
    if constexpr (BK == 64) fA = lr & 7;
    else                    fA = (lr >> 1) & 3;

    constexpr int AINSTR = ASZ / 2048;
    constexpr int BINSTR = BSZe / 2048;
    constexpr int RPI = 2048 / BK;

    f32x4 acc[4][NJ];
    #pragma unroll
    for (int i = 0; i < 4; ++i)
        #pragma unroll
        for (int j = 0; j < NJ; ++j)
            acc[i][j] = (f32x4){0.f, 0.f, 0.f, 0.f};

    auto stage = [&](int buf, int k0) {
        #pragma unroll
        for (int i = 0; i < AINSTR; ++i)
            gl_lds16(Ag + (long)(i * RPI + srow) * lda + k0 + sgcol,
                     As + buf * ASZ + i * 2048 + tid * 8);
        #pragma unroll
        for (int i = 0; i < BINSTR; ++i)
            gl_lds16(Bg + (long)(i * RPI + srow) * ldb + k0 + sgcol,
                     Bs + buf * BSZe + i * 2048 + tid * 8);
    };
    auto compute = [&](int buf) {
        #pragma unroll
        for (int kh = 0; kh < BK / 32; ++kh) {
            const int sl = ((kh * 4 + sidx) ^ fA) * 8;
            short8v af[4], bfr2[NJ];
            #pragma unroll
            for (int i = 0; i < 4; ++i)
                af[i] = *(const short8v*)&As[buf * ASZ + (wr * 64 + i * 16 + lr) * BK + sl];
            #pragma unroll
            for (int j = 0; j < NJ; ++j)
                bfr2[j] = *(const short8v*)&Bs[buf * BSZe + (wc * NJ * 16 + j * 16 + lr) * BK + sl];
            #pragma unroll
            for (int i = 0; i < 4; ++i)
                #pragma unroll
                for (int j = 0; j < NJ; ++j)
                    acc[i][j] = __builtin_amdgcn_mfma_f32_16x16x32_bf16(af[i], bfr2[j], acc[i][j], 0, 0, 0);
        }
    };

    stage(0, 0);
    __syncthreads();
    int cur = 0;
    for (int k0 = BK; k0 < K; k0 += BK) {
        stage(cur ^ 1, k0);
        compute(cur);
        __syncthreads();
        cur ^= 1;
    }
    compute(cur);

    const float alpha = coef_base ? coef_base[z * coef_stride] : 1.0f;
    const float* resz = nullptr;
    if (res) {
        if (resB) resz = (z == 0) ? res : ((z == 1) ? resB : resC);
        else      resz = res + z * sRes;
    }
    const float* biasz = bias ? bias + z * sBias : nullptr;
    float* Cfz = Cf ? Cf + (long)z * sC : nullptr;
    __hip_bfloat16* Cbz = Cb ? Cb + (long)z * sC : nullptr;
    #pragma unroll
    for (int i = 0; i < 4; ++i) {
        #pragma unroll
        for (int r = 0; r < 4; ++r) {
            const int row = bm0 + wr * 64 + i * 16 + (lane >> 4) * 4 + r;
            #pragma unroll
            for (int j = 0; j < NJ; ++j) {
                const int col = bn0 + wc * NJ * 16 + j * 16 + lr;
                float val = acc[i][j][r];
                if (biasz) val += biasz[col];
                if (act == 1)
                    val = (val > 20.f) ? val : LN2 * __log2f(1.f + EXP2F(val * LOG2E));
                val *= alpha;
                if (resz) val += resz[(long)row * ldc + col];
                if (Cfz) Cfz[(long)row * ldc + col] = val;
                else     Cbz[(long)row * ldc + col] = __float2bfloat16(val);
            }
        }
    }
}

// ---------------- fused prep: sec->bf16 + weight cvts + conv-wT + A2T ----------------
__global__ __launch_bounds__(256) void prep_kernel(
    const float* __restrict__ a, const float* __restrict__ t, const float* __restrict__ v,
    __hip_bfloat16* __restrict__ sec_bf,
    const float* __restrict__ couple_w, __hip_bfloat16* __restrict__ cw_bf,
    const float* __restrict__ in_w, __hip_bfloat16* __restrict__ inw_bf,
    const float* __restrict__ xproj_w, __hip_bfloat16* __restrict__ xpw_bf,
    const float* __restrict__ dt_w, __hip_bfloat16* __restrict__ dtw_bf,
    const float* __restrict__ out_w, __hip_bfloat16* __restrict__ outw_bf,
    const float* __restrict__ conv_w, float* __restrict__ cwT,
    const float* __restrict__ A_log, float* __restrict__ A2T)
{
    long idx = (long)blockIdx.x * 256 + threadIdx.x;
    if (idx < 1572864) {
        const int m = (int)(idx >> 19);
        const long off = idx & 524287;
        const float* sec = (m == 0) ? a : (m == 1) ? t : v;
        float4 sv = ((const float4*)sec)[off];
        short4v s;
        s.x = f2bf(sv.x); s.y = f2bf(sv.y); s.z = f2bf(sv.z); s.w = f2bf(sv.w);
        ((short4v*)sec_bf)[idx] = s;
        return;
    }
    idx -= 1572864;
    if (idx < 1449984) {
        const float* s; __hip_bfloat16* d; long off = idx;
        if      (off < 196608)              { s = couple_w; d = cw_bf; }
        else if ((off -= 196608) < 786432)  { s = in_w;     d = inw_bf; }
        else if ((off -= 786432) < 49152)   { s = xproj_w;  d = xpw_bf; }
        else if ((off -= 49152) < 24576)    { s = dt_w;     d = dtw_bf; }
        else    { off -= 24576;               s = out_w;    d = outw_bf; }
        float4 vv = ((const float4*)s)[off];
        short4v o;
        o.x = f2bf(vv.x); o.y = f2bf(vv.y); o.z = f2bf(vv.z); o.w = f2bf(vv.w);
        ((short4v*)d)[off] = o;
        return;
    }
    idx -= 1449984;
    if (idx < 12288) {
        const int k = (int)(idx & 3);
        const int c = (int)((idx >> 2) & 1023);
        const int m = (int)(idx >> 12);
        cwT[(m * DCONV + k) * DINNER + c] = conv_w[idx];
        return;
    }
    idx -= 12288;
    if (idx < 49152) {
        const int c = (int)(idx & 1023);
        const int n = (int)((idx >> 10) & 15);
        const int m = (int)(idx >> 14);
        A2T[idx] = -EXP2F(A_log[((long)m * DINNER + c) * NSTATE + n] * LOG2E) * LOG2E;
    }
}

// ---------------- LayerNorm: f32 in -> bf16 out ----------------
__global__ __launch_bounds__(256) void ln_kernel(const float* __restrict__ x, __hip_bfloat16* __restrict__ xn,
                                                 const float* __restrict__ nw, const float* __restrict__ nb)
{
    const int row = blockIdx.x;
    const int m = row >> 12;
    const int tid = threadIdx.x;
    const float2 v = *reinterpret_cast<const float2*>(x + (long)row * DMODEL + tid * 2);
    float s = v.x + v.y;
    float sq = v.x * v.x + v.y * v.y;
    #pragma unroll
    for (int off = 32; off > 0; off >>= 1) {
        s  += __shfl_down(s, off);
        sq += __shfl_down(sq, off);
    }
    __shared__ float ws_s[4], ws_q[4];
    const int wid = tid >> 6, lane = tid & 63;
    if (lane == 0) { ws_s[wid] = s; ws_q[wid] = sq; }
    __syncthreads();
    if (tid == 0) {
        float ts = ws_s[0] + ws_s[1] + ws_s[2] + ws_s[3];
        float tq = ws_q[0] + ws_q[1] + ws_q[2] + ws_q[3];
        float mu = ts / DMODEL;
        float var = tq / DMODEL - mu * mu;
        ws_s[0] = mu;
        ws_q[0] = rsqrtf(var + 1e-5f);
    }
    __syncthreads();
    const float mu = ws_s[0], rstd = ws_q[0];
    const int e0 = tid * 2;
    float2 w  = *reinterpret_cast<const float2*>(nw + m * DMODEL + e0);
    float2 bb = *reinterpret_cast<const float2*>(nb + m * DMODEL + e0);
    short2v o;
    o.x = f2bf((v.x - mu) * rstd * w.x + bb.x);
    o.y = f2bf((v.y - mu) * rstd * w.y + bb.y);
    *reinterpret_cast<short2v*>((short*)xn + (long)row * DMODEL + e0) = o;
}

// ---------------- depthwise causal conv(4) + SiLU ----------------
__global__ __launch_bounds__(256) void conv_silu_kernel(const __hip_bfloat16* __restrict__ xz,
    const float* __restrict__ cwT, const float* __restrict__ cb, __hip_bfloat16* __restrict__ xc)
{
    const int idx = blockIdx.x * 256 + threadIdx.x;   // < 6*256*128 = 196608
    const int c8 = idx & 127;
    const int lt = (idx >> 7) & 255;
    const int mb = idx >> 15;
    const int m  = mb >> 1;
    const int c0 = c8 * 8;
    const int l0 = lt * 8;

    float4 wlo[DCONV], whi[DCONV];
    #pragma unroll
    for (int k = 0; k < DCONV; ++k) {
        wlo[k] = *(const float4*)&cwT[(m * DCONV + k) * DINNER + c0];
        whi[k] = *(const float4*)&cwT[(m * DCONV + k) * DINNER + c0 + 4];
    }
    const float4 blo = *(const float4*)&cb[m * DINNER + c0];
    const float4 bhi = *(const float4*)&cb[m * DINNER + c0 + 4];

    const short* base = (const short*)xz + (long)mb * LSEQ * 2048 + c0;
    short* obase = (short*)xc + (long)mb * LSEQ * DINNER + c0;

    short8v r0 = {}, r1 = {}, r2 = {};
    if (l0 - 3 >= 0) r0 = *(const short8v*)(base + (long)(l0 - 3) * 2048);
    if (l0 - 2 >= 0) r1 = *(const short8v*)(base + (long)(l0 - 2) * 2048);
    if (l0 - 1 >= 0) r2 = *(const short8v*)(base + (long)(l0 - 1) * 2048);

    #pragma unroll
    for (int i = 0; i < 8; ++i) {
        const short8v cur = *(const short8v*)(base + (long)(l0 + i) * 2048);
        float acc[8];
        #pragma unroll
        for (int j = 0; j < 4; ++j) {
            acc[j]     = ((const float*)&blo)[j];
            acc[4 + j] = ((const float*)&bhi)[j];
        }
        #pragma unroll
        for (int j = 0; j < 8; ++j) {
            const float w0 = (j < 4) ? ((const float*)&wlo[0])[j] : ((const float*)&whi[0])[j - 4];
            const float w1 = (j < 4) ? ((const float*)&wlo[1])[j] : ((const float*)&whi[1])[j - 4];
            const float w2 = (j < 4) ? ((const float*)&wlo[2])[j] : ((const float*)&whi[2])[j - 4];
            const float w3 = (j < 4) ? ((const float*)&wlo[3])[j] : ((const float*)&whi[3])[j - 4];
            acc[j] += w0 * bf2f(r0[j]) + w1 * bf2f(r1[j]) + w2 * bf2f(r2[j]) + w3 * bf2f(cur[j]);
        }
        short8v o;
        #pragma unroll
        for (int j = 0; j < 8; ++j)
            o[j] = f2bf(acc[j] * sigmoid_f(acc[j]));
        *(short8v*)(obase + (long)(l0 + i) * DINNER) = o;
        r0 = r1; r1 = r2; r2 = cur;
    }
}

// ---------------- chunk-parallel selective scan: 2 channels/thread for ILP ----------
__device__ __forceinline__ bool geo_check(const float* A2) {
    bool g = true;
    #pragma unroll
    for (int n = 1; n < NSTATE; ++n)
        g = g && (__builtin_fabsf(A2[n] - (float)(n + 1) * A2[0]) <= 1e-4f * __builtin_fabsf(A2[n]));
    return g;
}

__global__ __launch_bounds__(256) void scan_pass1_kernel(
    const __hip_bfloat16* __restrict__ delta, const __hip_bfloat16* __restrict__ xc,
    const __hip_bfloat16* __restrict__ dbc, const float* __restrict__ A2T,
    float* __restrict__ Fbuf, float* __restrict__ sumd)
{
    const int bx = blockIdx.x;
    const int chunk = bx & (NCHUNK - 1);
    const int cg = (bx >> 6) & 1;
    const int mb = bx >> 7;
    const int m = mb >> 1, b = mb & 1;
    const int tid = threadIdx.x;
    const int c0 = cg * 256 + tid;
    const int c1 = c0 + 512;

    float A2a[NSTATE], A2b[NSTATE];
    #pragma unroll
    for (int n = 0; n < NSTATE; ++n) {
        A2a[n] = A2T[((long)m * NSTATE + n) * DINNER + c0];
        A2b[n] = A2T[((long)m * NSTATE + n) * DINNER + c1];
    }
    const bool geo = geo_check(A2a) && geo_check(A2b);
    float h0[NSTATE] = {}, h1[NSTATE] = {};
    float sd0 = 0.f, sd1 = 0.f;

    __shared__ float sB[CHUNK][NSTATE];
    const short* dbc_mb = (const short*)dbc + (long)m * MROWS * 64 + (long)b * LSEQ * 64;
    const int t0 = chunk * CHUNK;
    for (int i = tid; i < CHUNK * NSTATE; i += 256) {
        int tt = i >> 4, j = i & 15;
        sB[tt][j] = bf2f(dbc_mb[(long)(t0 + tt) * 64 + 32 + j]);
    }
    __syncthreads();

    const short* dp = (const short*)delta;
    const short* up = (const short*)xc;
    const long base = ((long)mb * LSEQ + t0) * DINNER + c0;
    if (geo) {
        #pragma unroll 2
        for (int tt = 0; tt < CHUNK; ++tt) {
            const long ix = base + (long)tt * DINNER;
            const float d0 = bf2f(dp[ix]),       u0 = bf2f(up[ix]);
            const float d1 = bf2f(dp[ix + 512]), u1 = bf2f(up[ix + 512]);
            const float du0 = d0 * u0, du1 = d1 * u1;
            sd0 += d0; sd1 += d1;
            const float E0 = EXP2F(d0 * A2a[0]);
            const float E1 = EXP2F(d1 * A2b[0]);
            float e0 = 1.f, e1 = 1.f;
            #pragma unroll
            for (int n = 0; n < NSTATE; ++n) {
                e0 *= E0; e1 *= E1;
                h0[n] = e0 * h0[n] + du0 * sB[tt][n];
                h1[n] = e1 * h1[n] + du1 * sB[tt][n];
            }
        }
    } else {
        #pragma unroll 2
        for (int tt = 0; tt < CHUNK; ++tt) {
            const long ix = base + (long)tt * DINNER;
            const float d0 = bf2f(dp[ix]),       u0 = bf2f(up[ix]);
            const float d1 = bf2f(dp[ix + 512]), u1 = bf2f(up[ix + 512]);
            const float du0 = d0 * u0, du1 = d1 * u1;
            sd0 += d0; sd1 += d1;
            #pragma unroll
            for (int n = 0; n < NSTATE; ++n) {
                h0[n] = EXP2F(d0 * A2a[n]) * h0[n] + du0 * sB[tt][n];
                h1[n] = EXP2F(d1 * A2b[n]) * h1[n] + du1 * sB[tt][n];
            }
        }
    }
    const long ob = ((long)mb * NCHUNK + chunk) * (NSTATE * DINNER) + c0;
    #pragma unroll
    for (int n = 0; n < NSTATE; ++n) {
        Fbuf[ob + n * DINNER] = h0[n];
        Fbuf[ob + n * DINNER + 512] = h1[n];
    }
    const long so = (((long)mb * NCHUNK + chunk) << 10) + c0;
    sumd[so] = sd0;
    sumd[so + 512] = sd1;
}

__global__ __launch_bounds__(256) void scan_pass2_kernel(float* __restrict__ Fbuf,
                                                         const float* __restrict__ sumd,
                                                         const float* __restrict__ A2T)
{
    const long idx = (long)blockIdx.x * 256 + threadIdx.x;  // < 6*16*1024
    const int mb = (int)(idx >> 14);
    const int cn = (int)(idx & 16383);
    const int n = cn >> 10;
    const int c = cn & 1023;
    const int m = mb >> 1;
    const float A2n = A2T[((long)m * NSTATE + n) * DINNER + c];
    float run = 0.f;
    #pragma unroll 4
    for (int k = 0; k < NCHUNK; ++k) {
        const long o = ((long)(mb * NCHUNK + k) << 14) + cn;
        const float f = Fbuf[o];
        const float p = EXP2F(sumd[(((long)mb * NCHUNK + k) << 10) + c] * A2n);
        Fbuf[o] = run;
        run = p * run + f;
    }
}

__global__ __launch_bounds__(256) void scan_pass3_kernel(
    const __hip_bfloat16* __restrict__ delta, const __hip_bfloat16* __restrict__ xc,
    const __hip_bfloat16* __restrict__ dbc, __hip_bfloat16* __restrict__ xz,
    const float* __restrict__ A2T, const float* __restrict__ D_skip,
    const float* __restrict__ Hin)
{
    const int bx = blockIdx.x;
    const int chunk = bx & (NCHUNK - 1);
    const int cg = (bx >> 6) & 1;
    const int mb = bx >> 7;
    const int m = mb >> 1, b = mb & 1;
    const int tid = threadIdx.x;
    const int c0 = cg * 256 + tid;
    const int c1 = c0 + 512;

    float A2a[NSTATE], A2b[NSTATE];
    #pragma unroll
    for (int n = 0; n < NSTATE; ++n) {
        A2a[n] = A2T[((long)m * NSTATE + n) * DINNER + c0];
        A2b[n] = A2T[((long)m * NSTATE + n) * DINNER + c1];
    }
    const bool geo = geo_check(A2a) && geo_check(A2b);
    const float Dsk0 = D_skip[m * DINNER + c0];
    const float Dsk1 = D_skip[m * DINNER + c1];

    float h0[NSTATE], h1[NSTATE];
    const long ho = ((long)mb * NCHUNK + chunk) * (NSTATE * DINNER) + c0;
    #pragma unroll
    for (int n = 0; n < NSTATE; ++n) {
        h0[n] = Hin[ho + n * DINNER];
        h1[n] = Hin[ho + n * DINNER + 512];
    }

    __shared__ float sBC[CHUNK][2 * NSTATE];
    const short* dbc_mb = (const short*)dbc + (long)m * MROWS * 64 + (long)b * LSEQ * 64;
    const int t0 = chunk * CHUNK;
    for (int i = tid; i < CHUNK * 2 * NSTATE; i += 256) {
        int tt = i >> 5, j = i & 31;
        sBC[tt][j] = bf2f(dbc_mb[(long)(t0 + tt) * 64 + 32 + j]);
    }
    __syncthreads();

    const short* dp = (const short*)delta;
    const short* up = (const short*)xc;
    short* xzp = (short*)xz;
    const long base = ((long)mb * LSEQ + t0) * DINNER + c0;
    const long xbase = ((long)mb * LSEQ + t0) * 2048 + c0;
    if (geo) {
        #pragma unroll 2
        for (int tt = 0; tt < CHUNK; ++tt) {
            const long ix = base + (long)tt * DINNER;
            const long xi = xbase + (long)tt * 2048;
            const float d0 = bf2f(dp[ix]),       u0 = bf2f(up[ix]);
            const float d1 = bf2f(dp[ix + 512]), u1 = bf2f(up[ix + 512]);
            const float zv0 = bf2f(xzp[xi + 1024]);
            const float zv1 = bf2f(xzp[xi + 1536]);
            const float du0 = d0 * u0, du1 = d1 * u1;
            const float E0 = EXP2F(d0 * A2a[0]);
            const float E1 = EXP2F(d1 * A2b[0]);
            float e0 = 1.f, e1 = 1.f;
            float y0 = 0.f, y1 = 0.f;
            #pragma unroll
            for (int n = 0; n < NSTATE; ++n) {
                e0 *= E0; e1 *= E1;
                h0[n] = e0 * h0[n] + du0 * sBC[tt][n];
                h1[n] = e1 * h1[n] + du1 * sBC[tt][n];
                y0 += h0[n] * sBC[tt][16 + n];
                y1 += h1[n] * sBC[tt][16 + n];
            }
            y0 += u0 * Dsk0;
            y1 += u1 * Dsk1;
            xzp[xi]       = f2bf(y0 * (zv0 * sigmoid_f(zv0)));
            xzp[xi + 512] = f2bf(y1 * (zv1 * sigmoid_f(zv1)));
        }
    } else {
        #pragma unroll 2
        for (int tt = 0; tt < CHUNK; ++tt) {
            const long ix = base + (long)tt * DINNER;
            const long xi = xbase + (long)tt * 2048;
            const float d0 = bf2f(dp[ix]),       u0 = bf2f(up[ix]);
            const float d1 = bf2f(dp[ix + 512]), u1 = bf2f(up[ix + 512]);
            const float zv0 = bf2f(xzp[xi + 1024]);
            const float zv1 = bf2f(xzp[xi + 1536]);
            const float du0 = d0 * u0, du1 = d1 * u1;
            float y0 = 0.f, y1 = 0.f;
            #pragma unroll
            for (int n = 0; n < NSTATE; ++n) {
                h0[n] = EXP2F(d0 * A2a[n]) * h0[n] + du0 * sBC[tt][n];
                h1[n] = EXP2F(d1 * A2b[n]) * h1[n] + du1 * sBC[tt][n];
                y0 += h0[n] * sBC[tt][16 + n];
                y1 += h1[n] * sBC[tt][16 + n];
            }
            y0 += u0 * Dsk0;
            y1 += u1 * Dsk1;
            xzp[xi]       = f2bf(y0 * (zv0 * sigmoid_f(zv0)));
            xzp[xi + 512] = f2bf(y1 * (zv1 * sigmoid_f(zv1)));
        }
    }
}

extern "C" void kernel_launch(void* const* d_in, const int* in_sizes, int n_in,
                              void* d_out, int out_size, void* d_ws, size_t ws_size,
                              hipStream_t stream)
{
    const float* v       = (const float*)d_in[0];
    const float* a       = (const float*)d_in[1];
    const float* t       = (const float*)d_in[2];
    const float* norm_w  = (const float*)d_in[3];
    const float* norm_b  = (const float*)d_in[4];
    const float* in_w    = (const float*)d_in[5];
    const float* conv_w  = (const float*)d_in[6];
    const float* conv_b  = (const float*)d_in[7];
    const float* xproj_w = (const float*)d_in[8];
    const float* dt_w    = (const float*)d_in[9];
    const float* dt_b    = (const float*)d_in[10];
    const float* A_log   = (const float*)d_in[11];
    const float* D_skip  = (const float*)d_in[12];
    const float* out_w   = (const float*)d_in[13];
    const float* couple_w= (const float*)d_in[14];
    const float* coef    = (const float*)d_in[15];
    float* out = (float*)d_out;

    typedef __hip_bfloat16 bf;
    float* x_in   = (float*)d_ws;                       // [3][4096][512] f32
    bf* xn_bf     = (bf*)(x_in + 6291456);              // [3][4096][512]
    bf* sec_bf    = xn_bf + 6291456;                    // [3][4096][512]
    bf* xz_bf     = sec_bf + 6291456;                   // [3][4096][2048]  (xc-pre | z; later y | z)
    bf* xc_bf     = xz_bf + 25165824;                   // [3][4096][1024]
    bf* delta_bf  = xc_bf + 12582912;                   // [3][4096][1024]
    bf* dbc_bf    = delta_bf + 12582912;                // [3][4096][64]
    bf* cw_bf     = dbc_bf + 786432;                    // [3][512][512]
    bf* inw_bf    = cw_bf + 786432;                     // [3][2048][512]
    bf* xpw_bf    = inw_bf + 3145728;                   // [3][64][1024]
    bf* dtw_bf    = xpw_bf + 196608;                    // [3][1024][32]
    bf* outw_bf   = dtw_bf + 98304;                     // [3][512][1024]
    float* cwT    = (float*)(outw_bf + 1572864);        // [3][4][1024] f32
    float* A2T    = cwT + 12288;                        // [3][16][1024] f32
    float* Fbuf   = A2T + 49152;                        // [6][64][16][1024] f32
    float* sumd   = Fbuf + 6291456;                     // [6][64][1024] f32

    dim3 blk(256);

    // 0. fused prep
    prep_kernel<<<(1572864 + 1449984 + 12288 + 49152 + 255) / 256, blk, 0, stream>>>(
        a, t, v, sec_bf, couple_w, cw_bf, in_w, inw_bf, xproj_w, xpw_bf,
        dt_w, dtw_bf, out_w, outw_bf, conv_w, cwT, A_log, A2T);

    // 1. coupling (merged z=3)
    gemm_bf16<2, 32><<<dim3(32, 8, 3), blk, 0, stream>>>(
        sec_bf, cw_bf, 512, 512, 512, 2097152L, 262144L,
        x_in, nullptr, 512, 2097152L,
        v, 0L, a, t, coef, 1, nullptr, 0L, 0);
    // 2. layernorm -> bf16
    ln_kernel<<<3*4096, blk, 0, stream>>>(x_in, xn_bf, norm_w, norm_b);
    // 3. in_proj (both halves, N=2048) -> xz  — 8-phase 256x256, 16 waves/block
    gemm8p_inproj<<<dim3(16, 8, 3), 1024, 0, stream>>>(xn_bf, inw_bf, xz_bf);
    // 4. conv + SiLU
    conv_silu_kernel<<<768, blk, 0, stream>>>(xz_bf, cwT, conv_b, xc_bf);
    // 5. x_proj -> dbc bf16
    gemm_bf16<2, 32><<<dim3(32, 1, 3), blk, 0, stream>>>(
        xc_bf, xpw_bf, 1024, 1024, 1024, 4194304L, 65536L,
        nullptr, dbc_bf, 64, 262144L, nullptr, 0L, nullptr, nullptr, nullptr, 0, nullptr, 0L, 0);
    // 6. delta = softplus(dt @ dt_w^T + dt_b) -> bf16
    gemm_bf16<4, 32><<<dim3(32, 8, 3), blk, 0, stream>>>(
        dbc_bf, dtw_bf, 32, 64, 32, 262144L, 32768L,
        nullptr, delta_bf, 1024, 4194304L, nullptr, 0L, nullptr, nullptr, nullptr, 0, dt_b, 1024L, 1);
    // 7. chunk-parallel scan (2 channels/thread)
    scan_pass1_kernel<<<6*2*NCHUNK, blk, 0, stream>>>(delta_bf, xc_bf, dbc_bf, A2T, Fbuf, sumd);
    scan_pass2_kernel<<<(6*1024*16)/256, blk, 0, stream>>>(Fbuf, sumd, A2T);
    scan_pass3_kernel<<<6*2*NCHUNK, blk, 0, stream>>>(delta_bf, xc_bf, dbc_bf, xz_bf,
                                                      A2T, D_skip, Fbuf);
    // 8. out_proj + residual -> d_out
    gemm_bf16<2, 32><<<dim3(32, 8, 3), blk, 0, stream>>>(
        xz_bf, outw_bf, 1024, 2048, 1024, 8388608L, 524288L,
        out, nullptr, 512, 2097152L, x_in, 2097152L, nullptr, nullptr, nullptr, 0, nullptr, 0L, 0);
}